// Round 1
// baseline (1380.499 us; speedup 1.0000x reference)
//
#include <hip/hip_runtime.h>
#include <cstdint>
#include <cmath>

typedef unsigned short u16;
typedef unsigned int   u32;

using bf16x8 = __attribute__((ext_vector_type(8))) short;
using f32x4  = __attribute__((ext_vector_type(4))) float;

#define DM 256        // d_model
#define W0 416        // layer-0 input width padded 392 -> 416 (multiple of 32)
#define W0_REAL 392

__device__ __forceinline__ float bf2f(u16 v) {
  union { u32 u; float f; } c; c.u = ((u32)v) << 16; return c.f;
}
__device__ __forceinline__ u16 f2bf(float f) {
  union { float f; u32 u; } c; c.f = f;
  u32 u = c.u;
  return (u16)((u + 0x7FFFu + ((u >> 16) & 1u)) >> 16);  // RNE
}
__device__ __forceinline__ float siluf(float y) {
  return y / (1.0f + __expf(-y));
}

// ---------------- weight transpose + bf16 convert: out[n*Kpad+k] = W[k*Nc+n] ----
__global__ void wT_kernel(const float* __restrict__ W, u16* __restrict__ out,
                          int nmat, int K, int Kpad, int Nc) {
  int idx = blockIdx.x * 256 + threadIdx.x;
  int tot = nmat * Nc * Kpad;
  if (idx >= tot) return;
  int m = idx / (Nc * Kpad);
  int r = idx - m * (Nc * Kpad);
  int n = r / Kpad;
  int k = r - n * Kpad;
  float v = (k < K) ? W[(size_t)m * K * Nc + (size_t)k * Nc + n] : 0.0f;
  out[idx] = f2bf(v);
}

// ---------------- timestep MLP table: 200 x 256 (f32) --------------------------
__global__ void t_table_kernel(const float* __restrict__ W1, const float* __restrict__ b1,
                               const float* __restrict__ W2, const float* __restrict__ b2,
                               float* __restrict__ out) {
  __shared__ float s[256];
  __shared__ float a1[256];
  int r = blockIdx.x, t = threadIdx.x;
  float tv = (float)r;
  float coef = -logf(10000.0f) / 127.0f;
  int j = t & 127;
  float ang = tv * expf(coef * (float)j);
  s[t] = (t < 128) ? sinf(ang) : cosf(ang);
  __syncthreads();
  float acc = b1[t];
  for (int k = 0; k < 256; ++k) acc = fmaf(s[k], W1[k * 256 + t], acc);
  a1[t] = acc / (1.0f + expf(-acc));
  __syncthreads();
  float acc2 = b2[t];
  for (int k = 0; k < 256; ++k) acc2 = fmaf(a1[k], W2[k * 256 + t], acc2);
  out[r * 256 + t] = acc2;
}

// ---------------- cond projection: B x 256 (f32) -------------------------------
__global__ void cproj_kernel(const float* __restrict__ cv, const float* __restrict__ W,
                             const float* __restrict__ b, float* __restrict__ out, int B) {
  int i = blockIdx.x * 256 + threadIdx.x;
  if (i < B * 256) {
    int g = i >> 8, c = i & 255;
    out[i] = fmaf(cv[g * 2], W[c], fmaf(cv[g * 2 + 1], W[256 + c], b[c]));
  }
}

// ---------------- edge-feature table: 10 x 256 (f32); idx = bond*2 + mask ------
__global__ void ef_tab_kernel(const float* __restrict__ bond_emb, const float* __restrict__ emask_emb,
                              const float* __restrict__ W1, const float* __restrict__ b1,
                              const float* __restrict__ W2, const float* __restrict__ b2,
                              float* __restrict__ out) {
  __shared__ float ein[72];
  __shared__ float a1[256];
  int bidx = blockIdx.x;           // 0..9
  int bt = bidx >> 1, m = bidx & 1;
  int t = threadIdx.x;
  if (t < 64) ein[t] = bond_emb[bt * 64 + t];
  else if (t < 72) ein[t] = emask_emb[m * 8 + (t - 64)];
  __syncthreads();
  float acc = b1[t];
  for (int k = 0; k < 72; ++k) acc = fmaf(ein[k], W1[k * 256 + t], acc);
  a1[t] = acc / (1.0f + expf(-acc));
  __syncthreads();
  float acc2 = b2[t];
  for (int k = 0; k < 256; ++k) acc2 = fmaf(a1[k], W2[k * 256 + t], acc2);
  out[bidx * 256 + t] = acc2;
}

// ---------------- layer-0 edge table: e_feat @ e0_W -> 10 x 416 (padded) -------
__global__ void e0_tab_kernel(const float* __restrict__ eftab, const float* __restrict__ e0W,
                              float* __restrict__ out) {
  __shared__ float ef[256];
  int bidx = blockIdx.x, t = threadIdx.x;
  if (t < 256) ef[t] = eftab[bidx * 256 + t];
  __syncthreads();
  if (t < W0) {
    float acc = 0.0f;
    if (t < W0_REAL) {
      for (int k = 0; k < 256; ++k) acc = fmaf(ef[k], e0W[k * W0_REAL + t], acc);
    }
    out[bidx * W0 + t] = acc;
  }
}

// ---------------- h0 build: [N, 416] bf16 --------------------------------------
__global__ void h0_kernel(const int* __restrict__ x, const int* __restrict__ nm,
                          const int* __restrict__ tnode, const int* __restrict__ batch,
                          const float* __restrict__ atom_emb, const float* __restrict__ nmask_emb,
                          const float* __restrict__ ttab, const float* __restrict__ cproj,
                          u16* __restrict__ h0, int N) {
  int i = blockIdx.x * 256 + threadIdx.x;
  if (i >= N * W0) return;
  int n = i / W0;
  int c = i - n * W0;
  float v;
  if (c < 128)       v = atom_emb[x[n] * 128 + c];
  else if (c < 136)  v = nmask_emb[nm[n] * 8 + (c - 128)];
  else if (c < W0_REAL) {
    int cc = c - 136;
    v = ttab[tnode[n] * 256 + cc] + cproj[batch[n] * 256 + cc];
  } else v = 0.0f;
  h0[i] = f2bf(v);
}

// ---------------- CSR build ----------------------------------------------------
__global__ void deg_kernel(const int* __restrict__ dst, int* __restrict__ deg, int E) {
  int e = blockIdx.x * 256 + threadIdx.x;
  if (e < E) atomicAdd(&deg[dst[e]], 1);
}

__global__ void scan_kernel(const int* __restrict__ deg, int* __restrict__ ro,
                            int* __restrict__ cur, int n) {
  __shared__ int tmp[1024];
  __shared__ int carry;
  int tid = threadIdx.x;
  if (tid == 0) carry = 0;
  __syncthreads();
  for (int base = 0; base < n; base += 1024) {
    int i = base + tid;
    int v = (i < n) ? deg[i] : 0;
    tmp[tid] = v;
    __syncthreads();
    for (int o = 1; o < 1024; o <<= 1) {
      int t = (tid >= o) ? tmp[tid - o] : 0;
      __syncthreads();
      tmp[tid] += t;
      __syncthreads();
    }
    int c = carry;
    if (i < n) { int ex = c + tmp[tid] - v; ro[i] = ex; cur[i] = ex; }
    __syncthreads();
    if (tid == 1023) carry = c + tmp[1023];
    __syncthreads();
  }
  if (tid == 0) ro[n] = carry;
}

__global__ void fill_kernel(const int* __restrict__ src, const int* __restrict__ dst,
                            const int* __restrict__ ea, const int* __restrict__ em,
                            int* __restrict__ cur, int* __restrict__ csr, int E) {
  int e = blockIdx.x * 256 + threadIdx.x;
  if (e < E) {
    int d = dst[e];
    int pos = atomicAdd(&cur[d], 1);
    csr[pos] = src[e] | ((ea[e] * 2 + em[e]) << 20);   // src < 2^20, etype in high bits
  }
}

// ---------------- aggregation + z = (1+eps)*h + sum relu(h[src]+e) -------------
__global__ void agg_z_kernel(const u16* __restrict__ h, const float* __restrict__ etab,
                             const int* __restrict__ ro, const int* __restrict__ csr,
                             const float* __restrict__ epsp, u16* __restrict__ z, int W) {
  int n = blockIdx.x;
  int s0 = ro[n], s1 = ro[n + 1];
  float eps1 = 1.0f + *epsp;
  for (int c = threadIdx.x; c < W; c += 256) {
    float acc = 0.0f;
    for (int j = s0; j < s1; ++j) {
      int p = csr[j];
      int s = p & 0xFFFFF;
      int et = p >> 20;
      float v = bf2f(h[(size_t)s * W + c]) + etab[et * W + c];
      acc += fmaxf(v, 0.0f);
    }
    float zz = eps1 * bf2f(h[(size_t)n * W + c]) + acc;
    z[(size_t)n * W + c] = f2bf(zz);
  }
}

// ---------------- bf16 MFMA GEMM: C[M,256] = silu(((A@B)+bias)*scale+shift) ----
// A: [M,K] bf16 row-major;  BT: [256,K] bf16 (B transposed);  scale==null -> 1/0
__device__ __forceinline__ void g2l16(const u16* g, u16* l) {
  __builtin_amdgcn_global_load_lds(
      (__attribute__((address_space(1))) u32*)g,
      (__attribute__((address_space(3))) u32*)l, 16, 0, 0);
}

__global__ __launch_bounds__(256) void gemm_fused(
    const u16* __restrict__ A, const u16* __restrict__ BT,
    const float* __restrict__ bias, const float* __restrict__ scale,
    const float* __restrict__ shift, u16* __restrict__ C, int M, int K) {
  __shared__ __align__(16) u16 lA[128 * 32];
  __shared__ __align__(16) u16 lB[128 * 32];
  int tid = threadIdx.x;
  int wid = tid >> 6, lane = tid & 63;
  int q = lane >> 4, rr = lane & 15;
  int wm = wid >> 1, wn = wid & 1;
  int m0 = blockIdx.x * 128, n0 = blockIdx.y * 128;

  f32x4 acc[4][4] = {};

  int arow = tid >> 2;            // 0..63
  int acol = (tid & 3) * 8;       // bf16 element offset within 32-wide k tile

  for (int k0 = 0; k0 < K; k0 += 32) {
#pragma unroll
    for (int p = 0; p < 2; ++p) {
      int gr = m0 + p * 64 + arow;
      if (gr >= M) gr = M - 1;                       // clamp (results masked on store)
      g2l16(A + (size_t)gr * K + k0 + acol, &lA[p * 2048 + wid * 512]);
      int br = n0 + p * 64 + arow;                   // always < 256
      g2l16(BT + (size_t)br * K + k0 + acol, &lB[p * 2048 + wid * 512]);
    }
    __syncthreads();
    bf16x8 af[4], bfr[4];
#pragma unroll
    for (int mt = 0; mt < 4; ++mt)
      af[mt] = *(const bf16x8*)&lA[(wm * 64 + mt * 16 + rr) * 32 + q * 8];
#pragma unroll
    for (int nt = 0; nt < 4; ++nt)
      bfr[nt] = *(const bf16x8*)&lB[(wn * 64 + nt * 16 + rr) * 32 + q * 8];
#pragma unroll
    for (int mt = 0; mt < 4; ++mt)
#pragma unroll
      for (int nt = 0; nt < 4; ++nt)
        acc[mt][nt] = __builtin_amdgcn_mfma_f32_16x16x32_bf16(af[mt], bfr[nt], acc[mt][nt], 0, 0, 0);
    __syncthreads();
  }

#pragma unroll
  for (int nt = 0; nt < 4; ++nt) {
    int c = n0 + wn * 64 + nt * 16 + rr;
    float b = bias[c];
    float sc = scale ? scale[c] * 0.9999950000374997f : 1.0f;   // gamma/sqrt(1+1e-5)
    float sh = shift ? shift[c] : 0.0f;
#pragma unroll
    for (int mt = 0; mt < 4; ++mt) {
      int rbase = m0 + wm * 64 + mt * 16 + q * 4;
#pragma unroll
      for (int r2 = 0; r2 < 4; ++r2) {
        int row = rbase + r2;
        if (row < M) {
          float y = (acc[mt][nt][r2] + b) * sc + sh;
          C[(size_t)row * 256 + c] = f2bf(siluf(y));
        }
      }
    }
  }
}

// ---------------- heads --------------------------------------------------------
__global__ void atom_head(const u16* __restrict__ h, const float* __restrict__ W,
                          const float* __restrict__ b, float* __restrict__ out, int N) {
  __shared__ __align__(16) u16 hr[16 * 256];
  __shared__ __align__(16) float wb[256 * 16];
  int tid = threadIdx.x;
  int nb = blockIdx.x * 16;
  int nrows = min(16, N - nb);
  for (int i = tid; i < nrows * 32; i += 256)           // 16B chunks
    ((uint4*)hr)[i] = ((const uint4*)(h + (size_t)nb * 256))[i];
  for (int i = tid; i < 1024; i += 256)                 // 256*16 floats
    ((uint4*)wb)[i] = ((const uint4*)W)[i];
  __syncthreads();
  int nl = tid >> 4, c = tid & 15;
  if (nl < nrows) {
    float acc = b[c];
    for (int k = 0; k < 256; ++k) acc = fmaf(bf2f(hr[nl * 256 + k]), wb[k * 16 + c], acc);
    out[(size_t)(nb + nl) * 16 + c] = acc;
  }
}

__global__ void bond_head(const u16* __restrict__ h, const int* __restrict__ src,
                          const int* __restrict__ dst, const float* __restrict__ W,
                          const float* __restrict__ b, float* __restrict__ out, int E) {
  int wid = threadIdx.x >> 6, lane = threadIdx.x & 63;
  int e = blockIdx.x * 4 + wid;
  if (e >= E) return;
  int s = src[e], d = dst[e];
  uint2 va = *(const uint2*)(h + (size_t)s * 256 + lane * 4);
  uint2 vb = *(const uint2*)(h + (size_t)d * 256 + lane * 4);
  float e0 = bf2f((u16)(va.x & 0xFFFF)) + bf2f((u16)(vb.x & 0xFFFF));
  float e1 = bf2f((u16)(va.x >> 16))   + bf2f((u16)(vb.x >> 16));
  float e2 = bf2f((u16)(va.y & 0xFFFF)) + bf2f((u16)(vb.y & 0xFFFF));
  float e3 = bf2f((u16)(va.y >> 16))   + bf2f((u16)(vb.y >> 16));
  int k0 = lane * 4;
  float p[5];
#pragma unroll
  for (int o = 0; o < 5; ++o)
    p[o] = e0 * W[(k0 + 0) * 5 + o] + e1 * W[(k0 + 1) * 5 + o]
         + e2 * W[(k0 + 2) * 5 + o] + e3 * W[(k0 + 3) * 5 + o];
#pragma unroll
  for (int o = 0; o < 5; ++o)
    for (int sh2 = 32; sh2 > 0; sh2 >>= 1) p[o] += __shfl_down(p[o], sh2);
  if (lane == 0) {
#pragma unroll
    for (int o = 0; o < 5; ++o) out[(size_t)e * 5 + o] = p[o] + b[o];
  }
}

// ---------------- host ---------------------------------------------------------
extern "C" void kernel_launch(void* const* d_in, const int* in_sizes, int n_in,
                              void* d_out, int out_size, void* d_ws, size_t ws_size,
                              hipStream_t stream) {
  const int*   x_noisy   = (const int*)d_in[0];
  const int*   nmaskobs  = (const int*)d_in[1];
  const int*   ea        = (const int*)d_in[2];
  const int*   em        = (const int*)d_in[3];
  const int*   eidx      = (const int*)d_in[4];
  const int*   tnode     = (const int*)d_in[5];
  const float* cvec      = (const float*)d_in[6];
  const int*   batch     = (const int*)d_in[7];
  const float* atom_emb  = (const float*)d_in[8];
  const float* bond_emb  = (const float*)d_in[9];
  const float* nmask_emb = (const float*)d_in[10];
  const float* emask_emb = (const float*)d_in[11];
  const float* t_W1      = (const float*)d_in[12];
  const float* t_b1      = (const float*)d_in[13];
  const float* t_W2      = (const float*)d_in[14];
  const float* t_b2      = (const float*)d_in[15];
  const float* cond_W    = (const float*)d_in[16];
  const float* cond_b    = (const float*)d_in[17];
  const float* edge_W1   = (const float*)d_in[18];
  const float* edge_b1   = (const float*)d_in[19];
  const float* edge_W2   = (const float*)d_in[20];
  const float* edge_b2   = (const float*)d_in[21];
  const float* e0_W      = (const float*)d_in[22];
  const float* conv0_W1  = (const float*)d_in[23];
  const float* conv0_b1  = (const float*)d_in[24];
  const float* conv0_W2  = (const float*)d_in[25];
  const float* conv0_b2  = (const float*)d_in[26];
  const float* conv0_eps = (const float*)d_in[27];
  const float* convs_W1  = (const float*)d_in[28];
  const float* convs_b1  = (const float*)d_in[29];
  const float* convs_W2  = (const float*)d_in[30];
  const float* convs_b2  = (const float*)d_in[31];
  const float* convs_eps = (const float*)d_in[32];
  const float* bn_gamma  = (const float*)d_in[33];
  const float* bn_beta   = (const float*)d_in[34];
  const float* atom_W    = (const float*)d_in[35];
  const float* atom_b    = (const float*)d_in[36];
  const float* bond_W    = (const float*)d_in[37];
  const float* bond_b    = (const float*)d_in[38];

  const int N = in_sizes[0];
  const int E = in_sizes[2];
  const int B = in_sizes[6] / 2;
  const int* srcp = eidx;
  const int* dstp = eidx + E;

  char* base = (char*)d_ws;
  size_t off = 0;
  auto alloc = [&](size_t bytes) -> char* {
    char* p = base + off;
    off = (off + bytes + 255) & ~(size_t)255;
    return p;
  };
  u16* h0   = (u16*)alloc((size_t)N * W0 * 2);     // reused as h [N,256] after layer 0
  u16* z0   = (u16*)alloc((size_t)N * W0 * 2);     // reused as z [N,256]
  u16* ubuf = (u16*)alloc((size_t)N * DM * 2);
  u16* w10t = (u16*)alloc((size_t)DM * W0 * 2);
  u16* w20t = (u16*)alloc((size_t)DM * DM * 2);
  u16* wc1t = (u16*)alloc((size_t)5 * DM * DM * 2);
  u16* wc2t = (u16*)alloc((size_t)5 * DM * DM * 2);
  float* ttab  = (float*)alloc((size_t)200 * DM * 4);
  float* cprojb= (float*)alloc((size_t)B * DM * 4);
  float* eftab = (float*)alloc((size_t)10 * DM * 4);
  float* e0tab = (float*)alloc((size_t)10 * W0 * 4);
  int* deg = (int*)alloc((size_t)N * 4);
  int* ro  = (int*)alloc((size_t)(N + 1) * 4);
  int* cur = (int*)alloc((size_t)N * 4);
  int* csr = (int*)alloc((size_t)E * 4);
  (void)ws_size; (void)n_in; (void)out_size;

  u16* hbuf = h0;
  u16* zbuf = z0;
  float* atom_out = (float*)d_out;
  float* bond_out = atom_out + (size_t)N * 16;

  hipMemsetAsync(deg, 0, (size_t)N * 4, stream);

  // precompute: weights (transposed bf16), tables
  wT_kernel<<<(DM * W0 + 255) / 256, 256, 0, stream>>>(conv0_W1, w10t, 1, W0_REAL, W0, DM);
  wT_kernel<<<(DM * DM + 255) / 256, 256, 0, stream>>>(conv0_W2, w20t, 1, DM, DM, DM);
  wT_kernel<<<(5 * DM * DM + 255) / 256, 256, 0, stream>>>(convs_W1, wc1t, 5, DM, DM, DM);
  wT_kernel<<<(5 * DM * DM + 255) / 256, 256, 0, stream>>>(convs_W2, wc2t, 5, DM, DM, DM);
  t_table_kernel<<<200, 256, 0, stream>>>(t_W1, t_b1, t_W2, t_b2, ttab);
  cproj_kernel<<<(B * DM + 255) / 256, 256, 0, stream>>>(cvec, cond_W, cond_b, cprojb, B);
  ef_tab_kernel<<<10, 256, 0, stream>>>(bond_emb, emask_emb, edge_W1, edge_b1, edge_W2, edge_b2, eftab);
  e0_tab_kernel<<<10, 512, 0, stream>>>(eftab, e0_W, e0tab);
  h0_kernel<<<(N * W0 + 255) / 256, 256, 0, stream>>>(x_noisy, nmaskobs, tnode, batch,
      atom_emb, nmask_emb, ttab, cprojb, h0, N);
  // CSR by dst
  deg_kernel<<<(E + 255) / 256, 256, 0, stream>>>(dstp, deg, E);
  scan_kernel<<<1, 1024, 0, stream>>>(deg, ro, cur, N);
  fill_kernel<<<(E + 255) / 256, 256, 0, stream>>>(srcp, dstp, ea, em, cur, csr, E);

  dim3 ggrid((N + 127) / 128, 2);
  // layer 0
  agg_z_kernel<<<N, 256, 0, stream>>>(h0, e0tab, ro, csr, conv0_eps, z0, W0);
  gemm_fused<<<ggrid, 256, 0, stream>>>(z0, w10t, conv0_b1, nullptr, nullptr, ubuf, N, W0);
  gemm_fused<<<ggrid, 256, 0, stream>>>(ubuf, w20t, conv0_b2, bn_gamma, bn_beta, hbuf, N, DM);
  // layers 1..5
  for (int i = 0; i < 5; ++i) {
    agg_z_kernel<<<N, 256, 0, stream>>>(hbuf, eftab, ro, csr, convs_eps + i, zbuf, DM);
    gemm_fused<<<ggrid, 256, 0, stream>>>(zbuf, wc1t + (size_t)i * DM * DM, convs_b1 + i * DM,
                                          nullptr, nullptr, ubuf, N, DM);
    gemm_fused<<<ggrid, 256, 0, stream>>>(ubuf, wc2t + (size_t)i * DM * DM, convs_b2 + i * DM,
                                          bn_gamma + (i + 1) * DM, bn_beta + (i + 1) * DM, hbuf, N, DM);
  }
  // heads
  atom_head<<<(N + 15) / 16, 256, 0, stream>>>(hbuf, atom_W, atom_b, atom_out, N);
  bond_head<<<(E + 3) / 4, 256, 0, stream>>>(hbuf, srcp, dstp, bond_W, bond_b, bond_out, E);
}

// Round 2
// 1035.991 us; speedup vs baseline: 1.3325x; 1.3325x over previous
//
#include <hip/hip_runtime.h>
#include <cstdint>
#include <cmath>

typedef unsigned short u16;
typedef unsigned int   u32;

using bf16x8 = __attribute__((ext_vector_type(8))) short;
using f32x4  = __attribute__((ext_vector_type(4))) float;

#define DM 256        // d_model
#define W0 416        // layer-0 input width padded 392 -> 416 (multiple of 32)
#define W0_REAL 392

__device__ __forceinline__ float bf2f(u16 v) {
  union { u32 u; float f; } c; c.u = ((u32)v) << 16; return c.f;
}
__device__ __forceinline__ u16 f2bf(float f) {
  union { float f; u32 u; } c; c.f = f;
  u32 u = c.u;
  return (u16)((u + 0x7FFFu + ((u >> 16) & 1u)) >> 16);  // RNE
}
__device__ __forceinline__ float siluf(float y) {
  return y / (1.0f + __expf(-y));
}

// ---------------- weight transpose + bf16 convert: out[n*Kpad+k] = W[k*Nc+n] ----
__global__ void wT_kernel(const float* __restrict__ W, u16* __restrict__ out,
                          int nmat, int K, int Kpad, int Nc) {
  int idx = blockIdx.x * 256 + threadIdx.x;
  int tot = nmat * Nc * Kpad;
  if (idx >= tot) return;
  int m = idx / (Nc * Kpad);
  int r = idx - m * (Nc * Kpad);
  int n = r / Kpad;
  int k = r - n * Kpad;
  float v = (k < K) ? W[(size_t)m * K * Nc + (size_t)k * Nc + n] : 0.0f;
  out[idx] = f2bf(v);
}

// ---------------- timestep MLP table: 200 x 256 (f32) --------------------------
__global__ void t_table_kernel(const float* __restrict__ W1, const float* __restrict__ b1,
                               const float* __restrict__ W2, const float* __restrict__ b2,
                               float* __restrict__ out) {
  __shared__ float s[256];
  __shared__ float a1[256];
  int r = blockIdx.x, t = threadIdx.x;
  float tv = (float)r;
  float coef = -logf(10000.0f) / 127.0f;
  int j = t & 127;
  float ang = tv * expf(coef * (float)j);
  s[t] = (t < 128) ? sinf(ang) : cosf(ang);
  __syncthreads();
  float acc = b1[t];
  for (int k = 0; k < 256; ++k) acc = fmaf(s[k], W1[k * 256 + t], acc);
  a1[t] = acc / (1.0f + expf(-acc));
  __syncthreads();
  float acc2 = b2[t];
  for (int k = 0; k < 256; ++k) acc2 = fmaf(a1[k], W2[k * 256 + t], acc2);
  out[r * 256 + t] = acc2;
}

// ---------------- cond projection: B x 256 (f32) -------------------------------
__global__ void cproj_kernel(const float* __restrict__ cv, const float* __restrict__ W,
                             const float* __restrict__ b, float* __restrict__ out, int B) {
  int i = blockIdx.x * 256 + threadIdx.x;
  if (i < B * 256) {
    int g = i >> 8, c = i & 255;
    out[i] = fmaf(cv[g * 2], W[c], fmaf(cv[g * 2 + 1], W[256 + c], b[c]));
  }
}

// ---------------- edge-feature table: 10 x 256 (f32); idx = bond*2 + mask ------
__global__ void ef_tab_kernel(const float* __restrict__ bond_emb, const float* __restrict__ emask_emb,
                              const float* __restrict__ W1, const float* __restrict__ b1,
                              const float* __restrict__ W2, const float* __restrict__ b2,
                              float* __restrict__ out) {
  __shared__ float ein[72];
  __shared__ float a1[256];
  int bidx = blockIdx.x;           // 0..9
  int bt = bidx >> 1, m = bidx & 1;
  int t = threadIdx.x;
  if (t < 64) ein[t] = bond_emb[bt * 64 + t];
  else if (t < 72) ein[t] = emask_emb[m * 8 + (t - 64)];
  __syncthreads();
  float acc = b1[t];
  for (int k = 0; k < 72; ++k) acc = fmaf(ein[k], W1[k * 256 + t], acc);
  a1[t] = acc / (1.0f + expf(-acc));
  __syncthreads();
  float acc2 = b2[t];
  for (int k = 0; k < 256; ++k) acc2 = fmaf(a1[k], W2[k * 256 + t], acc2);
  out[bidx * 256 + t] = acc2;
}

// ---------------- layer-0 edge table: e_feat @ e0_W -> 10 x 416 (padded) -------
__global__ void e0_tab_kernel(const float* __restrict__ eftab, const float* __restrict__ e0W,
                              float* __restrict__ out) {
  __shared__ float ef[256];
  int bidx = blockIdx.x, t = threadIdx.x;
  if (t < 256) ef[t] = eftab[bidx * 256 + t];
  __syncthreads();
  if (t < W0) {
    float acc = 0.0f;
    if (t < W0_REAL) {
      for (int k = 0; k < 256; ++k) acc = fmaf(ef[k], e0W[k * W0_REAL + t], acc);
    }
    out[bidx * W0 + t] = acc;
  }
}

// ---------------- h0 build: [N, 416] bf16 --------------------------------------
__global__ void h0_kernel(const int* __restrict__ x, const int* __restrict__ nm,
                          const int* __restrict__ tnode, const int* __restrict__ batch,
                          const float* __restrict__ atom_emb, const float* __restrict__ nmask_emb,
                          const float* __restrict__ ttab, const float* __restrict__ cproj,
                          u16* __restrict__ h0, int N) {
  int i = blockIdx.x * 256 + threadIdx.x;
  if (i >= N * W0) return;
  int n = i / W0;
  int c = i - n * W0;
  float v;
  if (c < 128)       v = atom_emb[x[n] * 128 + c];
  else if (c < 136)  v = nmask_emb[nm[n] * 8 + (c - 128)];
  else if (c < W0_REAL) {
    int cc = c - 136;
    v = ttab[tnode[n] * 256 + cc] + cproj[batch[n] * 256 + cc];
  } else v = 0.0f;
  h0[i] = f2bf(v);
}

// ---------------- CSR build ----------------------------------------------------
__global__ void deg_kernel(const int* __restrict__ dst, int* __restrict__ deg, int E) {
  int e = blockIdx.x * 256 + threadIdx.x;
  if (e < E) atomicAdd(&deg[dst[e]], 1);
}

// 3-kernel scan: per-block exclusive scan + block sums, scan sums, add offsets
__global__ void scan1_kernel(const int* __restrict__ deg, int* __restrict__ ro,
                             int* __restrict__ bsum, int N) {
  __shared__ int tmp[256];
  int tid = threadIdx.x, i = blockIdx.x * 256 + tid;
  int v = (i < N) ? deg[i] : 0;
  tmp[tid] = v;
  __syncthreads();
  for (int o = 1; o < 256; o <<= 1) {
    int t = (tid >= o) ? tmp[tid - o] : 0;
    __syncthreads();
    tmp[tid] += t;
    __syncthreads();
  }
  if (i < N) ro[i] = tmp[tid] - v;     // exclusive within block
  if (tid == 255) bsum[blockIdx.x] = tmp[255];
}

__global__ void scan2_kernel(int* __restrict__ bsum, int nb) {
  __shared__ int tmp[256];
  int tid = threadIdx.x;
  int v = (tid < nb) ? bsum[tid] : 0;
  tmp[tid] = v;
  __syncthreads();
  for (int o = 1; o < 256; o <<= 1) {
    int t = (tid >= o) ? tmp[tid - o] : 0;
    __syncthreads();
    tmp[tid] += t;
    __syncthreads();
  }
  if (tid < nb) bsum[tid] = tmp[tid] - v;   // exclusive block offsets
}

__global__ void scan3_kernel(int* __restrict__ ro, int* __restrict__ cur,
                             const int* __restrict__ bsum, int N, int E) {
  int i = blockIdx.x * 256 + threadIdx.x;
  if (i < N) {
    int r = ro[i] + bsum[blockIdx.x];
    ro[i] = r;
    cur[i] = r;
  }
  if (i == 0) ro[N] = E;
}

__global__ void fill_kernel(const int* __restrict__ src, const int* __restrict__ dst,
                            const int* __restrict__ ea, const int* __restrict__ em,
                            int* __restrict__ cur, int* __restrict__ csr, int E) {
  int e = blockIdx.x * 256 + threadIdx.x;
  if (e < E) {
    int d = dst[e];
    int pos = atomicAdd(&cur[d], 1);
    csr[pos] = src[e] | ((ea[e] * 2 + em[e]) << 20);   // src < 2^20, etype in high bits
  }
}

// ---------------- aggregation + z = (1+eps)*h + sum relu(h[src]+e) -------------
// One WAVE per node (4 nodes / 256-thread block). Lane owns 4 columns (uint2).
// CSR entries are loaded once per 64-chunk coalesced and broadcast via shfl.
// Edge loop unrolled x2 so each wave keeps 2 independent 512B gathers in flight.
__global__ __launch_bounds__(256) void agg_z_kernel(
    const u16* __restrict__ h, const float* __restrict__ etab,
    const int* __restrict__ ro, const int* __restrict__ csr,
    const float* __restrict__ epsp, u16* __restrict__ z, int N, int W) {
  int wid = threadIdx.x >> 6, lane = threadIdx.x & 63;
  int n = blockIdx.x * 4 + wid;
  if (n >= N) return;
  int s0 = ro[n], s1 = ro[n + 1];
  float eps1 = 1.0f + *epsp;

  for (int cbase = 0; cbase < W; cbase += 256) {
    int c4 = cbase + lane * 4;
    bool live = (c4 < W);                 // W is a multiple of 4
    int c4c = live ? c4 : (W - 4);        // clamp for harmless loads
    float a0 = 0.f, a1 = 0.f, a2 = 0.f, a3 = 0.f;

    for (int base = s0; base < s1; base += 64) {
      int m = s1 - base; if (m > 64) m = 64;
      int pk = (lane < m) ? csr[base + lane] : 0;
      int j = 0;
      for (; j + 1 < m; j += 2) {
        int pa = __shfl(pk, j);
        int pb = __shfl(pk, j + 1);
        int sa = pa & 0xFFFFF, ea_ = pa >> 20;
        int sb = pb & 0xFFFFF, eb_ = pb >> 20;
        uint2 ha = *(const uint2*)(h + (size_t)sa * W + c4c);
        uint2 hb = *(const uint2*)(h + (size_t)sb * W + c4c);
        float4 va = *(const float4*)(etab + (size_t)ea_ * W + c4c);
        float4 vb = *(const float4*)(etab + (size_t)eb_ * W + c4c);
        a0 += fmaxf(bf2f((u16)(ha.x & 0xFFFF)) + va.x, 0.f);
        a1 += fmaxf(bf2f((u16)(ha.x >> 16))    + va.y, 0.f);
        a2 += fmaxf(bf2f((u16)(ha.y & 0xFFFF)) + va.z, 0.f);
        a3 += fmaxf(bf2f((u16)(ha.y >> 16))    + va.w, 0.f);
        a0 += fmaxf(bf2f((u16)(hb.x & 0xFFFF)) + vb.x, 0.f);
        a1 += fmaxf(bf2f((u16)(hb.x >> 16))    + vb.y, 0.f);
        a2 += fmaxf(bf2f((u16)(hb.y & 0xFFFF)) + vb.z, 0.f);
        a3 += fmaxf(bf2f((u16)(hb.y >> 16))    + vb.w, 0.f);
      }
      if (j < m) {
        int pa = __shfl(pk, j);
        int sa = pa & 0xFFFFF, ea_ = pa >> 20;
        uint2 ha = *(const uint2*)(h + (size_t)sa * W + c4c);
        float4 va = *(const float4*)(etab + (size_t)ea_ * W + c4c);
        a0 += fmaxf(bf2f((u16)(ha.x & 0xFFFF)) + va.x, 0.f);
        a1 += fmaxf(bf2f((u16)(ha.x >> 16))    + va.y, 0.f);
        a2 += fmaxf(bf2f((u16)(ha.y & 0xFFFF)) + va.z, 0.f);
        a3 += fmaxf(bf2f((u16)(ha.y >> 16))    + va.w, 0.f);
      }
    }

    if (live) {
      uint2 hn = *(const uint2*)(h + (size_t)n * W + c4);
      float z0 = eps1 * bf2f((u16)(hn.x & 0xFFFF)) + a0;
      float z1 = eps1 * bf2f((u16)(hn.x >> 16))    + a1;
      float z2 = eps1 * bf2f((u16)(hn.y & 0xFFFF)) + a2;
      float z3 = eps1 * bf2f((u16)(hn.y >> 16))    + a3;
      uint2 o;
      o.x = (u32)f2bf(z0) | ((u32)f2bf(z1) << 16);
      o.y = (u32)f2bf(z2) | ((u32)f2bf(z3) << 16);
      *(uint2*)(z + (size_t)n * W + c4) = o;
    }
  }
}

// ---------------- bf16 MFMA GEMM: C[M,256] = silu(((A@B)+bias)*scale+shift) ----
__device__ __forceinline__ void g2l16(const u16* g, u16* l) {
  __builtin_amdgcn_global_load_lds(
      (__attribute__((address_space(1))) u32*)g,
      (__attribute__((address_space(3))) u32*)l, 16, 0, 0);
}

__global__ __launch_bounds__(256) void gemm_fused(
    const u16* __restrict__ A, const u16* __restrict__ BT,
    const float* __restrict__ bias, const float* __restrict__ scale,
    const float* __restrict__ shift, u16* __restrict__ C, int M, int K) {
  __shared__ __align__(16) u16 lA[128 * 32];
  __shared__ __align__(16) u16 lB[128 * 32];
  int tid = threadIdx.x;
  int wid = tid >> 6, lane = tid & 63;
  int q = lane >> 4, rr = lane & 15;
  int wm = wid >> 1, wn = wid & 1;
  int m0 = blockIdx.x * 128, n0 = blockIdx.y * 128;

  f32x4 acc[4][4] = {};

  int arow = tid >> 2;            // 0..63
  int acol = (tid & 3) * 8;       // bf16 element offset within 32-wide k tile

  for (int k0 = 0; k0 < K; k0 += 32) {
#pragma unroll
    for (int p = 0; p < 2; ++p) {
      int gr = m0 + p * 64 + arow;
      if (gr >= M) gr = M - 1;                       // clamp (results masked on store)
      g2l16(A + (size_t)gr * K + k0 + acol, &lA[p * 2048 + wid * 512]);
      int br = n0 + p * 64 + arow;                   // always < 256
      g2l16(BT + (size_t)br * K + k0 + acol, &lB[p * 2048 + wid * 512]);
    }
    __syncthreads();
    bf16x8 af[4], bfr[4];
#pragma unroll
    for (int mt = 0; mt < 4; ++mt)
      af[mt] = *(const bf16x8*)&lA[(wm * 64 + mt * 16 + rr) * 32 + q * 8];
#pragma unroll
    for (int nt = 0; nt < 4; ++nt)
      bfr[nt] = *(const bf16x8*)&lB[(wn * 64 + nt * 16 + rr) * 32 + q * 8];
#pragma unroll
    for (int mt = 0; mt < 4; ++mt)
#pragma unroll
      for (int nt = 0; nt < 4; ++nt)
        acc[mt][nt] = __builtin_amdgcn_mfma_f32_16x16x32_bf16(af[mt], bfr[nt], acc[mt][nt], 0, 0, 0);
    __syncthreads();
  }

#pragma unroll
  for (int nt = 0; nt < 4; ++nt) {
    int c = n0 + wn * 64 + nt * 16 + rr;
    float b = bias[c];
    float sc = scale ? scale[c] * 0.9999950000374997f : 1.0f;   // gamma/sqrt(1+1e-5)
    float sh = shift ? shift[c] : 0.0f;
#pragma unroll
    for (int mt = 0; mt < 4; ++mt) {
      int rbase = m0 + wm * 64 + mt * 16 + q * 4;
#pragma unroll
      for (int r2 = 0; r2 < 4; ++r2) {
        int row = rbase + r2;
        if (row < M) {
          float y = (acc[mt][nt][r2] + b) * sc + sh;
          C[(size_t)row * 256 + c] = f2bf(siluf(y));
        }
      }
    }
  }
}

// ---------------- heads --------------------------------------------------------
__global__ void atom_head(const u16* __restrict__ h, const float* __restrict__ W,
                          const float* __restrict__ b, float* __restrict__ out, int N) {
  __shared__ __align__(16) u16 hr[16 * 256];
  __shared__ __align__(16) float wb[256 * 16];
  int tid = threadIdx.x;
  int nb = blockIdx.x * 16;
  int nrows = min(16, N - nb);
  for (int i = tid; i < nrows * 32; i += 256)           // 16B chunks
    ((uint4*)hr)[i] = ((const uint4*)(h + (size_t)nb * 256))[i];
  for (int i = tid; i < 1024; i += 256)                 // 256*16 floats
    ((uint4*)wb)[i] = ((const uint4*)W)[i];
  __syncthreads();
  int nl = tid >> 4, c = tid & 15;
  if (nl < nrows) {
    float acc = b[c];
    for (int k = 0; k < 256; ++k) acc = fmaf(bf2f(hr[nl * 256 + k]), wb[k * 16 + c], acc);
    out[(size_t)(nb + nl) * 16 + c] = acc;
  }
}

__global__ void bond_head(const u16* __restrict__ h, const int* __restrict__ src,
                          const int* __restrict__ dst, const float* __restrict__ W,
                          const float* __restrict__ b, float* __restrict__ out, int E) {
  int wid = threadIdx.x >> 6, lane = threadIdx.x & 63;
  int e = blockIdx.x * 4 + wid;
  if (e >= E) return;
  int s = src[e], d = dst[e];
  uint2 va = *(const uint2*)(h + (size_t)s * 256 + lane * 4);
  uint2 vb = *(const uint2*)(h + (size_t)d * 256 + lane * 4);
  float e0 = bf2f((u16)(va.x & 0xFFFF)) + bf2f((u16)(vb.x & 0xFFFF));
  float e1 = bf2f((u16)(va.x >> 16))   + bf2f((u16)(vb.x >> 16));
  float e2 = bf2f((u16)(va.y & 0xFFFF)) + bf2f((u16)(vb.y & 0xFFFF));
  float e3 = bf2f((u16)(va.y >> 16))   + bf2f((u16)(vb.y >> 16));
  int k0 = lane * 4;
  float p[5];
#pragma unroll
  for (int o = 0; o < 5; ++o)
    p[o] = e0 * W[(k0 + 0) * 5 + o] + e1 * W[(k0 + 1) * 5 + o]
         + e2 * W[(k0 + 2) * 5 + o] + e3 * W[(k0 + 3) * 5 + o];
#pragma unroll
  for (int o = 0; o < 5; ++o)
    for (int sh2 = 32; sh2 > 0; sh2 >>= 1) p[o] += __shfl_down(p[o], sh2);
  if (lane == 0) {
#pragma unroll
    for (int o = 0; o < 5; ++o) out[(size_t)e * 5 + o] = p[o] + b[o];
  }
}

// ---------------- host ---------------------------------------------------------
extern "C" void kernel_launch(void* const* d_in, const int* in_sizes, int n_in,
                              void* d_out, int out_size, void* d_ws, size_t ws_size,
                              hipStream_t stream) {
  const int*   x_noisy   = (const int*)d_in[0];
  const int*   nmaskobs  = (const int*)d_in[1];
  const int*   ea        = (const int*)d_in[2];
  const int*   em        = (const int*)d_in[3];
  const int*   eidx      = (const int*)d_in[4];
  const int*   tnode     = (const int*)d_in[5];
  const float* cvec      = (const float*)d_in[6];
  const int*   batch     = (const int*)d_in[7];
  const float* atom_emb  = (const float*)d_in[8];
  const float* bond_emb  = (const float*)d_in[9];
  const float* nmask_emb = (const float*)d_in[10];
  const float* emask_emb = (const float*)d_in[11];
  const float* t_W1      = (const float*)d_in[12];
  const float* t_b1      = (const float*)d_in[13];
  const float* t_W2      = (const float*)d_in[14];
  const float* t_b2      = (const float*)d_in[15];
  const float* cond_W    = (const float*)d_in[16];
  const float* cond_b    = (const float*)d_in[17];
  const float* edge_W1   = (const float*)d_in[18];
  const float* edge_b1   = (const float*)d_in[19];
  const float* edge_W2   = (const float*)d_in[20];
  const float* edge_b2   = (const float*)d_in[21];
  const float* e0_W      = (const float*)d_in[22];
  const float* conv0_W1  = (const float*)d_in[23];
  const float* conv0_b1  = (const float*)d_in[24];
  const float* conv0_W2  = (const float*)d_in[25];
  const float* conv0_b2  = (const float*)d_in[26];
  const float* conv0_eps = (const float*)d_in[27];
  const float* convs_W1  = (const float*)d_in[28];
  const float* convs_b1  = (const float*)d_in[29];
  const float* convs_W2  = (const float*)d_in[30];
  const float* convs_b2  = (const float*)d_in[31];
  const float* convs_eps = (const float*)d_in[32];
  const float* bn_gamma  = (const float*)d_in[33];
  const float* bn_beta   = (const float*)d_in[34];
  const float* atom_W    = (const float*)d_in[35];
  const float* atom_b    = (const float*)d_in[36];
  const float* bond_W    = (const float*)d_in[37];
  const float* bond_b    = (const float*)d_in[38];

  const int N = in_sizes[0];
  const int E = in_sizes[2];
  const int B = in_sizes[6] / 2;
  const int* srcp = eidx;
  const int* dstp = eidx + E;

  char* base = (char*)d_ws;
  size_t off = 0;
  auto alloc = [&](size_t bytes) -> char* {
    char* p = base + off;
    off = (off + bytes + 255) & ~(size_t)255;
    return p;
  };
  u16* h0   = (u16*)alloc((size_t)N * W0 * 2);     // reused as h [N,256] after layer 0
  u16* z0   = (u16*)alloc((size_t)N * W0 * 2);     // reused as z [N,256]
  u16* ubuf = (u16*)alloc((size_t)N * DM * 2);
  u16* w10t = (u16*)alloc((size_t)DM * W0 * 2);
  u16* w20t = (u16*)alloc((size_t)DM * DM * 2);
  u16* wc1t = (u16*)alloc((size_t)5 * DM * DM * 2);
  u16* wc2t = (u16*)alloc((size_t)5 * DM * DM * 2);
  float* ttab  = (float*)alloc((size_t)200 * DM * 4);
  float* cprojb= (float*)alloc((size_t)B * DM * 4);
  float* eftab = (float*)alloc((size_t)10 * DM * 4);
  float* e0tab = (float*)alloc((size_t)10 * W0 * 4);
  int* deg  = (int*)alloc((size_t)N * 4);
  int* ro   = (int*)alloc((size_t)(N + 1) * 4);
  int* cur  = (int*)alloc((size_t)N * 4);
  int* csr  = (int*)alloc((size_t)E * 4);
  int* bsum = (int*)alloc((size_t)256 * 4);
  (void)ws_size; (void)n_in; (void)out_size;

  u16* hbuf = h0;
  u16* zbuf = z0;
  float* atom_out = (float*)d_out;
  float* bond_out = atom_out + (size_t)N * 16;

  hipMemsetAsync(deg, 0, (size_t)N * 4, stream);

  // precompute: weights (transposed bf16), tables
  wT_kernel<<<(DM * W0 + 255) / 256, 256, 0, stream>>>(conv0_W1, w10t, 1, W0_REAL, W0, DM);
  wT_kernel<<<(DM * DM + 255) / 256, 256, 0, stream>>>(conv0_W2, w20t, 1, DM, DM, DM);
  wT_kernel<<<(5 * DM * DM + 255) / 256, 256, 0, stream>>>(convs_W1, wc1t, 5, DM, DM, DM);
  wT_kernel<<<(5 * DM * DM + 255) / 256, 256, 0, stream>>>(convs_W2, wc2t, 5, DM, DM, DM);
  t_table_kernel<<<200, 256, 0, stream>>>(t_W1, t_b1, t_W2, t_b2, ttab);
  cproj_kernel<<<(B * DM + 255) / 256, 256, 0, stream>>>(cvec, cond_W, cond_b, cprojb, B);
  ef_tab_kernel<<<10, 256, 0, stream>>>(bond_emb, emask_emb, edge_W1, edge_b1, edge_W2, edge_b2, eftab);
  e0_tab_kernel<<<10, 512, 0, stream>>>(eftab, e0_W, e0tab);
  h0_kernel<<<(N * W0 + 255) / 256, 256, 0, stream>>>(x_noisy, nmaskobs, tnode, batch,
      atom_emb, nmask_emb, ttab, cprojb, h0, N);
  // CSR by dst
  const int nscan = (N + 255) / 256;
  deg_kernel<<<(E + 255) / 256, 256, 0, stream>>>(dstp, deg, E);
  scan1_kernel<<<nscan, 256, 0, stream>>>(deg, ro, bsum, N);
  scan2_kernel<<<1, 256, 0, stream>>>(bsum, nscan);
  scan3_kernel<<<nscan, 256, 0, stream>>>(ro, cur, bsum, N, E);
  fill_kernel<<<(E + 255) / 256, 256, 0, stream>>>(srcp, dstp, ea, em, cur, csr, E);

  dim3 ggrid((N + 127) / 128, 2);
  const int nagg = (N + 3) / 4;
  // layer 0
  agg_z_kernel<<<nagg, 256, 0, stream>>>(h0, e0tab, ro, csr, conv0_eps, z0, N, W0);
  gemm_fused<<<ggrid, 256, 0, stream>>>(z0, w10t, conv0_b1, nullptr, nullptr, ubuf, N, W0);
  gemm_fused<<<ggrid, 256, 0, stream>>>(ubuf, w20t, conv0_b2, bn_gamma, bn_beta, hbuf, N, DM);
  // layers 1..5
  for (int i = 0; i < 5; ++i) {
    agg_z_kernel<<<nagg, 256, 0, stream>>>(hbuf, eftab, ro, csr, convs_eps + i, zbuf, N, DM);
    gemm_fused<<<ggrid, 256, 0, stream>>>(zbuf, wc1t + (size_t)i * DM * DM, convs_b1 + i * DM,
                                          nullptr, nullptr, ubuf, N, DM);
    gemm_fused<<<ggrid, 256, 0, stream>>>(ubuf, wc2t + (size_t)i * DM * DM, convs_b2 + i * DM,
                                          bn_gamma + (i + 1) * DM, bn_beta + (i + 1) * DM, hbuf, N, DM);
  }
  // heads
  atom_head<<<(N + 15) / 16, 256, 0, stream>>>(hbuf, atom_W, atom_b, atom_out, N);
  bond_head<<<(E + 3) / 4, 256, 0, stream>>>(hbuf, srcp, dstp, bond_W, bond_b, bond_out, E);
}

// Round 3
// 1011.958 us; speedup vs baseline: 1.3642x; 1.0237x over previous
//
#include <hip/hip_runtime.h>
#include <cstdint>
#include <cmath>

typedef unsigned short u16;
typedef unsigned int   u32;

using bf16x8 = __attribute__((ext_vector_type(8))) short;
using f32x4  = __attribute__((ext_vector_type(4))) float;

#define DM 256        // d_model
#define W0 416        // layer-0 input width padded 392 -> 416 (multiple of 32)
#define W0_REAL 392

__device__ __forceinline__ float bf2f(u16 v) {
  union { u32 u; float f; } c; c.u = ((u32)v) << 16; return c.f;
}
__device__ __forceinline__ u16 f2bf(float f) {
  union { float f; u32 u; } c; c.f = f;
  u32 u = c.u;
  return (u16)((u + 0x7FFFu + ((u >> 16) & 1u)) >> 16);  // RNE
}
__device__ __forceinline__ float siluf(float y) {
  return y / (1.0f + __expf(-y));
}

// ---------------- weight transpose + bf16 convert: out[n*Kpad+k] = W[k*Nc+n] ----
__global__ void wT_kernel(const float* __restrict__ W, u16* __restrict__ out,
                          int nmat, int K, int Kpad, int Nc) {
  int idx = blockIdx.x * 256 + threadIdx.x;
  int tot = nmat * Nc * Kpad;
  if (idx >= tot) return;
  int m = idx / (Nc * Kpad);
  int r = idx - m * (Nc * Kpad);
  int n = r / Kpad;
  int k = r - n * Kpad;
  float v = (k < K) ? W[(size_t)m * K * Nc + (size_t)k * Nc + n] : 0.0f;
  out[idx] = f2bf(v);
}

// ---------------- timestep MLP table: 200 x 256 (f32) --------------------------
__global__ void t_table_kernel(const float* __restrict__ W1, const float* __restrict__ b1,
                               const float* __restrict__ W2, const float* __restrict__ b2,
                               float* __restrict__ out) {
  __shared__ float s[256];
  __shared__ float a1[256];
  int r = blockIdx.x, t = threadIdx.x;
  float tv = (float)r;
  float coef = -logf(10000.0f) / 127.0f;
  int j = t & 127;
  float ang = tv * expf(coef * (float)j);
  s[t] = (t < 128) ? sinf(ang) : cosf(ang);
  __syncthreads();
  float acc = b1[t];
  for (int k = 0; k < 256; ++k) acc = fmaf(s[k], W1[k * 256 + t], acc);
  a1[t] = acc / (1.0f + expf(-acc));
  __syncthreads();
  float acc2 = b2[t];
  for (int k = 0; k < 256; ++k) acc2 = fmaf(a1[k], W2[k * 256 + t], acc2);
  out[r * 256 + t] = acc2;
}

// ---------------- cond projection: B x 256 (f32) -------------------------------
__global__ void cproj_kernel(const float* __restrict__ cv, const float* __restrict__ W,
                             const float* __restrict__ b, float* __restrict__ out, int B) {
  int i = blockIdx.x * 256 + threadIdx.x;
  if (i < B * 256) {
    int g = i >> 8, c = i & 255;
    out[i] = fmaf(cv[g * 2], W[c], fmaf(cv[g * 2 + 1], W[256 + c], b[c]));
  }
}

// ---------------- edge-feature table: 10 x 256 (f32); idx = bond*2 + mask ------
__global__ void ef_tab_kernel(const float* __restrict__ bond_emb, const float* __restrict__ emask_emb,
                              const float* __restrict__ W1, const float* __restrict__ b1,
                              const float* __restrict__ W2, const float* __restrict__ b2,
                              float* __restrict__ out) {
  __shared__ float ein[72];
  __shared__ float a1[256];
  int bidx = blockIdx.x;           // 0..9
  int bt = bidx >> 1, m = bidx & 1;
  int t = threadIdx.x;
  if (t < 64) ein[t] = bond_emb[bt * 64 + t];
  else if (t < 72) ein[t] = emask_emb[m * 8 + (t - 64)];
  __syncthreads();
  float acc = b1[t];
  for (int k = 0; k < 72; ++k) acc = fmaf(ein[k], W1[k * 256 + t], acc);
  a1[t] = acc / (1.0f + expf(-acc));
  __syncthreads();
  float acc2 = b2[t];
  for (int k = 0; k < 256; ++k) acc2 = fmaf(a1[k], W2[k * 256 + t], acc2);
  out[bidx * 256 + t] = acc2;
}

// ---------------- layer-0 edge table: e_feat @ e0_W -> 10 x 416 (padded) -------
__global__ void e0_tab_kernel(const float* __restrict__ eftab, const float* __restrict__ e0W,
                              float* __restrict__ out) {
  __shared__ float ef[256];
  int bidx = blockIdx.x, t = threadIdx.x;
  if (t < 256) ef[t] = eftab[bidx * 256 + t];
  __syncthreads();
  if (t < W0) {
    float acc = 0.0f;
    if (t < W0_REAL) {
      for (int k = 0; k < 256; ++k) acc = fmaf(ef[k], e0W[k * W0_REAL + t], acc);
    }
    out[bidx * W0 + t] = acc;
  }
}

// ---------------- h0 build: [N, 416] bf16 --------------------------------------
__global__ void h0_kernel(const int* __restrict__ x, const int* __restrict__ nm,
                          const int* __restrict__ tnode, const int* __restrict__ batch,
                          const float* __restrict__ atom_emb, const float* __restrict__ nmask_emb,
                          const float* __restrict__ ttab, const float* __restrict__ cproj,
                          u16* __restrict__ h0, int N) {
  int i = blockIdx.x * 256 + threadIdx.x;
  if (i >= N * W0) return;
  int n = i / W0;
  int c = i - n * W0;
  float v;
  if (c < 128)       v = atom_emb[x[n] * 128 + c];
  else if (c < 136)  v = nmask_emb[nm[n] * 8 + (c - 128)];
  else if (c < W0_REAL) {
    int cc = c - 136;
    v = ttab[tnode[n] * 256 + cc] + cproj[batch[n] * 256 + cc];
  } else v = 0.0f;
  h0[i] = f2bf(v);
}

// ---------------- CSR build ----------------------------------------------------
__global__ void deg_kernel(const int* __restrict__ dst, int* __restrict__ deg, int E) {
  int e = blockIdx.x * 256 + threadIdx.x;
  if (e < E) atomicAdd(&deg[dst[e]], 1);
}

// 3-kernel scan: per-block exclusive scan + block sums, scan sums, add offsets
__global__ void scan1_kernel(const int* __restrict__ deg, int* __restrict__ ro,
                             int* __restrict__ bsum, int N) {
  __shared__ int tmp[256];
  int tid = threadIdx.x, i = blockIdx.x * 256 + tid;
  int v = (i < N) ? deg[i] : 0;
  tmp[tid] = v;
  __syncthreads();
  for (int o = 1; o < 256; o <<= 1) {
    int t = (tid >= o) ? tmp[tid - o] : 0;
    __syncthreads();
    tmp[tid] += t;
    __syncthreads();
  }
  if (i < N) ro[i] = tmp[tid] - v;     // exclusive within block
  if (tid == 255) bsum[blockIdx.x] = tmp[255];
}

__global__ void scan2_kernel(int* __restrict__ bsum, int nb) {
  __shared__ int tmp[256];
  int tid = threadIdx.x;
  int v = (tid < nb) ? bsum[tid] : 0;
  tmp[tid] = v;
  __syncthreads();
  for (int o = 1; o < 256; o <<= 1) {
    int t = (tid >= o) ? tmp[tid - o] : 0;
    __syncthreads();
    tmp[tid] += t;
    __syncthreads();
  }
  if (tid < nb) bsum[tid] = tmp[tid] - v;   // exclusive block offsets
}

__global__ void scan3_kernel(int* __restrict__ ro, int* __restrict__ cur,
                             const int* __restrict__ bsum, int N, int E) {
  int i = blockIdx.x * 256 + threadIdx.x;
  if (i < N) {
    int r = ro[i] + bsum[blockIdx.x];
    ro[i] = r;
    cur[i] = r;
  }
  if (i == 0) ro[N] = E;
}

__global__ void fill_kernel(const int* __restrict__ src, const int* __restrict__ dst,
                            const int* __restrict__ ea, const int* __restrict__ em,
                            int* __restrict__ cur, int* __restrict__ csr, int E) {
  int e = blockIdx.x * 256 + threadIdx.x;
  if (e < E) {
    int d = dst[e];
    int pos = atomicAdd(&cur[d], 1);
    csr[pos] = src[e] | ((ea[e] * 2 + em[e]) << 20);   // src < 2^20, etype in high bits
  }
}

// ---------------- aggregation + z = (1+eps)*h + sum relu(h[src]+e) -------------
// One WAVE per node (4 nodes / 256-thread block). Lane owns 4 columns (uint2).
__global__ __launch_bounds__(256) void agg_z_kernel(
    const u16* __restrict__ h, const float* __restrict__ etab,
    const int* __restrict__ ro, const int* __restrict__ csr,
    const float* __restrict__ epsp, u16* __restrict__ z, int N, int W) {
  int wid = threadIdx.x >> 6, lane = threadIdx.x & 63;
  int n = blockIdx.x * 4 + wid;
  if (n >= N) return;
  int s0 = ro[n], s1 = ro[n + 1];
  float eps1 = 1.0f + *epsp;

  for (int cbase = 0; cbase < W; cbase += 256) {
    int c4 = cbase + lane * 4;
    bool live = (c4 < W);                 // W is a multiple of 4
    int c4c = live ? c4 : (W - 4);        // clamp for harmless loads
    float a0 = 0.f, a1 = 0.f, a2 = 0.f, a3 = 0.f;

    for (int base = s0; base < s1; base += 64) {
      int m = s1 - base; if (m > 64) m = 64;
      int pk = (lane < m) ? csr[base + lane] : 0;
      int j = 0;
      for (; j + 1 < m; j += 2) {
        int pa = __shfl(pk, j);
        int pb = __shfl(pk, j + 1);
        int sa = pa & 0xFFFFF, ea_ = pa >> 20;
        int sb = pb & 0xFFFFF, eb_ = pb >> 20;
        uint2 ha = *(const uint2*)(h + (size_t)sa * W + c4c);
        uint2 hb = *(const uint2*)(h + (size_t)sb * W + c4c);
        float4 va = *(const float4*)(etab + (size_t)ea_ * W + c4c);
        float4 vb = *(const float4*)(etab + (size_t)eb_ * W + c4c);
        a0 += fmaxf(bf2f((u16)(ha.x & 0xFFFF)) + va.x, 0.f);
        a1 += fmaxf(bf2f((u16)(ha.x >> 16))    + va.y, 0.f);
        a2 += fmaxf(bf2f((u16)(ha.y & 0xFFFF)) + va.z, 0.f);
        a3 += fmaxf(bf2f((u16)(ha.y >> 16))    + va.w, 0.f);
        a0 += fmaxf(bf2f((u16)(hb.x & 0xFFFF)) + vb.x, 0.f);
        a1 += fmaxf(bf2f((u16)(hb.x >> 16))    + vb.y, 0.f);
        a2 += fmaxf(bf2f((u16)(hb.y & 0xFFFF)) + vb.z, 0.f);
        a3 += fmaxf(bf2f((u16)(hb.y >> 16))    + vb.w, 0.f);
      }
      if (j < m) {
        int pa = __shfl(pk, j);
        int sa = pa & 0xFFFFF, ea_ = pa >> 20;
        uint2 ha = *(const uint2*)(h + (size_t)sa * W + c4c);
        float4 va = *(const float4*)(etab + (size_t)ea_ * W + c4c);
        a0 += fmaxf(bf2f((u16)(ha.x & 0xFFFF)) + va.x, 0.f);
        a1 += fmaxf(bf2f((u16)(ha.x >> 16))    + va.y, 0.f);
        a2 += fmaxf(bf2f((u16)(ha.y & 0xFFFF)) + va.z, 0.f);
        a3 += fmaxf(bf2f((u16)(ha.y >> 16))    + va.w, 0.f);
      }
    }

    if (live) {
      uint2 hn = *(const uint2*)(h + (size_t)n * W + c4);
      float z0 = eps1 * bf2f((u16)(hn.x & 0xFFFF)) + a0;
      float z1 = eps1 * bf2f((u16)(hn.x >> 16))    + a1;
      float z2 = eps1 * bf2f((u16)(hn.y & 0xFFFF)) + a2;
      float z3 = eps1 * bf2f((u16)(hn.y >> 16))    + a3;
      uint2 o;
      o.x = (u32)f2bf(z0) | ((u32)f2bf(z1) << 16);
      o.y = (u32)f2bf(z2) | ((u32)f2bf(z3) << 16);
      *(uint2*)(z + (size_t)n * W + c4) = o;
    }
  }
}

// ---------------- bf16 MFMA GEMM: C[M,256] = silu(((A@B)+bias)*scale+shift) ----
__device__ __forceinline__ void g2l16(const u16* g, u16* l) {
  __builtin_amdgcn_global_load_lds(
      (__attribute__((address_space(1))) u32*)g,
      (__attribute__((address_space(3))) u32*)l, 16, 0, 0);
}

__global__ __launch_bounds__(256) void gemm_fused(
    const u16* __restrict__ A, const u16* __restrict__ BT,
    const float* __restrict__ bias, const float* __restrict__ scale,
    const float* __restrict__ shift, u16* __restrict__ C, int M, int K) {
  __shared__ __align__(16) u16 lA[128 * 32];
  __shared__ __align__(16) u16 lB[128 * 32];
  int tid = threadIdx.x;
  int wid = tid >> 6, lane = tid & 63;
  int q = lane >> 4, rr = lane & 15;
  int wm = wid >> 1, wn = wid & 1;
  int m0 = blockIdx.x * 128, n0 = blockIdx.y * 128;

  f32x4 acc[4][4] = {};

  int arow = tid >> 2;            // 0..63
  int acol = (tid & 3) * 8;       // bf16 element offset within 32-wide k tile

  for (int k0 = 0; k0 < K; k0 += 32) {
#pragma unroll
    for (int p = 0; p < 2; ++p) {
      int gr = m0 + p * 64 + arow;
      if (gr >= M) gr = M - 1;                       // clamp (results masked on store)
      g2l16(A + (size_t)gr * K + k0 + acol, &lA[p * 2048 + wid * 512]);
      int br = n0 + p * 64 + arow;                   // always < 256
      g2l16(BT + (size_t)br * K + k0 + acol, &lB[p * 2048 + wid * 512]);
    }
    __syncthreads();
    bf16x8 af[4], bfr[4];
#pragma unroll
    for (int mt = 0; mt < 4; ++mt)
      af[mt] = *(const bf16x8*)&lA[(wm * 64 + mt * 16 + rr) * 32 + q * 8];
#pragma unroll
    for (int nt = 0; nt < 4; ++nt)
      bfr[nt] = *(const bf16x8*)&lB[(wn * 64 + nt * 16 + rr) * 32 + q * 8];
#pragma unroll
    for (int mt = 0; mt < 4; ++mt)
#pragma unroll
      for (int nt = 0; nt < 4; ++nt)
        acc[mt][nt] = __builtin_amdgcn_mfma_f32_16x16x32_bf16(af[mt], bfr[nt], acc[mt][nt], 0, 0, 0);
    __syncthreads();
  }

#pragma unroll
  for (int nt = 0; nt < 4; ++nt) {
    int c = n0 + wn * 64 + nt * 16 + rr;
    float b = bias[c];
    float sc = scale ? scale[c] * 0.9999950000374997f : 1.0f;   // gamma/sqrt(1+1e-5)
    float sh = shift ? shift[c] : 0.0f;
#pragma unroll
    for (int mt = 0; mt < 4; ++mt) {
      int rbase = m0 + wm * 64 + mt * 16 + q * 4;
#pragma unroll
      for (int r2 = 0; r2 < 4; ++r2) {
        int row = rbase + r2;
        if (row < M) {
          float y = (acc[mt][nt][r2] + b) * sc + sh;
          C[(size_t)row * 256 + c] = f2bf(siluf(y));
        }
      }
    }
  }
}

// ---------------- fused node heads: atom logits [N,16] + bond-P [N,8(5)] -------
// bond_logits[e] = (h[src]+h[dst])@bondW + b  ==  P[src] + P[dst] + b,  P = h@bondW
__global__ __launch_bounds__(256) void heads_node(
    const u16* __restrict__ h, const float* __restrict__ atomW,
    const float* __restrict__ atomB, const float* __restrict__ bondW,
    float* __restrict__ atom_out, float* __restrict__ P, int N) {
  __shared__ __align__(16) u16 hr[16 * 264];        // +8 u16 row pad: kill bank aliasing
  __shared__ __align__(16) float wa[256 * 16];
  __shared__ float wp[256 * 5];
  int tid = threadIdx.x;
  int nb = blockIdx.x * 16;
  int nrows = min(16, N - nb);
  for (int i = tid; i < nrows * 32; i += 256) {      // 16B chunks, padded rows
    int row = i >> 5, j = i & 31;
    ((uint4*)(hr + row * 264))[j] = ((const uint4*)(h + (size_t)(nb + row) * 256))[j];
  }
  for (int i = tid; i < 1024; i += 256)              // 256*16 floats
    ((uint4*)wa)[i] = ((const uint4*)atomW)[i];
  for (int i = tid; i < 1280; i += 256)
    wp[i] = bondW[i];
  __syncthreads();
  int nl = tid >> 4, c = tid & 15;
  if (nl < nrows) {
    float accA = atomB[c];
    float accP = 0.0f;
    bool doP = (c < 5);
    for (int k = 0; k < 256; ++k) {
      float hv = bf2f(hr[nl * 264 + k]);
      accA = fmaf(hv, wa[k * 16 + c], accA);
      if (doP) accP = fmaf(hv, wp[k * 5 + c], accP);
    }
    atom_out[(size_t)(nb + nl) * 16 + c] = accA;
    if (doP) P[(size_t)(nb + nl) * 8 + c] = accP;
  }
}

// ---------------- bond edge output: out[e] = P[src]+P[dst]+b -------------------
__global__ __launch_bounds__(256) void bond_edge(
    const float* __restrict__ P, const int* __restrict__ src,
    const int* __restrict__ dst, const float* __restrict__ b,
    float* __restrict__ out, int E) {
  __shared__ float so[256 * 5];
  int t = threadIdx.x;
  int e = blockIdx.x * 256 + t;
  float v0 = 0, v1 = 0, v2 = 0, v3 = 0, v4 = 0;
  if (e < E) {
    int s = src[e], d = dst[e];
    float4 ps = *(const float4*)(P + (size_t)s * 8);
    float  p4s = P[(size_t)s * 8 + 4];
    float4 pd = *(const float4*)(P + (size_t)d * 8);
    float  p4d = P[(size_t)d * 8 + 4];
    v0 = ps.x + pd.x + b[0];
    v1 = ps.y + pd.y + b[1];
    v2 = ps.z + pd.z + b[2];
    v3 = ps.w + pd.w + b[3];
    v4 = p4s + p4d + b[4];
  }
  so[t * 5 + 0] = v0; so[t * 5 + 1] = v1; so[t * 5 + 2] = v2;
  so[t * 5 + 3] = v3; so[t * 5 + 4] = v4;
  __syncthreads();
  size_t base = (size_t)blockIdx.x * 256 * 5;
  size_t lim = (size_t)E * 5;
  for (int i = t; i < 256 * 5; i += 256) {
    size_t g = base + i;
    if (g < lim) out[g] = so[i];
  }
}

// ---------------- host ---------------------------------------------------------
extern "C" void kernel_launch(void* const* d_in, const int* in_sizes, int n_in,
                              void* d_out, int out_size, void* d_ws, size_t ws_size,
                              hipStream_t stream) {
  const int*   x_noisy   = (const int*)d_in[0];
  const int*   nmaskobs  = (const int*)d_in[1];
  const int*   ea        = (const int*)d_in[2];
  const int*   em        = (const int*)d_in[3];
  const int*   eidx      = (const int*)d_in[4];
  const int*   tnode     = (const int*)d_in[5];
  const float* cvec      = (const float*)d_in[6];
  const int*   batch     = (const int*)d_in[7];
  const float* atom_emb  = (const float*)d_in[8];
  const float* bond_emb  = (const float*)d_in[9];
  const float* nmask_emb = (const float*)d_in[10];
  const float* emask_emb = (const float*)d_in[11];
  const float* t_W1      = (const float*)d_in[12];
  const float* t_b1      = (const float*)d_in[13];
  const float* t_W2      = (const float*)d_in[14];
  const float* t_b2      = (const float*)d_in[15];
  const float* cond_W    = (const float*)d_in[16];
  const float* cond_b    = (const float*)d_in[17];
  const float* edge_W1   = (const float*)d_in[18];
  const float* edge_b1   = (const float*)d_in[19];
  const float* edge_W2   = (const float*)d_in[20];
  const float* edge_b2   = (const float*)d_in[21];
  const float* e0_W      = (const float*)d_in[22];
  const float* conv0_W1  = (const float*)d_in[23];
  const float* conv0_b1  = (const float*)d_in[24];
  const float* conv0_W2  = (const float*)d_in[25];
  const float* conv0_b2  = (const float*)d_in[26];
  const float* conv0_eps = (const float*)d_in[27];
  const float* convs_W1  = (const float*)d_in[28];
  const float* convs_b1  = (const float*)d_in[29];
  const float* convs_W2  = (const float*)d_in[30];
  const float* convs_b2  = (const float*)d_in[31];
  const float* convs_eps = (const float*)d_in[32];
  const float* bn_gamma  = (const float*)d_in[33];
  const float* bn_beta   = (const float*)d_in[34];
  const float* atom_W    = (const float*)d_in[35];
  const float* atom_b    = (const float*)d_in[36];
  const float* bond_W    = (const float*)d_in[37];
  const float* bond_b    = (const float*)d_in[38];

  const int N = in_sizes[0];
  const int E = in_sizes[2];
  const int B = in_sizes[6] / 2;
  const int* srcp = eidx;
  const int* dstp = eidx + E;

  char* base = (char*)d_ws;
  size_t off = 0;
  auto alloc = [&](size_t bytes) -> char* {
    char* p = base + off;
    off = (off + bytes + 255) & ~(size_t)255;
    return p;
  };
  u16* h0   = (u16*)alloc((size_t)N * W0 * 2);     // reused as h [N,256] after layer 0
  u16* z0   = (u16*)alloc((size_t)N * W0 * 2);     // reused as z [N,256]
  u16* ubuf = (u16*)alloc((size_t)N * DM * 2);
  u16* w10t = (u16*)alloc((size_t)DM * W0 * 2);
  u16* w20t = (u16*)alloc((size_t)DM * DM * 2);
  u16* wc1t = (u16*)alloc((size_t)5 * DM * DM * 2);
  u16* wc2t = (u16*)alloc((size_t)5 * DM * DM * 2);
  float* ttab  = (float*)alloc((size_t)200 * DM * 4);
  float* cprojb= (float*)alloc((size_t)B * DM * 4);
  float* eftab = (float*)alloc((size_t)10 * DM * 4);
  float* e0tab = (float*)alloc((size_t)10 * W0 * 4);
  float* Pbuf  = (float*)alloc((size_t)N * 8 * 4);
  int* deg  = (int*)alloc((size_t)N * 4);
  int* ro   = (int*)alloc((size_t)(N + 1) * 4);
  int* cur  = (int*)alloc((size_t)N * 4);
  int* csr  = (int*)alloc((size_t)E * 4);
  int* bsum = (int*)alloc((size_t)256 * 4);
  (void)ws_size; (void)n_in; (void)out_size;

  u16* hbuf = h0;
  u16* zbuf = z0;
  float* atom_out = (float*)d_out;
  float* bond_out = atom_out + (size_t)N * 16;

  hipMemsetAsync(deg, 0, (size_t)N * 4, stream);

  // precompute: weights (transposed bf16), tables
  wT_kernel<<<(DM * W0 + 255) / 256, 256, 0, stream>>>(conv0_W1, w10t, 1, W0_REAL, W0, DM);
  wT_kernel<<<(DM * DM + 255) / 256, 256, 0, stream>>>(conv0_W2, w20t, 1, DM, DM, DM);
  wT_kernel<<<(5 * DM * DM + 255) / 256, 256, 0, stream>>>(convs_W1, wc1t, 5, DM, DM, DM);
  wT_kernel<<<(5 * DM * DM + 255) / 256, 256, 0, stream>>>(convs_W2, wc2t, 5, DM, DM, DM);
  t_table_kernel<<<200, 256, 0, stream>>>(t_W1, t_b1, t_W2, t_b2, ttab);
  cproj_kernel<<<(B * DM + 255) / 256, 256, 0, stream>>>(cvec, cond_W, cond_b, cprojb, B);
  ef_tab_kernel<<<10, 256, 0, stream>>>(bond_emb, emask_emb, edge_W1, edge_b1, edge_W2, edge_b2, eftab);
  e0_tab_kernel<<<10, 512, 0, stream>>>(eftab, e0_W, e0tab);
  h0_kernel<<<(N * W0 + 255) / 256, 256, 0, stream>>>(x_noisy, nmaskobs, tnode, batch,
      atom_emb, nmask_emb, ttab, cprojb, h0, N);
  // CSR by dst
  const int nscan = (N + 255) / 256;
  deg_kernel<<<(E + 255) / 256, 256, 0, stream>>>(dstp, deg, E);
  scan1_kernel<<<nscan, 256, 0, stream>>>(deg, ro, bsum, N);
  scan2_kernel<<<1, 256, 0, stream>>>(bsum, nscan);
  scan3_kernel<<<nscan, 256, 0, stream>>>(ro, cur, bsum, N, E);
  fill_kernel<<<(E + 255) / 256, 256, 0, stream>>>(srcp, dstp, ea, em, cur, csr, E);

  dim3 ggrid((N + 127) / 128, 2);
  const int nagg = (N + 3) / 4;
  // layer 0
  agg_z_kernel<<<nagg, 256, 0, stream>>>(h0, e0tab, ro, csr, conv0_eps, z0, N, W0);
  gemm_fused<<<ggrid, 256, 0, stream>>>(z0, w10t, conv0_b1, nullptr, nullptr, ubuf, N, W0);
  gemm_fused<<<ggrid, 256, 0, stream>>>(ubuf, w20t, conv0_b2, bn_gamma, bn_beta, hbuf, N, DM);
  // layers 1..5
  for (int i = 0; i < 5; ++i) {
    agg_z_kernel<<<nagg, 256, 0, stream>>>(hbuf, eftab, ro, csr, convs_eps + i, zbuf, N, DM);
    gemm_fused<<<ggrid, 256, 0, stream>>>(zbuf, wc1t + (size_t)i * DM * DM, convs_b1 + i * DM,
                                          nullptr, nullptr, ubuf, N, DM);
    gemm_fused<<<ggrid, 256, 0, stream>>>(ubuf, wc2t + (size_t)i * DM * DM, convs_b2 + i * DM,
                                          bn_gamma + (i + 1) * DM, bn_beta + (i + 1) * DM, hbuf, N, DM);
  }
  // heads
  heads_node<<<(N + 15) / 16, 256, 0, stream>>>(hbuf, atom_W, atom_b, bond_W, atom_out, Pbuf, N);
  bond_edge<<<(E + 255) / 256, 256, 0, stream>>>(Pbuf, srcp, dstp, bond_b, bond_out, E);
}

// Round 4
// 929.068 us; speedup vs baseline: 1.4859x; 1.0892x over previous
//
#include <hip/hip_runtime.h>
#include <cstdint>
#include <cmath>

typedef unsigned short u16;
typedef unsigned int   u32;

using bf16x8 = __attribute__((ext_vector_type(8))) short;
using f32x4  = __attribute__((ext_vector_type(4))) float;

#define DM 256        // d_model
#define W0 416        // layer-0 input width padded 392 -> 416 (multiple of 32)
#define W0_REAL 392

__device__ __forceinline__ float bf2f(u16 v) {
  union { u32 u; float f; } c; c.u = ((u32)v) << 16; return c.f;
}
__device__ __forceinline__ u16 f2bf(float f) {
  union { float f; u32 u; } c; c.f = f;
  u32 u = c.u;
  return (u16)((u + 0x7FFFu + ((u >> 16) & 1u)) >> 16);  // RNE
}
__device__ __forceinline__ float siluf(float y) {
  return y / (1.0f + __expf(-y));
}
__device__ __forceinline__ uint4 pack8(float f0, float f1, float f2, float f3,
                                       float f4, float f5, float f6, float f7) {
  uint4 o;
  o.x = (u32)f2bf(f0) | ((u32)f2bf(f1) << 16);
  o.y = (u32)f2bf(f2) | ((u32)f2bf(f3) << 16);
  o.z = (u32)f2bf(f4) | ((u32)f2bf(f5) << 16);
  o.w = (u32)f2bf(f6) | ((u32)f2bf(f7) << 16);
  return o;
}

// ---------------- weight transpose + bf16 convert: out[n*Kpad+k] = W[k*Nc+n] ----
__global__ void wT_kernel(const float* __restrict__ W, u16* __restrict__ out,
                          int nmat, int K, int Kpad, int Nc) {
  int idx = blockIdx.x * 256 + threadIdx.x;
  int tot = nmat * Nc * Kpad;
  if (idx >= tot) return;
  int m = idx / (Nc * Kpad);
  int r = idx - m * (Nc * Kpad);
  int n = r / Kpad;
  int k = r - n * Kpad;
  float v = (k < K) ? W[(size_t)m * K * Nc + (size_t)k * Nc + n] : 0.0f;
  out[idx] = f2bf(v);
}

// ---------------- combined head weight: [32,256] bf16; rows 0-15 atomW^T, 16-20 bondW^T
__global__ void whead_kernel(const float* __restrict__ atomW, const float* __restrict__ bondW,
                             u16* __restrict__ out) {
  int idx = blockIdx.x * 256 + threadIdx.x;
  if (idx >= 32 * 256) return;
  int j = idx >> 8, k = idx & 255;
  float v = 0.0f;
  if (j < 16) v = atomW[k * 16 + j];
  else if (j < 21) v = bondW[k * 5 + (j - 16)];
  out[idx] = f2bf(v);
}

// ---------------- timestep MLP table: 200 x 256 (f32) --------------------------
__global__ void t_table_kernel(const float* __restrict__ W1, const float* __restrict__ b1,
                               const float* __restrict__ W2, const float* __restrict__ b2,
                               float* __restrict__ out) {
  __shared__ float s[256];
  __shared__ float a1[256];
  int r = blockIdx.x, t = threadIdx.x;
  float tv = (float)r;
  float coef = -logf(10000.0f) / 127.0f;
  int j = t & 127;
  float ang = tv * expf(coef * (float)j);
  s[t] = (t < 128) ? sinf(ang) : cosf(ang);
  __syncthreads();
  float acc = b1[t];
  for (int k = 0; k < 256; ++k) acc = fmaf(s[k], W1[k * 256 + t], acc);
  a1[t] = acc / (1.0f + expf(-acc));
  __syncthreads();
  float acc2 = b2[t];
  for (int k = 0; k < 256; ++k) acc2 = fmaf(a1[k], W2[k * 256 + t], acc2);
  out[r * 256 + t] = acc2;
}

// ---------------- cond projection: B x 256 (f32) -------------------------------
__global__ void cproj_kernel(const float* __restrict__ cv, const float* __restrict__ W,
                             const float* __restrict__ b, float* __restrict__ out, int B) {
  int i = blockIdx.x * 256 + threadIdx.x;
  if (i < B * 256) {
    int g = i >> 8, c = i & 255;
    out[i] = fmaf(cv[g * 2], W[c], fmaf(cv[g * 2 + 1], W[256 + c], b[c]));
  }
}

// ---------------- edge-feature table: 10 x 256 (f32); idx = bond*2 + mask ------
__global__ void ef_tab_kernel(const float* __restrict__ bond_emb, const float* __restrict__ emask_emb,
                              const float* __restrict__ W1, const float* __restrict__ b1,
                              const float* __restrict__ W2, const float* __restrict__ b2,
                              float* __restrict__ out) {
  __shared__ float ein[72];
  __shared__ float a1[256];
  int bidx = blockIdx.x;           // 0..9
  int bt = bidx >> 1, m = bidx & 1;
  int t = threadIdx.x;
  if (t < 64) ein[t] = bond_emb[bt * 64 + t];
  else if (t < 72) ein[t] = emask_emb[m * 8 + (t - 64)];
  __syncthreads();
  float acc = b1[t];
  for (int k = 0; k < 72; ++k) acc = fmaf(ein[k], W1[k * 256 + t], acc);
  a1[t] = acc / (1.0f + expf(-acc));
  __syncthreads();
  float acc2 = b2[t];
  for (int k = 0; k < 256; ++k) acc2 = fmaf(a1[k], W2[k * 256 + t], acc2);
  out[bidx * 256 + t] = acc2;
}

// ---------------- layer-0 edge table: e_feat @ e0_W -> 10 x 416 (padded) -------
__global__ void e0_tab_kernel(const float* __restrict__ eftab, const float* __restrict__ e0W,
                              float* __restrict__ out) {
  __shared__ float ef[256];
  int bidx = blockIdx.x, t = threadIdx.x;
  if (t < 256) ef[t] = eftab[bidx * 256 + t];
  __syncthreads();
  if (t < W0) {
    float acc = 0.0f;
    if (t < W0_REAL) {
      for (int k = 0; k < 256; ++k) acc = fmaf(ef[k], e0W[k * W0_REAL + t], acc);
    }
    out[bidx * W0 + t] = acc;
  }
}

// ---------------- h0 build: [N, 416] bf16, 8-col chunks ------------------------
// ch 0..15: atom_emb; ch 16: nmask_emb; ch 17..48: ttab+cproj; ch 49..51: pad
__global__ void h0_kernel(const int* __restrict__ x, const int* __restrict__ nm,
                          const int* __restrict__ tnode, const int* __restrict__ batch,
                          const float* __restrict__ atom_emb, const float* __restrict__ nmask_emb,
                          const float* __restrict__ ttab, const float* __restrict__ cproj,
                          u16* __restrict__ h0, int N) {
  int idx = blockIdx.x * 256 + threadIdx.x;
  if (idx >= N * 52) return;
  int n = idx / 52;
  int ch = idx - n * 52;
  uint4 o;
  if (ch < 16) {
    const float* s = atom_emb + (size_t)x[n] * 128 + ch * 8;
    float4 a = *(const float4*)s, b = *(const float4*)(s + 4);
    o = pack8(a.x, a.y, a.z, a.w, b.x, b.y, b.z, b.w);
  } else if (ch == 16) {
    const float* s = nmask_emb + (size_t)nm[n] * 8;
    float4 a = *(const float4*)s, b = *(const float4*)(s + 4);
    o = pack8(a.x, a.y, a.z, a.w, b.x, b.y, b.z, b.w);
  } else if (ch < 49) {
    int cc = ch * 8 - 136;
    const float* ta = ttab + (size_t)tnode[n] * 256 + cc;
    const float* cb = cproj + (size_t)batch[n] * 256 + cc;
    float4 a = *(const float4*)ta, b = *(const float4*)(ta + 4);
    float4 c = *(const float4*)cb, d = *(const float4*)(cb + 4);
    o = pack8(a.x + c.x, a.y + c.y, a.z + c.z, a.w + c.w,
              b.x + d.x, b.y + d.y, b.z + d.z, b.w + d.w);
  } else {
    o = make_uint4(0, 0, 0, 0);
  }
  *(uint4*)(h0 + (size_t)n * W0 + ch * 8) = o;
}

// ---------------- CSR build ----------------------------------------------------
__global__ void deg_kernel(const int* __restrict__ dst, int* __restrict__ deg, int E) {
  int e = blockIdx.x * 256 + threadIdx.x;
  if (e < E) atomicAdd(&deg[dst[e]], 1);
}

__global__ void scan1_kernel(const int* __restrict__ deg, int* __restrict__ ro,
                             int* __restrict__ bsum, int N) {
  __shared__ int tmp[256];
  int tid = threadIdx.x, i = blockIdx.x * 256 + tid;
  int v = (i < N) ? deg[i] : 0;
  tmp[tid] = v;
  __syncthreads();
  for (int o = 1; o < 256; o <<= 1) {
    int t = (tid >= o) ? tmp[tid - o] : 0;
    __syncthreads();
    tmp[tid] += t;
    __syncthreads();
  }
  if (i < N) ro[i] = tmp[tid] - v;     // exclusive within block
  if (tid == 255) bsum[blockIdx.x] = tmp[255];
}

__global__ void scan2_kernel(int* __restrict__ bsum, int nb) {
  __shared__ int tmp[256];
  int tid = threadIdx.x;
  int v = (tid < nb) ? bsum[tid] : 0;
  tmp[tid] = v;
  __syncthreads();
  for (int o = 1; o < 256; o <<= 1) {
    int t = (tid >= o) ? tmp[tid - o] : 0;
    __syncthreads();
    tmp[tid] += t;
    __syncthreads();
  }
  if (tid < nb) bsum[tid] = tmp[tid] - v;   // exclusive block offsets
}

__global__ void scan3_kernel(int* __restrict__ ro, int* __restrict__ cur,
                             const int* __restrict__ bsum, int N, int E) {
  int i = blockIdx.x * 256 + threadIdx.x;
  if (i < N) {
    int r = ro[i] + bsum[blockIdx.x];
    ro[i] = r;
    cur[i] = r;
  }
  if (i == 0) ro[N] = E;
}

__global__ void fill_kernel(const int* __restrict__ src, const int* __restrict__ dst,
                            const int* __restrict__ ea, const int* __restrict__ em,
                            int* __restrict__ cur, int* __restrict__ csr, int E) {
  int e = blockIdx.x * 256 + threadIdx.x;
  if (e < E) {
    int d = dst[e];
    int pos = atomicAdd(&cur[d], 1);
    csr[pos] = src[e] | ((ea[e] * 2 + em[e]) << 20);   // src < 2^20, etype in high bits
  }
}

// ---------------- aggregation + z = (1+eps)*h + sum relu(h[src]+e) -------------
__global__ __launch_bounds__(256) void agg_z_kernel(
    const u16* __restrict__ h, const float* __restrict__ etab,
    const int* __restrict__ ro, const int* __restrict__ csr,
    const float* __restrict__ epsp, u16* __restrict__ z, int N, int W) {
  int wid = threadIdx.x >> 6, lane = threadIdx.x & 63;
  int n = blockIdx.x * 4 + wid;
  if (n >= N) return;
  int s0 = ro[n], s1 = ro[n + 1];
  float eps1 = 1.0f + *epsp;

  for (int cbase = 0; cbase < W; cbase += 256) {
    int c4 = cbase + lane * 4;
    bool live = (c4 < W);
    int c4c = live ? c4 : (W - 4);
    float a0 = 0.f, a1 = 0.f, a2 = 0.f, a3 = 0.f;

    for (int base = s0; base < s1; base += 64) {
      int m = s1 - base; if (m > 64) m = 64;
      int pk = (lane < m) ? csr[base + lane] : 0;
      int j = 0;
      for (; j + 1 < m; j += 2) {
        int pa = __shfl(pk, j);
        int pb = __shfl(pk, j + 1);
        int sa = pa & 0xFFFFF, ea_ = pa >> 20;
        int sb = pb & 0xFFFFF, eb_ = pb >> 20;
        uint2 ha = *(const uint2*)(h + (size_t)sa * W + c4c);
        uint2 hb = *(const uint2*)(h + (size_t)sb * W + c4c);
        float4 va = *(const float4*)(etab + (size_t)ea_ * W + c4c);
        float4 vb = *(const float4*)(etab + (size_t)eb_ * W + c4c);
        a0 += fmaxf(bf2f((u16)(ha.x & 0xFFFF)) + va.x, 0.f);
        a1 += fmaxf(bf2f((u16)(ha.x >> 16))    + va.y, 0.f);
        a2 += fmaxf(bf2f((u16)(ha.y & 0xFFFF)) + va.z, 0.f);
        a3 += fmaxf(bf2f((u16)(ha.y >> 16))    + va.w, 0.f);
        a0 += fmaxf(bf2f((u16)(hb.x & 0xFFFF)) + vb.x, 0.f);
        a1 += fmaxf(bf2f((u16)(hb.x >> 16))    + vb.y, 0.f);
        a2 += fmaxf(bf2f((u16)(hb.y & 0xFFFF)) + vb.z, 0.f);
        a3 += fmaxf(bf2f((u16)(hb.y >> 16))    + vb.w, 0.f);
      }
      if (j < m) {
        int pa = __shfl(pk, j);
        int sa = pa & 0xFFFFF, ea_ = pa >> 20;
        uint2 ha = *(const uint2*)(h + (size_t)sa * W + c4c);
        float4 va = *(const float4*)(etab + (size_t)ea_ * W + c4c);
        a0 += fmaxf(bf2f((u16)(ha.x & 0xFFFF)) + va.x, 0.f);
        a1 += fmaxf(bf2f((u16)(ha.x >> 16))    + va.y, 0.f);
        a2 += fmaxf(bf2f((u16)(ha.y & 0xFFFF)) + va.z, 0.f);
        a3 += fmaxf(bf2f((u16)(ha.y >> 16))    + va.w, 0.f);
      }
    }

    if (live) {
      uint2 hn = *(const uint2*)(h + (size_t)n * W + c4);
      float z0 = eps1 * bf2f((u16)(hn.x & 0xFFFF)) + a0;
      float z1 = eps1 * bf2f((u16)(hn.x >> 16))    + a1;
      float z2 = eps1 * bf2f((u16)(hn.y & 0xFFFF)) + a2;
      float z3 = eps1 * bf2f((u16)(hn.y >> 16))    + a3;
      uint2 o;
      o.x = (u32)f2bf(z0) | ((u32)f2bf(z1) << 16);
      o.y = (u32)f2bf(z2) | ((u32)f2bf(z3) << 16);
      *(uint2*)(z + (size_t)n * W + c4) = o;
    }
  }
}

// ---------------- bf16 MFMA GEMM: C[M,256] = silu(((A@B)+bias)*scale+shift) ----
__device__ __forceinline__ void g2l16(const u16* g, u16* l) {
  __builtin_amdgcn_global_load_lds(
      (__attribute__((address_space(1))) u32*)g,
      (__attribute__((address_space(3))) u32*)l, 16, 0, 0);
}

__global__ __launch_bounds__(256) void gemm_fused(
    const u16* __restrict__ A, const u16* __restrict__ BT,
    const float* __restrict__ bias, const float* __restrict__ scale,
    const float* __restrict__ shift, u16* __restrict__ C, int M, int K) {
  __shared__ __align__(16) u16 lA[128 * 32];
  __shared__ __align__(16) u16 lB[128 * 32];
  int tid = threadIdx.x;
  int wid = tid >> 6, lane = tid & 63;
  int q = lane >> 4, rr = lane & 15;
  int wm = wid >> 1, wn = wid & 1;
  int m0 = blockIdx.x * 128, n0 = blockIdx.y * 128;

  f32x4 acc[4][4] = {};

  int arow = tid >> 2;            // 0..63
  int acol = (tid & 3) * 8;       // bf16 element offset within 32-wide k tile

  for (int k0 = 0; k0 < K; k0 += 32) {
#pragma unroll
    for (int p = 0; p < 2; ++p) {
      int gr = m0 + p * 64 + arow;
      if (gr >= M) gr = M - 1;                       // clamp (results masked on store)
      g2l16(A + (size_t)gr * K + k0 + acol, &lA[p * 2048 + wid * 512]);
      int br = n0 + p * 64 + arow;                   // always < 256
      g2l16(BT + (size_t)br * K + k0 + acol, &lB[p * 2048 + wid * 512]);
    }
    __syncthreads();
    bf16x8 af[4], bfr[4];
#pragma unroll
    for (int mt = 0; mt < 4; ++mt)
      af[mt] = *(const bf16x8*)&lA[(wm * 64 + mt * 16 + rr) * 32 + q * 8];
#pragma unroll
    for (int nt = 0; nt < 4; ++nt)
      bfr[nt] = *(const bf16x8*)&lB[(wn * 64 + nt * 16 + rr) * 32 + q * 8];
#pragma unroll
    for (int mt = 0; mt < 4; ++mt)
#pragma unroll
      for (int nt = 0; nt < 4; ++nt)
        acc[mt][nt] = __builtin_amdgcn_mfma_f32_16x16x32_bf16(af[mt], bfr[nt], acc[mt][nt], 0, 0, 0);
    __syncthreads();
  }

#pragma unroll
  for (int nt = 0; nt < 4; ++nt) {
    int c = n0 + wn * 64 + nt * 16 + rr;
    float b = bias[c];
    float sc = scale ? scale[c] * 0.9999950000374997f : 1.0f;   // gamma/sqrt(1+1e-5)
    float sh = shift ? shift[c] : 0.0f;
#pragma unroll
    for (int mt = 0; mt < 4; ++mt) {
      int rbase = m0 + wm * 64 + mt * 16 + q * 4;
#pragma unroll
      for (int r2 = 0; r2 < 4; ++r2) {
        int row = rbase + r2;
        if (row < M) {
          float y = (acc[mt][nt][r2] + b) * sc + sh;
          C[(size_t)row * 256 + c] = f2bf(siluf(y));
        }
      }
    }
  }
}

// ---------------- MFMA head GEMM: [N,256] @ [256,32] -> atom_out[N,16], P[N,8(5)]
__global__ __launch_bounds__(256) void head_gemm(
    const u16* __restrict__ A, const u16* __restrict__ WT,
    const float* __restrict__ atomB,
    float* __restrict__ atom_out, float* __restrict__ P, int M) {
  __shared__ __align__(16) u16 lA[128 * 32];
  __shared__ __align__(16) u16 lB[32 * 264];     // row pad 256->264: <=2-way banks
  int tid = threadIdx.x;
  int wid = tid >> 6, lane = tid & 63;
  int q = lane >> 4, rr = lane & 15;
  int m0 = blockIdx.x * 128;

  for (int i = tid; i < 32 * 256; i += 256)
    lB[(i >> 8) * 264 + (i & 255)] = WT[i];

  f32x4 acc[2][2] = {};
  int arow = tid >> 2, acol = (tid & 3) * 8;

  for (int k0 = 0; k0 < 256; k0 += 32) {
#pragma unroll
    for (int p = 0; p < 2; ++p) {
      int gr = m0 + p * 64 + arow;
      if (gr >= M) gr = M - 1;
      g2l16(A + (size_t)gr * 256 + k0 + acol, &lA[p * 2048 + wid * 512]);
    }
    __syncthreads();
    bf16x8 af[2], bfr[2];
#pragma unroll
    for (int mt = 0; mt < 2; ++mt)
      af[mt] = *(const bf16x8*)&lA[(wid * 32 + mt * 16 + rr) * 32 + q * 8];
#pragma unroll
    for (int nt = 0; nt < 2; ++nt)
      bfr[nt] = *(const bf16x8*)&lB[(nt * 16 + rr) * 264 + k0 + q * 8];
#pragma unroll
    for (int mt = 0; mt < 2; ++mt)
#pragma unroll
      for (int nt = 0; nt < 2; ++nt)
        acc[mt][nt] = __builtin_amdgcn_mfma_f32_16x16x32_bf16(af[mt], bfr[nt], acc[mt][nt], 0, 0, 0);
    __syncthreads();
  }

#pragma unroll
  for (int nt = 0; nt < 2; ++nt) {
    int c = nt * 16 + rr;
    float bb = (c < 16) ? atomB[c] : 0.0f;
#pragma unroll
    for (int mt = 0; mt < 2; ++mt) {
      int rbase = m0 + wid * 32 + mt * 16 + q * 4;
#pragma unroll
      for (int r2 = 0; r2 < 4; ++r2) {
        int row = rbase + r2;
        if (row < M) {
          float v = acc[mt][nt][r2];
          if (c < 16) atom_out[(size_t)row * 16 + c] = v + bb;
          else if (c < 21) P[(size_t)row * 8 + (c - 16)] = v;
        }
      }
    }
  }
}

// ---------------- bond edge output: out[e] = P[src]+P[dst]+b -------------------
__global__ __launch_bounds__(256) void bond_edge(
    const float* __restrict__ P, const int* __restrict__ src,
    const int* __restrict__ dst, const float* __restrict__ b,
    float* __restrict__ out, int E) {
  __shared__ float so[256 * 5];
  int t = threadIdx.x;
  int e = blockIdx.x * 256 + t;
  float v0 = 0, v1 = 0, v2 = 0, v3 = 0, v4 = 0;
  if (e < E) {
    int s = src[e], d = dst[e];
    float4 ps = *(const float4*)(P + (size_t)s * 8);
    float  p4s = P[(size_t)s * 8 + 4];
    float4 pd = *(const float4*)(P + (size_t)d * 8);
    float  p4d = P[(size_t)d * 8 + 4];
    v0 = ps.x + pd.x + b[0];
    v1 = ps.y + pd.y + b[1];
    v2 = ps.z + pd.z + b[2];
    v3 = ps.w + pd.w + b[3];
    v4 = p4s + p4d + b[4];
  }
  so[t * 5 + 0] = v0; so[t * 5 + 1] = v1; so[t * 5 + 2] = v2;
  so[t * 5 + 3] = v3; so[t * 5 + 4] = v4;
  __syncthreads();
  size_t base = (size_t)blockIdx.x * 256 * 5;
  size_t lim = (size_t)E * 5;
  for (int i = t; i < 256 * 5; i += 256) {
    size_t g = base + i;
    if (g < lim) out[g] = so[i];
  }
}

// ---------------- host ---------------------------------------------------------
extern "C" void kernel_launch(void* const* d_in, const int* in_sizes, int n_in,
                              void* d_out, int out_size, void* d_ws, size_t ws_size,
                              hipStream_t stream) {
  const int*   x_noisy   = (const int*)d_in[0];
  const int*   nmaskobs  = (const int*)d_in[1];
  const int*   ea        = (const int*)d_in[2];
  const int*   em        = (const int*)d_in[3];
  const int*   eidx      = (const int*)d_in[4];
  const int*   tnode     = (const int*)d_in[5];
  const float* cvec      = (const float*)d_in[6];
  const int*   batch     = (const int*)d_in[7];
  const float* atom_emb  = (const float*)d_in[8];
  const float* bond_emb  = (const float*)d_in[9];
  const float* nmask_emb = (const float*)d_in[10];
  const float* emask_emb = (const float*)d_in[11];
  const float* t_W1      = (const float*)d_in[12];
  const float* t_b1      = (const float*)d_in[13];
  const float* t_W2      = (const float*)d_in[14];
  const float* t_b2      = (const float*)d_in[15];
  const float* cond_W    = (const float*)d_in[16];
  const float* cond_b    = (const float*)d_in[17];
  const float* edge_W1   = (const float*)d_in[18];
  const float* edge_b1   = (const float*)d_in[19];
  const float* edge_W2   = (const float*)d_in[20];
  const float* edge_b2   = (const float*)d_in[21];
  const float* e0_W      = (const float*)d_in[22];
  const float* conv0_W1  = (const float*)d_in[23];
  const float* conv0_b1  = (const float*)d_in[24];
  const float* conv0_W2  = (const float*)d_in[25];
  const float* conv0_b2  = (const float*)d_in[26];
  const float* conv0_eps = (const float*)d_in[27];
  const float* convs_W1  = (const float*)d_in[28];
  const float* convs_b1  = (const float*)d_in[29];
  const float* convs_W2  = (const float*)d_in[30];
  const float* convs_b2  = (const float*)d_in[31];
  const float* convs_eps = (const float*)d_in[32];
  const float* bn_gamma  = (const float*)d_in[33];
  const float* bn_beta   = (const float*)d_in[34];
  const float* atom_W    = (const float*)d_in[35];
  const float* atom_b    = (const float*)d_in[36];
  const float* bond_W    = (const float*)d_in[37];
  const float* bond_b    = (const float*)d_in[38];

  const int N = in_sizes[0];
  const int E = in_sizes[2];
  const int B = in_sizes[6] / 2;
  const int* srcp = eidx;
  const int* dstp = eidx + E;

  char* base = (char*)d_ws;
  size_t off = 0;
  auto alloc = [&](size_t bytes) -> char* {
    char* p = base + off;
    off = (off + bytes + 255) & ~(size_t)255;
    return p;
  };
  u16* h0   = (u16*)alloc((size_t)N * W0 * 2);     // reused as h [N,256] after layer 0
  u16* z0   = (u16*)alloc((size_t)N * W0 * 2);     // reused as z [N,256]
  u16* ubuf = (u16*)alloc((size_t)N * DM * 2);
  u16* w10t = (u16*)alloc((size_t)DM * W0 * 2);
  u16* w20t = (u16*)alloc((size_t)DM * DM * 2);
  u16* wc1t = (u16*)alloc((size_t)5 * DM * DM * 2);
  u16* wc2t = (u16*)alloc((size_t)5 * DM * DM * 2);
  u16* wht  = (u16*)alloc((size_t)32 * DM * 2);
  float* ttab  = (float*)alloc((size_t)200 * DM * 4);
  float* cprojb= (float*)alloc((size_t)B * DM * 4);
  float* eftab = (float*)alloc((size_t)10 * DM * 4);
  float* e0tab = (float*)alloc((size_t)10 * W0 * 4);
  float* Pbuf  = (float*)alloc((size_t)N * 8 * 4);
  int* deg  = (int*)alloc((size_t)N * 4);
  int* ro   = (int*)alloc((size_t)(N + 1) * 4);
  int* cur  = (int*)alloc((size_t)N * 4);
  int* csr  = (int*)alloc((size_t)E * 4);
  int* bsum = (int*)alloc((size_t)256 * 4);
  (void)ws_size; (void)n_in; (void)out_size;

  u16* hbuf = h0;
  u16* zbuf = z0;
  float* atom_out = (float*)d_out;
  float* bond_out = atom_out + (size_t)N * 16;

  hipMemsetAsync(deg, 0, (size_t)N * 4, stream);

  // precompute: weights (transposed bf16), tables
  wT_kernel<<<(DM * W0 + 255) / 256, 256, 0, stream>>>(conv0_W1, w10t, 1, W0_REAL, W0, DM);
  wT_kernel<<<(DM * DM + 255) / 256, 256, 0, stream>>>(conv0_W2, w20t, 1, DM, DM, DM);
  wT_kernel<<<(5 * DM * DM + 255) / 256, 256, 0, stream>>>(convs_W1, wc1t, 5, DM, DM, DM);
  wT_kernel<<<(5 * DM * DM + 255) / 256, 256, 0, stream>>>(convs_W2, wc2t, 5, DM, DM, DM);
  whead_kernel<<<32, 256, 0, stream>>>(atom_W, bond_W, wht);
  t_table_kernel<<<200, 256, 0, stream>>>(t_W1, t_b1, t_W2, t_b2, ttab);
  cproj_kernel<<<(B * DM + 255) / 256, 256, 0, stream>>>(cvec, cond_W, cond_b, cprojb, B);
  ef_tab_kernel<<<10, 256, 0, stream>>>(bond_emb, emask_emb, edge_W1, edge_b1, edge_W2, edge_b2, eftab);
  e0_tab_kernel<<<10, 512, 0, stream>>>(eftab, e0_W, e0tab);
  h0_kernel<<<(N * 52 + 255) / 256, 256, 0, stream>>>(x_noisy, nmaskobs, tnode, batch,
      atom_emb, nmask_emb, ttab, cprojb, h0, N);
  // CSR by dst
  const int nscan = (N + 255) / 256;
  deg_kernel<<<(E + 255) / 256, 256, 0, stream>>>(dstp, deg, E);
  scan1_kernel<<<nscan, 256, 0, stream>>>(deg, ro, bsum, N);
  scan2_kernel<<<1, 256, 0, stream>>>(bsum, nscan);
  scan3_kernel<<<nscan, 256, 0, stream>>>(ro, cur, bsum, N, E);
  fill_kernel<<<(E + 255) / 256, 256, 0, stream>>>(srcp, dstp, ea, em, cur, csr, E);

  dim3 ggrid((N + 127) / 128, 2);
  const int nagg = (N + 3) / 4;
  // layer 0
  agg_z_kernel<<<nagg, 256, 0, stream>>>(h0, e0tab, ro, csr, conv0_eps, z0, N, W0);
  gemm_fused<<<ggrid, 256, 0, stream>>>(z0, w10t, conv0_b1, nullptr, nullptr, ubuf, N, W0);
  gemm_fused<<<ggrid, 256, 0, stream>>>(ubuf, w20t, conv0_b2, bn_gamma, bn_beta, hbuf, N, DM);
  // layers 1..5
  for (int i = 0; i < 5; ++i) {
    agg_z_kernel<<<nagg, 256, 0, stream>>>(hbuf, eftab, ro, csr, convs_eps + i, zbuf, N, DM);
    gemm_fused<<<ggrid, 256, 0, stream>>>(zbuf, wc1t + (size_t)i * DM * DM, convs_b1 + i * DM,
                                          nullptr, nullptr, ubuf, N, DM);
    gemm_fused<<<ggrid, 256, 0, stream>>>(ubuf, wc2t + (size_t)i * DM * DM, convs_b2 + i * DM,
                                          bn_gamma + (i + 1) * DM, bn_beta + (i + 1) * DM, hbuf, N, DM);
  }
  // heads
  head_gemm<<<(N + 127) / 128, 256, 0, stream>>>(hbuf, wht, atom_b, atom_out, Pbuf, N);
  bond_edge<<<(E + 255) / 256, 256, 0, stream>>>(Pbuf, srcp, dstp, bond_b, bond_out, E);
}

// Round 5
// 713.035 us; speedup vs baseline: 1.9361x; 1.3030x over previous
//
#include <hip/hip_runtime.h>
#include <cstdint>
#include <cmath>

typedef unsigned short u16;
typedef unsigned int   u32;

using bf16x8 = __attribute__((ext_vector_type(8))) short;
using f32x4  = __attribute__((ext_vector_type(4))) float;

#define DM 256        // d_model
#define W0 448        // layer-0 input width padded 392 -> 448 (multiple of 64)
#define W0_REAL 392

__device__ __forceinline__ float bf2f(u16 v) {
  union { u32 u; float f; } c; c.u = ((u32)v) << 16; return c.f;
}
__device__ __forceinline__ u16 f2bf(float f) {
  union { float f; u32 u; } c; c.f = f;
  u32 u = c.u;
  return (u16)((u + 0x7FFFu + ((u >> 16) & 1u)) >> 16);  // RNE
}
__device__ __forceinline__ float siluf(float y) {
  return y / (1.0f + __expf(-y));
}
__device__ __forceinline__ uint4 pack8(float f0, float f1, float f2, float f3,
                                       float f4, float f5, float f6, float f7) {
  uint4 o;
  o.x = (u32)f2bf(f0) | ((u32)f2bf(f1) << 16);
  o.y = (u32)f2bf(f2) | ((u32)f2bf(f3) << 16);
  o.z = (u32)f2bf(f4) | ((u32)f2bf(f5) << 16);
  o.w = (u32)f2bf(f6) | ((u32)f2bf(f7) << 16);
  return o;
}

// ---------------- weight transpose + bf16 convert: out[n*Kpad+k] = W[k*Nc+n] ----
__global__ void wT_kernel(const float* __restrict__ W, u16* __restrict__ out,
                          int nmat, int K, int Kpad, int Nc) {
  int idx = blockIdx.x * 256 + threadIdx.x;
  int tot = nmat * Nc * Kpad;
  if (idx >= tot) return;
  int m = idx / (Nc * Kpad);
  int r = idx - m * (Nc * Kpad);
  int n = r / Kpad;
  int k = r - n * Kpad;
  float v = (k < K) ? W[(size_t)m * K * Nc + (size_t)k * Nc + n] : 0.0f;
  out[idx] = f2bf(v);
}

// ---------------- combined head weight: [32,256] bf16 --------------------------
__global__ void whead_kernel(const float* __restrict__ atomW, const float* __restrict__ bondW,
                             u16* __restrict__ out) {
  int idx = blockIdx.x * 256 + threadIdx.x;
  if (idx >= 32 * 256) return;
  int j = idx >> 8, k = idx & 255;
  float v = 0.0f;
  if (j < 16) v = atomW[k * 16 + j];
  else if (j < 21) v = bondW[k * 5 + (j - 16)];
  out[idx] = f2bf(v);
}

// ---------------- timestep MLP table: 200 x 256 (f32) --------------------------
__global__ void t_table_kernel(const float* __restrict__ W1, const float* __restrict__ b1,
                               const float* __restrict__ W2, const float* __restrict__ b2,
                               float* __restrict__ out) {
  __shared__ float s[256];
  __shared__ float a1[256];
  int r = blockIdx.x, t = threadIdx.x;
  float tv = (float)r;
  float coef = -logf(10000.0f) / 127.0f;
  int j = t & 127;
  float ang = tv * expf(coef * (float)j);
  s[t] = (t < 128) ? sinf(ang) : cosf(ang);
  __syncthreads();
  float acc = b1[t];
  for (int k = 0; k < 256; ++k) acc = fmaf(s[k], W1[k * 256 + t], acc);
  a1[t] = acc / (1.0f + expf(-acc));
  __syncthreads();
  float acc2 = b2[t];
  for (int k = 0; k < 256; ++k) acc2 = fmaf(a1[k], W2[k * 256 + t], acc2);
  out[r * 256 + t] = acc2;
}

// ---------------- cond projection: B x 256 (f32) -------------------------------
__global__ void cproj_kernel(const float* __restrict__ cv, const float* __restrict__ W,
                             const float* __restrict__ b, float* __restrict__ out, int B) {
  int i = blockIdx.x * 256 + threadIdx.x;
  if (i < B * 256) {
    int g = i >> 8, c = i & 255;
    out[i] = fmaf(cv[g * 2], W[c], fmaf(cv[g * 2 + 1], W[256 + c], b[c]));
  }
}

// ---------------- edge-feature table: 10 x 256 (f32) ---------------------------
__global__ void ef_tab_kernel(const float* __restrict__ bond_emb, const float* __restrict__ emask_emb,
                              const float* __restrict__ W1, const float* __restrict__ b1,
                              const float* __restrict__ W2, const float* __restrict__ b2,
                              float* __restrict__ out) {
  __shared__ float ein[72];
  __shared__ float a1[256];
  int bidx = blockIdx.x;           // 0..9
  int bt = bidx >> 1, m = bidx & 1;
  int t = threadIdx.x;
  if (t < 64) ein[t] = bond_emb[bt * 64 + t];
  else if (t < 72) ein[t] = emask_emb[m * 8 + (t - 64)];
  __syncthreads();
  float acc = b1[t];
  for (int k = 0; k < 72; ++k) acc = fmaf(ein[k], W1[k * 256 + t], acc);
  a1[t] = acc / (1.0f + expf(-acc));
  __syncthreads();
  float acc2 = b2[t];
  for (int k = 0; k < 256; ++k) acc2 = fmaf(a1[k], W2[k * 256 + t], acc2);
  out[bidx * 256 + t] = acc2;
}

// ---------------- layer-0 edge table: e_feat @ e0_W -> 10 x 448 (padded) -------
__global__ void e0_tab_kernel(const float* __restrict__ eftab, const float* __restrict__ e0W,
                              float* __restrict__ out) {
  __shared__ float ef[256];
  int bidx = blockIdx.x, t = threadIdx.x;
  if (t < 256) ef[t] = eftab[bidx * 256 + t];
  __syncthreads();
  if (t < W0) {
    float acc = 0.0f;
    if (t < W0_REAL) {
      for (int k = 0; k < 256; ++k) acc = fmaf(ef[k], e0W[k * W0_REAL + t], acc);
    }
    out[bidx * W0 + t] = acc;
  }
}

// ---------------- h0 build: [N, 448] bf16, 8-col chunks ------------------------
// ch 0..15: atom_emb; ch 16: nmask_emb; ch 17..48: ttab+cproj; ch 49..55: pad
__global__ void h0_kernel(const int* __restrict__ x, const int* __restrict__ nm,
                          const int* __restrict__ tnode, const int* __restrict__ batch,
                          const float* __restrict__ atom_emb, const float* __restrict__ nmask_emb,
                          const float* __restrict__ ttab, const float* __restrict__ cproj,
                          u16* __restrict__ h0, int N) {
  int idx = blockIdx.x * 256 + threadIdx.x;
  if (idx >= N * 56) return;
  int n = idx / 56;
  int ch = idx - n * 56;
  uint4 o;
  if (ch < 16) {
    const float* s = atom_emb + (size_t)x[n] * 128 + ch * 8;
    float4 a = *(const float4*)s, b = *(const float4*)(s + 4);
    o = pack8(a.x, a.y, a.z, a.w, b.x, b.y, b.z, b.w);
  } else if (ch == 16) {
    const float* s = nmask_emb + (size_t)nm[n] * 8;
    float4 a = *(const float4*)s, b = *(const float4*)(s + 4);
    o = pack8(a.x, a.y, a.z, a.w, b.x, b.y, b.z, b.w);
  } else if (ch < 49) {
    int cc = ch * 8 - 136;
    const float* ta = ttab + (size_t)tnode[n] * 256 + cc;
    const float* cb = cproj + (size_t)batch[n] * 256 + cc;
    float4 a = *(const float4*)ta, b = *(const float4*)(ta + 4);
    float4 c = *(const float4*)cb, d = *(const float4*)(cb + 4);
    o = pack8(a.x + c.x, a.y + c.y, a.z + c.z, a.w + c.w,
              b.x + d.x, b.y + d.y, b.z + d.z, b.w + d.w);
  } else {
    o = make_uint4(0, 0, 0, 0);
  }
  *(uint4*)(h0 + (size_t)n * W0 + ch * 8) = o;
}

// ---------------- CSR build ----------------------------------------------------
__global__ void deg_kernel(const int* __restrict__ dst, int* __restrict__ deg, int E) {
  int e = blockIdx.x * 256 + threadIdx.x;
  if (e < E) atomicAdd(&deg[dst[e]], 1);
}

__global__ void scan1_kernel(const int* __restrict__ deg, int* __restrict__ ro,
                             int* __restrict__ bsum, int N) {
  __shared__ int tmp[256];
  int tid = threadIdx.x, i = blockIdx.x * 256 + tid;
  int v = (i < N) ? deg[i] : 0;
  tmp[tid] = v;
  __syncthreads();
  for (int o = 1; o < 256; o <<= 1) {
    int t = (tid >= o) ? tmp[tid - o] : 0;
    __syncthreads();
    tmp[tid] += t;
    __syncthreads();
  }
  if (i < N) ro[i] = tmp[tid] - v;
  if (tid == 255) bsum[blockIdx.x] = tmp[255];
}

__global__ void scan2_kernel(int* __restrict__ bsum, int nb) {
  __shared__ int tmp[256];
  int tid = threadIdx.x;
  int v = (tid < nb) ? bsum[tid] : 0;
  tmp[tid] = v;
  __syncthreads();
  for (int o = 1; o < 256; o <<= 1) {
    int t = (tid >= o) ? tmp[tid - o] : 0;
    __syncthreads();
    tmp[tid] += t;
    __syncthreads();
  }
  if (tid < nb) bsum[tid] = tmp[tid] - v;
}

__global__ void scan3_kernel(int* __restrict__ ro, int* __restrict__ cur,
                             const int* __restrict__ bsum, int N, int E) {
  int i = blockIdx.x * 256 + threadIdx.x;
  if (i < N) {
    int r = ro[i] + bsum[blockIdx.x];
    ro[i] = r;
    cur[i] = r;
  }
  if (i == 0) ro[N] = E;
}

__global__ void fill_kernel(const int* __restrict__ src, const int* __restrict__ dst,
                            const int* __restrict__ ea, const int* __restrict__ em,
                            int* __restrict__ cur, int* __restrict__ csr, int E) {
  int e = blockIdx.x * 256 + threadIdx.x;
  if (e < E) {
    int d = dst[e];
    int pos = atomicAdd(&cur[d], 1);
    csr[pos] = src[e] | ((ea[e] * 2 + em[e]) << 20);
  }
}

// ---------------- aggregation + z = (1+eps)*h + sum relu(h[src]+e) -------------
__global__ __launch_bounds__(256) void agg_z_kernel(
    const u16* __restrict__ h, const float* __restrict__ etab,
    const int* __restrict__ ro, const int* __restrict__ csr,
    const float* __restrict__ epsp, u16* __restrict__ z, int N, int W) {
  int wid = threadIdx.x >> 6, lane = threadIdx.x & 63;
  int n = blockIdx.x * 4 + wid;
  if (n >= N) return;
  int s0 = ro[n], s1 = ro[n + 1];
  float eps1 = 1.0f + *epsp;

  for (int cbase = 0; cbase < W; cbase += 256) {
    int c4 = cbase + lane * 4;
    bool live = (c4 < W);
    int c4c = live ? c4 : (W - 4);
    float a0 = 0.f, a1 = 0.f, a2 = 0.f, a3 = 0.f;

    for (int base = s0; base < s1; base += 64) {
      int m = s1 - base; if (m > 64) m = 64;
      int pk = (lane < m) ? csr[base + lane] : 0;
      int j = 0;
      for (; j + 1 < m; j += 2) {
        int pa = __shfl(pk, j);
        int pb = __shfl(pk, j + 1);
        int sa = pa & 0xFFFFF, ea_ = pa >> 20;
        int sb = pb & 0xFFFFF, eb_ = pb >> 20;
        uint2 ha = *(const uint2*)(h + (size_t)sa * W + c4c);
        uint2 hb = *(const uint2*)(h + (size_t)sb * W + c4c);
        float4 va = *(const float4*)(etab + (size_t)ea_ * W + c4c);
        float4 vb = *(const float4*)(etab + (size_t)eb_ * W + c4c);
        a0 += fmaxf(bf2f((u16)(ha.x & 0xFFFF)) + va.x, 0.f);
        a1 += fmaxf(bf2f((u16)(ha.x >> 16))    + va.y, 0.f);
        a2 += fmaxf(bf2f((u16)(ha.y & 0xFFFF)) + va.z, 0.f);
        a3 += fmaxf(bf2f((u16)(ha.y >> 16))    + va.w, 0.f);
        a0 += fmaxf(bf2f((u16)(hb.x & 0xFFFF)) + vb.x, 0.f);
        a1 += fmaxf(bf2f((u16)(hb.x >> 16))    + vb.y, 0.f);
        a2 += fmaxf(bf2f((u16)(hb.y & 0xFFFF)) + vb.z, 0.f);
        a3 += fmaxf(bf2f((u16)(hb.y >> 16))    + vb.w, 0.f);
      }
      if (j < m) {
        int pa = __shfl(pk, j);
        int sa = pa & 0xFFFFF, ea_ = pa >> 20;
        uint2 ha = *(const uint2*)(h + (size_t)sa * W + c4c);
        float4 va = *(const float4*)(etab + (size_t)ea_ * W + c4c);
        a0 += fmaxf(bf2f((u16)(ha.x & 0xFFFF)) + va.x, 0.f);
        a1 += fmaxf(bf2f((u16)(ha.x >> 16))    + va.y, 0.f);
        a2 += fmaxf(bf2f((u16)(ha.y & 0xFFFF)) + va.z, 0.f);
        a3 += fmaxf(bf2f((u16)(ha.y >> 16))    + va.w, 0.f);
      }
    }

    if (live) {
      uint2 hn = *(const uint2*)(h + (size_t)n * W + c4);
      float z0 = eps1 * bf2f((u16)(hn.x & 0xFFFF)) + a0;
      float z1 = eps1 * bf2f((u16)(hn.x >> 16))    + a1;
      float z2 = eps1 * bf2f((u16)(hn.y & 0xFFFF)) + a2;
      float z3 = eps1 * bf2f((u16)(hn.y >> 16))    + a3;
      uint2 o;
      o.x = (u32)f2bf(z0) | ((u32)f2bf(z1) << 16);
      o.y = (u32)f2bf(z2) | ((u32)f2bf(z3) << 16);
      *(uint2*)(z + (size_t)n * W + c4) = o;
    }
  }
}

// ---------------- bf16 MFMA GEMM: C[M,256] = silu(((A@B)+bias)*scale+shift) ----
// Block: 128 rows x full 256 cols. BK=64, XOR-swizzled LDS chunks (conflict-free
// fragment reads, 128B-coalesced global segments). Coalesced epilogue via LDS.
__device__ __forceinline__ void g2l16(const u16* g, u16* l) {
  __builtin_amdgcn_global_load_lds(
      (__attribute__((address_space(1))) u32*)g,
      (__attribute__((address_space(3))) u32*)l, 16, 0, 0);
}

__global__ __launch_bounds__(256, 2) void gemm_fused(
    const u16* __restrict__ A, const u16* __restrict__ BT,
    const float* __restrict__ bias, const float* __restrict__ scale,
    const float* __restrict__ shift, u16* __restrict__ C, int M, int K) {
  __shared__ __align__(16) u16 smem[32768];   // 64 KB: staging (48 KB) / epilogue (64 KB)
  u16* lA = smem;                // 128 rows x 64 k  (8192 u16)
  u16* lB = smem + 8192;         // 256 rows x 64 k  (16384 u16)
  int tid = threadIdx.x;
  int wid = tid >> 6, lane = tid & 63;
  int q = lane >> 4, rr = lane & 15;
  int m0 = blockIdx.x * 128;
  int lr = lane >> 3;                       // row within an 8-row DMA group
  int swz = (lane & 7) ^ (lr & 7);          // swizzled k-chunk this lane fetches

  f32x4 acc[2][16] = {};

  for (int k0 = 0; k0 < K; k0 += 64) {
#pragma unroll
    for (int p = 0; p < 4; ++p) {           // A tile: 16 KB
      int idx = wid * 4 + p;                // 0..15
      int gr = m0 + idx * 8 + lr;
      if (gr >= M) gr = M - 1;
      g2l16(A + (size_t)gr * K + k0 + swz * 8, lA + idx * 512);
    }
#pragma unroll
    for (int p = 0; p < 8; ++p) {           // B tile: 32 KB
      int idx = wid * 8 + p;                // 0..31
      int nr = idx * 8 + lr;
      g2l16(BT + (size_t)nr * K + k0 + swz * 8, lB + idx * 512);
    }
    __syncthreads();
#pragma unroll
    for (int ks = 0; ks < 2; ++ks) {
      int ch = (ks << 2) | q;
      int r0 = wid * 32 + rr;
      bf16x8 a0 = *(const bf16x8*)&lA[r0 * 64 + ((ch ^ (rr & 7)) << 3)];
      bf16x8 a1 = *(const bf16x8*)&lA[(r0 + 16) * 64 + ((ch ^ (rr & 7)) << 3)];
#pragma unroll
      for (int ct = 0; ct < 16; ++ct) {
        int n = ct * 16 + rr;
        bf16x8 b = *(const bf16x8*)&lB[n * 64 + ((ch ^ (rr & 7)) << 3)];
        acc[0][ct] = __builtin_amdgcn_mfma_f32_16x16x32_bf16(a0, b, acc[0][ct], 0, 0, 0);
        acc[1][ct] = __builtin_amdgcn_mfma_f32_16x16x32_bf16(a1, b, acc[1][ct], 0, 0, 0);
      }
    }
    __syncthreads();
  }

  // epilogue: fused bias/BN/SiLU -> per-wave LDS slice -> coalesced dwordx4 stores
  u16* slice = smem + wid * 8192;           // 32 rows x 256 cols per wave
#pragma unroll
  for (int ct = 0; ct < 16; ++ct) {
    int c = ct * 16 + rr;
    float b = bias[c];
    float sc = scale ? scale[c] * 0.9999950000374997f : 1.0f;   // gamma/sqrt(1+1e-5)
    float sh = shift ? shift[c] : 0.0f;
#pragma unroll
    for (int rt = 0; rt < 2; ++rt)
#pragma unroll
      for (int i = 0; i < 4; ++i) {
        float y = (acc[rt][ct][i] + b) * sc + sh;
        slice[(rt * 16 + q * 4 + i) * 256 + c] = f2bf(siluf(y));
      }
  }
  __syncthreads();
  int rbase = m0 + wid * 32;
#pragma unroll
  for (int j = 0; j < 16; ++j) {
    int off = j * 512 + lane * 8;           // u16 index within slice
    int rloc = off >> 8;
    if (rbase + rloc < M)
      *(uint4*)(C + (size_t)(rbase + rloc) * 256 + (off & 255)) =
          *(const uint4*)(slice + off);
  }
}

// ---------------- MFMA head GEMM: [N,256] @ [256,32] -> atom_out[N,16], P[N,8(5)]
__global__ __launch_bounds__(256) void head_gemm(
    const u16* __restrict__ A, const u16* __restrict__ WT,
    const float* __restrict__ atomB,
    float* __restrict__ atom_out, float* __restrict__ P, int M) {
  __shared__ __align__(16) u16 lA[128 * 32];
  __shared__ __align__(16) u16 lB[32 * 264];
  int tid = threadIdx.x;
  int wid = tid >> 6, lane = tid & 63;
  int q = lane >> 4, rr = lane & 15;
  int m0 = blockIdx.x * 128;

  for (int i = tid; i < 32 * 256; i += 256)
    lB[(i >> 8) * 264 + (i & 255)] = WT[i];

  f32x4 acc[2][2] = {};
  int arow = tid >> 2, acol = (tid & 3) * 8;

  for (int k0 = 0; k0 < 256; k0 += 32) {
#pragma unroll
    for (int p = 0; p < 2; ++p) {
      int gr = m0 + p * 64 + arow;
      if (gr >= M) gr = M - 1;
      g2l16(A + (size_t)gr * 256 + k0 + acol, &lA[p * 2048 + wid * 512]);
    }
    __syncthreads();
    bf16x8 af[2], bfr[2];
#pragma unroll
    for (int mt = 0; mt < 2; ++mt)
      af[mt] = *(const bf16x8*)&lA[(wid * 32 + mt * 16 + rr) * 32 + q * 8];
#pragma unroll
    for (int nt = 0; nt < 2; ++nt)
      bfr[nt] = *(const bf16x8*)&lB[(nt * 16 + rr) * 264 + k0 + q * 8];
#pragma unroll
    for (int mt = 0; mt < 2; ++mt)
#pragma unroll
      for (int nt = 0; nt < 2; ++nt)
        acc[mt][nt] = __builtin_amdgcn_mfma_f32_16x16x32_bf16(af[mt], bfr[nt], acc[mt][nt], 0, 0, 0);
    __syncthreads();
  }

#pragma unroll
  for (int nt = 0; nt < 2; ++nt) {
    int c = nt * 16 + rr;
    float bb = (c < 16) ? atomB[c] : 0.0f;
#pragma unroll
    for (int mt = 0; mt < 2; ++mt) {
      int rbase = m0 + wid * 32 + mt * 16 + q * 4;
#pragma unroll
      for (int r2 = 0; r2 < 4; ++r2) {
        int row = rbase + r2;
        if (row < M) {
          float v = acc[mt][nt][r2];
          if (c < 16) atom_out[(size_t)row * 16 + c] = v + bb;
          else if (c < 21) P[(size_t)row * 8 + (c - 16)] = v;
        }
      }
    }
  }
}

// ---------------- bond edge output: out[e] = P[src]+P[dst]+b -------------------
__global__ __launch_bounds__(256) void bond_edge(
    const float* __restrict__ P, const int* __restrict__ src,
    const int* __restrict__ dst, const float* __restrict__ b,
    float* __restrict__ out, int E) {
  __shared__ float so[256 * 5];
  int t = threadIdx.x;
  int e = blockIdx.x * 256 + t;
  float v0 = 0, v1 = 0, v2 = 0, v3 = 0, v4 = 0;
  if (e < E) {
    int s = src[e], d = dst[e];
    float4 ps = *(const float4*)(P + (size_t)s * 8);
    float  p4s = P[(size_t)s * 8 + 4];
    float4 pd = *(const float4*)(P + (size_t)d * 8);
    float  p4d = P[(size_t)d * 8 + 4];
    v0 = ps.x + pd.x + b[0];
    v1 = ps.y + pd.y + b[1];
    v2 = ps.z + pd.z + b[2];
    v3 = ps.w + pd.w + b[3];
    v4 = p4s + p4d + b[4];
  }
  so[t * 5 + 0] = v0; so[t * 5 + 1] = v1; so[t * 5 + 2] = v2;
  so[t * 5 + 3] = v3; so[t * 5 + 4] = v4;
  __syncthreads();
  size_t base = (size_t)blockIdx.x * 256 * 5;
  size_t lim = (size_t)E * 5;
  for (int i = t; i < 256 * 5; i += 256) {
    size_t g = base + i;
    if (g < lim) out[g] = so[i];
  }
}

// ---------------- host ---------------------------------------------------------
extern "C" void kernel_launch(void* const* d_in, const int* in_sizes, int n_in,
                              void* d_out, int out_size, void* d_ws, size_t ws_size,
                              hipStream_t stream) {
  const int*   x_noisy   = (const int*)d_in[0];
  const int*   nmaskobs  = (const int*)d_in[1];
  const int*   ea        = (const int*)d_in[2];
  const int*   em        = (const int*)d_in[3];
  const int*   eidx      = (const int*)d_in[4];
  const int*   tnode     = (const int*)d_in[5];
  const float* cvec      = (const float*)d_in[6];
  const int*   batch     = (const int*)d_in[7];
  const float* atom_emb  = (const float*)d_in[8];
  const float* bond_emb  = (const float*)d_in[9];
  const float* nmask_emb = (const float*)d_in[10];
  const float* emask_emb = (const float*)d_in[11];
  const float* t_W1      = (const float*)d_in[12];
  const float* t_b1      = (const float*)d_in[13];
  const float* t_W2      = (const float*)d_in[14];
  const float* t_b2      = (const float*)d_in[15];
  const float* cond_W    = (const float*)d_in[16];
  const float* cond_b    = (const float*)d_in[17];
  const float* edge_W1   = (const float*)d_in[18];
  const float* edge_b1   = (const float*)d_in[19];
  const float* edge_W2   = (const float*)d_in[20];
  const float* edge_b2   = (const float*)d_in[21];
  const float* e0_W      = (const float*)d_in[22];
  const float* conv0_W1  = (const float*)d_in[23];
  const float* conv0_b1  = (const float*)d_in[24];
  const float* conv0_W2  = (const float*)d_in[25];
  const float* conv0_b2  = (const float*)d_in[26];
  const float* conv0_eps = (const float*)d_in[27];
  const float* convs_W1  = (const float*)d_in[28];
  const float* convs_b1  = (const float*)d_in[29];
  const float* convs_W2  = (const float*)d_in[30];
  const float* convs_b2  = (const float*)d_in[31];
  const float* convs_eps = (const float*)d_in[32];
  const float* bn_gamma  = (const float*)d_in[33];
  const float* bn_beta   = (const float*)d_in[34];
  const float* atom_W    = (const float*)d_in[35];
  const float* atom_b    = (const float*)d_in[36];
  const float* bond_W    = (const float*)d_in[37];
  const float* bond_b    = (const float*)d_in[38];

  const int N = in_sizes[0];
  const int E = in_sizes[2];
  const int B = in_sizes[6] / 2;
  const int* srcp = eidx;
  const int* dstp = eidx + E;

  char* base = (char*)d_ws;
  size_t off = 0;
  auto alloc = [&](size_t bytes) -> char* {
    char* p = base + off;
    off = (off + bytes + 255) & ~(size_t)255;
    return p;
  };
  u16* h0   = (u16*)alloc((size_t)N * W0 * 2);     // reused as h [N,256] after layer 0
  u16* z0   = (u16*)alloc((size_t)N * W0 * 2);     // reused as z [N,256]
  u16* ubuf = (u16*)alloc((size_t)N * DM * 2);
  u16* w10t = (u16*)alloc((size_t)DM * W0 * 2);
  u16* w20t = (u16*)alloc((size_t)DM * DM * 2);
  u16* wc1t = (u16*)alloc((size_t)5 * DM * DM * 2);
  u16* wc2t = (u16*)alloc((size_t)5 * DM * DM * 2);
  u16* wht  = (u16*)alloc((size_t)32 * DM * 2);
  float* ttab  = (float*)alloc((size_t)200 * DM * 4);
  float* cprojb= (float*)alloc((size_t)B * DM * 4);
  float* eftab = (float*)alloc((size_t)10 * DM * 4);
  float* e0tab = (float*)alloc((size_t)10 * W0 * 4);
  float* Pbuf  = (float*)alloc((size_t)N * 8 * 4);
  int* deg  = (int*)alloc((size_t)N * 4);
  int* ro   = (int*)alloc((size_t)(N + 1) * 4);
  int* cur  = (int*)alloc((size_t)N * 4);
  int* csr  = (int*)alloc((size_t)E * 4);
  int* bsum = (int*)alloc((size_t)256 * 4);
  (void)ws_size; (void)n_in; (void)out_size;

  u16* hbuf = h0;
  u16* zbuf = z0;
  float* atom_out = (float*)d_out;
  float* bond_out = atom_out + (size_t)N * 16;

  hipMemsetAsync(deg, 0, (size_t)N * 4, stream);

  // precompute: weights (transposed bf16), tables
  wT_kernel<<<(DM * W0 + 255) / 256, 256, 0, stream>>>(conv0_W1, w10t, 1, W0_REAL, W0, DM);
  wT_kernel<<<(DM * DM + 255) / 256, 256, 0, stream>>>(conv0_W2, w20t, 1, DM, DM, DM);
  wT_kernel<<<(5 * DM * DM + 255) / 256, 256, 0, stream>>>(convs_W1, wc1t, 5, DM, DM, DM);
  wT_kernel<<<(5 * DM * DM + 255) / 256, 256, 0, stream>>>(convs_W2, wc2t, 5, DM, DM, DM);
  whead_kernel<<<32, 256, 0, stream>>>(atom_W, bond_W, wht);
  t_table_kernel<<<200, 256, 0, stream>>>(t_W1, t_b1, t_W2, t_b2, ttab);
  cproj_kernel<<<(B * DM + 255) / 256, 256, 0, stream>>>(cvec, cond_W, cond_b, cprojb, B);
  ef_tab_kernel<<<10, 256, 0, stream>>>(bond_emb, emask_emb, edge_W1, edge_b1, edge_W2, edge_b2, eftab);
  e0_tab_kernel<<<10, 512, 0, stream>>>(eftab, e0_W, e0tab);
  h0_kernel<<<(N * 56 + 255) / 256, 256, 0, stream>>>(x_noisy, nmaskobs, tnode, batch,
      atom_emb, nmask_emb, ttab, cprojb, h0, N);
  // CSR by dst
  const int nscan = (N + 255) / 256;
  deg_kernel<<<(E + 255) / 256, 256, 0, stream>>>(dstp, deg, E);
  scan1_kernel<<<nscan, 256, 0, stream>>>(deg, ro, bsum, N);
  scan2_kernel<<<1, 256, 0, stream>>>(bsum, nscan);
  scan3_kernel<<<nscan, 256, 0, stream>>>(ro, cur, bsum, N, E);
  fill_kernel<<<(E + 255) / 256, 256, 0, stream>>>(srcp, dstp, ea, em, cur, csr, E);

  const int ggrid = (N + 127) / 128;
  const int nagg = (N + 3) / 4;
  // layer 0
  agg_z_kernel<<<nagg, 256, 0, stream>>>(h0, e0tab, ro, csr, conv0_eps, z0, N, W0);
  gemm_fused<<<ggrid, 256, 0, stream>>>(z0, w10t, conv0_b1, nullptr, nullptr, ubuf, N, W0);
  gemm_fused<<<ggrid, 256, 0, stream>>>(ubuf, w20t, conv0_b2, bn_gamma, bn_beta, hbuf, N, DM);
  // layers 1..5
  for (int i = 0; i < 5; ++i) {
    agg_z_kernel<<<nagg, 256, 0, stream>>>(hbuf, eftab, ro, csr, convs_eps + i, zbuf, N, DM);
    gemm_fused<<<ggrid, 256, 0, stream>>>(zbuf, wc1t + (size_t)i * DM * DM, convs_b1 + i * DM,
                                          nullptr, nullptr, ubuf, N, DM);
    gemm_fused<<<ggrid, 256, 0, stream>>>(ubuf, wc2t + (size_t)i * DM * DM, convs_b2 + i * DM,
                                          bn_gamma + (i + 1) * DM, bn_beta + (i + 1) * DM, hbuf, N, DM);
  }
  // heads
  head_gemm<<<(N + 127) / 128, 256, 0, stream>>>(hbuf, wht, atom_b, atom_out, Pbuf, N);
  bond_edge<<<(E + 255) / 256, 256, 0, stream>>>(Pbuf, srcp, dstp, bond_b, bond_out, E);
}

// Round 6
// 705.458 us; speedup vs baseline: 1.9569x; 1.0107x over previous
//
#include <hip/hip_runtime.h>
#include <cstdint>
#include <cmath>

typedef unsigned short u16;
typedef unsigned int   u32;

using bf16x8 = __attribute__((ext_vector_type(8))) short;
using f32x4  = __attribute__((ext_vector_type(4))) float;

#define DM 256        // d_model
#define W0 448        // layer-0 input width padded 392 -> 448 (multiple of 64)
#define W0_REAL 392

__device__ __forceinline__ float bf2f(u16 v) {
  union { u32 u; float f; } c; c.u = ((u32)v) << 16; return c.f;
}
__device__ __forceinline__ u16 f2bf(float f) {
  union { float f; u32 u; } c; c.f = f;
  u32 u = c.u;
  return (u16)((u + 0x7FFFu + ((u >> 16) & 1u)) >> 16);  // RNE
}
__device__ __forceinline__ float siluf(float y) {
  return y / (1.0f + __expf(-y));
}
__device__ __forceinline__ uint4 pack8(float f0, float f1, float f2, float f3,
                                       float f4, float f5, float f6, float f7) {
  uint4 o;
  o.x = (u32)f2bf(f0) | ((u32)f2bf(f1) << 16);
  o.y = (u32)f2bf(f2) | ((u32)f2bf(f3) << 16);
  o.z = (u32)f2bf(f4) | ((u32)f2bf(f5) << 16);
  o.w = (u32)f2bf(f6) | ((u32)f2bf(f7) << 16);
  return o;
}
// acc += relu(bf16x8(hv) + e[0..7]) elementwise
__device__ __forceinline__ void acc8(float4& lo, float4& hi, uint4 hv,
                                     float4 ea, float4 eb) {
  lo.x += fmaxf(bf2f((u16)(hv.x & 0xFFFF)) + ea.x, 0.f);
  lo.y += fmaxf(bf2f((u16)(hv.x >> 16))    + ea.y, 0.f);
  lo.z += fmaxf(bf2f((u16)(hv.y & 0xFFFF)) + ea.z, 0.f);
  lo.w += fmaxf(bf2f((u16)(hv.y >> 16))    + ea.w, 0.f);
  hi.x += fmaxf(bf2f((u16)(hv.z & 0xFFFF)) + eb.x, 0.f);
  hi.y += fmaxf(bf2f((u16)(hv.z >> 16))    + eb.y, 0.f);
  hi.z += fmaxf(bf2f((u16)(hv.w & 0xFFFF)) + eb.z, 0.f);
  hi.w += fmaxf(bf2f((u16)(hv.w >> 16))    + eb.w, 0.f);
}

// ---------------- weight transpose + bf16 convert: out[n*Kpad+k] = W[k*Nc+n] ----
__global__ void wT_kernel(const float* __restrict__ W, u16* __restrict__ out,
                          int nmat, int K, int Kpad, int Nc) {
  int idx = blockIdx.x * 256 + threadIdx.x;
  int tot = nmat * Nc * Kpad;
  if (idx >= tot) return;
  int m = idx / (Nc * Kpad);
  int r = idx - m * (Nc * Kpad);
  int n = r / Kpad;
  int k = r - n * Kpad;
  float v = (k < K) ? W[(size_t)m * K * Nc + (size_t)k * Nc + n] : 0.0f;
  out[idx] = f2bf(v);
}

// ---------------- combined head weight: [32,256] bf16 --------------------------
__global__ void whead_kernel(const float* __restrict__ atomW, const float* __restrict__ bondW,
                             u16* __restrict__ out) {
  int idx = blockIdx.x * 256 + threadIdx.x;
  if (idx >= 32 * 256) return;
  int j = idx >> 8, k = idx & 255;
  float v = 0.0f;
  if (j < 16) v = atomW[k * 16 + j];
  else if (j < 21) v = bondW[k * 5 + (j - 16)];
  out[idx] = f2bf(v);
}

// ---------------- timestep MLP table: 200 x 256 (f32) --------------------------
__global__ void t_table_kernel(const float* __restrict__ W1, const float* __restrict__ b1,
                               const float* __restrict__ W2, const float* __restrict__ b2,
                               float* __restrict__ out) {
  __shared__ float s[256];
  __shared__ float a1[256];
  int r = blockIdx.x, t = threadIdx.x;
  float tv = (float)r;
  float coef = -logf(10000.0f) / 127.0f;
  int j = t & 127;
  float ang = tv * expf(coef * (float)j);
  s[t] = (t < 128) ? sinf(ang) : cosf(ang);
  __syncthreads();
  float acc = b1[t];
  for (int k = 0; k < 256; ++k) acc = fmaf(s[k], W1[k * 256 + t], acc);
  a1[t] = acc / (1.0f + expf(-acc));
  __syncthreads();
  float acc2 = b2[t];
  for (int k = 0; k < 256; ++k) acc2 = fmaf(a1[k], W2[k * 256 + t], acc2);
  out[r * 256 + t] = acc2;
}

// ---------------- cond projection: B x 256 (f32) -------------------------------
__global__ void cproj_kernel(const float* __restrict__ cv, const float* __restrict__ W,
                             const float* __restrict__ b, float* __restrict__ out, int B) {
  int i = blockIdx.x * 256 + threadIdx.x;
  if (i < B * 256) {
    int g = i >> 8, c = i & 255;
    out[i] = fmaf(cv[g * 2], W[c], fmaf(cv[g * 2 + 1], W[256 + c], b[c]));
  }
}

// ---------------- edge-feature table: 10 x 256 (f32) ---------------------------
__global__ void ef_tab_kernel(const float* __restrict__ bond_emb, const float* __restrict__ emask_emb,
                              const float* __restrict__ W1, const float* __restrict__ b1,
                              const float* __restrict__ W2, const float* __restrict__ b2,
                              float* __restrict__ out) {
  __shared__ float ein[72];
  __shared__ float a1[256];
  int bidx = blockIdx.x;           // 0..9
  int bt = bidx >> 1, m = bidx & 1;
  int t = threadIdx.x;
  if (t < 64) ein[t] = bond_emb[bt * 64 + t];
  else if (t < 72) ein[t] = emask_emb[m * 8 + (t - 64)];
  __syncthreads();
  float acc = b1[t];
  for (int k = 0; k < 72; ++k) acc = fmaf(ein[k], W1[k * 256 + t], acc);
  a1[t] = acc / (1.0f + expf(-acc));
  __syncthreads();
  float acc2 = b2[t];
  for (int k = 0; k < 256; ++k) acc2 = fmaf(a1[k], W2[k * 256 + t], acc2);
  out[bidx * 256 + t] = acc2;
}

// ---------------- layer-0 edge table: e_feat @ e0_W -> 10 x 448 (padded) -------
__global__ void e0_tab_kernel(const float* __restrict__ eftab, const float* __restrict__ e0W,
                              float* __restrict__ out) {
  __shared__ float ef[256];
  int bidx = blockIdx.x, t = threadIdx.x;
  if (t < 256) ef[t] = eftab[bidx * 256 + t];
  __syncthreads();
  if (t < W0) {
    float acc = 0.0f;
    if (t < W0_REAL) {
      for (int k = 0; k < 256; ++k) acc = fmaf(ef[k], e0W[k * W0_REAL + t], acc);
    }
    out[bidx * W0 + t] = acc;
  }
}

// ---------------- h0 build: [N, 448] bf16, 8-col chunks ------------------------
__global__ void h0_kernel(const int* __restrict__ x, const int* __restrict__ nm,
                          const int* __restrict__ tnode, const int* __restrict__ batch,
                          const float* __restrict__ atom_emb, const float* __restrict__ nmask_emb,
                          const float* __restrict__ ttab, const float* __restrict__ cproj,
                          u16* __restrict__ h0, int N) {
  int idx = blockIdx.x * 256 + threadIdx.x;
  if (idx >= N * 56) return;
  int n = idx / 56;
  int ch = idx - n * 56;
  uint4 o;
  if (ch < 16) {
    const float* s = atom_emb + (size_t)x[n] * 128 + ch * 8;
    float4 a = *(const float4*)s, b = *(const float4*)(s + 4);
    o = pack8(a.x, a.y, a.z, a.w, b.x, b.y, b.z, b.w);
  } else if (ch == 16) {
    const float* s = nmask_emb + (size_t)nm[n] * 8;
    float4 a = *(const float4*)s, b = *(const float4*)(s + 4);
    o = pack8(a.x, a.y, a.z, a.w, b.x, b.y, b.z, b.w);
  } else if (ch < 49) {
    int cc = ch * 8 - 136;
    const float* ta = ttab + (size_t)tnode[n] * 256 + cc;
    const float* cb = cproj + (size_t)batch[n] * 256 + cc;
    float4 a = *(const float4*)ta, b = *(const float4*)(ta + 4);
    float4 c = *(const float4*)cb, d = *(const float4*)(cb + 4);
    o = pack8(a.x + c.x, a.y + c.y, a.z + c.z, a.w + c.w,
              b.x + d.x, b.y + d.y, b.z + d.z, b.w + d.w);
  } else {
    o = make_uint4(0, 0, 0, 0);
  }
  *(uint4*)(h0 + (size_t)n * W0 + ch * 8) = o;
}

// ---------------- CSR build ----------------------------------------------------
__global__ void deg_kernel(const int* __restrict__ dst, int* __restrict__ deg, int E) {
  int e = blockIdx.x * 256 + threadIdx.x;
  if (e < E) atomicAdd(&deg[dst[e]], 1);
}

__global__ void scan1_kernel(const int* __restrict__ deg, int* __restrict__ ro,
                             int* __restrict__ bsum, int N) {
  __shared__ int tmp[256];
  int tid = threadIdx.x, i = blockIdx.x * 256 + tid;
  int v = (i < N) ? deg[i] : 0;
  tmp[tid] = v;
  __syncthreads();
  for (int o = 1; o < 256; o <<= 1) {
    int t = (tid >= o) ? tmp[tid - o] : 0;
    __syncthreads();
    tmp[tid] += t;
    __syncthreads();
  }
  if (i < N) ro[i] = tmp[tid] - v;
  if (tid == 255) bsum[blockIdx.x] = tmp[255];
}

__global__ void scan2_kernel(int* __restrict__ bsum, int nb) {
  __shared__ int tmp[256];
  int tid = threadIdx.x;
  int v = (tid < nb) ? bsum[tid] : 0;
  tmp[tid] = v;
  __syncthreads();
  for (int o = 1; o < 256; o <<= 1) {
    int t = (tid >= o) ? tmp[tid - o] : 0;
    __syncthreads();
    tmp[tid] += t;
    __syncthreads();
  }
  if (tid < nb) bsum[tid] = tmp[tid] - v;
}

__global__ void scan3_kernel(int* __restrict__ ro, int* __restrict__ cur,
                             const int* __restrict__ bsum, int N, int E) {
  int i = blockIdx.x * 256 + threadIdx.x;
  if (i < N) {
    int r = ro[i] + bsum[blockIdx.x];
    ro[i] = r;
    cur[i] = r;
  }
  if (i == 0) ro[N] = E;
}

__global__ void fill_kernel(const int* __restrict__ src, const int* __restrict__ dst,
                            const int* __restrict__ ea, const int* __restrict__ em,
                            int* __restrict__ cur, int* __restrict__ csr, int E) {
  int e = blockIdx.x * 256 + threadIdx.x;
  if (e < E) {
    int d = dst[e];
    int pos = atomicAdd(&cur[d], 1);
    csr[pos] = src[e] | ((ea[e] * 2 + em[e]) << 20);
  }
}

// ---------------- agg (W=256): 2 edges per wave, lane owns 8 cols --------------
__global__ __launch_bounds__(256) void agg_z256(
    const u16* __restrict__ h, const float* __restrict__ etab,
    const int* __restrict__ ro, const int* __restrict__ csr,
    const float* __restrict__ epsp, u16* __restrict__ z, int N) {
  int wid = threadIdx.x >> 6, lane = threadIdx.x & 63;
  int n = blockIdx.x * 4 + wid;
  if (n >= N) return;
  int s0 = ro[n], s1 = ro[n + 1];
  float eps1 = 1.0f + *epsp;
  int half = lane >> 5, li = lane & 31;
  int c8 = li * 8;
  float4 aLo = {0, 0, 0, 0}, aHi = {0, 0, 0, 0};

  for (int base = s0; base < s1; base += 64) {
    int m = s1 - base; if (m > 64) m = 64;
    int pk = (lane < m) ? csr[base + lane] : 0;
    int j = 0;
    for (; j + 3 < m; j += 4) {       // 4 edges per iter (2 per half-wave pair)
      int p0 = __shfl(pk, j + half);
      int p1 = __shfl(pk, j + 2 + half);
      uint4 h0v = *(const uint4*)(h + (size_t)(p0 & 0xFFFFF) * 256 + c8);
      uint4 h1v = *(const uint4*)(h + (size_t)(p1 & 0xFFFFF) * 256 + c8);
      const float* e0p = etab + (size_t)(p0 >> 20) * 256 + c8;
      const float* e1p = etab + (size_t)(p1 >> 20) * 256 + c8;
      float4 e0a = *(const float4*)e0p, e0b = *(const float4*)(e0p + 4);
      float4 e1a = *(const float4*)e1p, e1b = *(const float4*)(e1p + 4);
      acc8(aLo, aHi, h0v, e0a, e0b);
      acc8(aLo, aHi, h1v, e1a, e1b);
    }
    for (; j < m; j += 2) {           // tail (up to 3 edges)
      int idx = j + half;
      bool act = idx < m;
      int p = __shfl(pk, act ? idx : (m - 1));
      uint4 hv = *(const uint4*)(h + (size_t)(p & 0xFFFFF) * 256 + c8);
      const float* ep = etab + (size_t)(p >> 20) * 256 + c8;
      float4 ea = *(const float4*)ep, eb = *(const float4*)(ep + 4);
      if (act) acc8(aLo, aHi, hv, ea, eb);
    }
  }
  // fold half-1 partial sums into half-0
  aLo.x += __shfl(aLo.x, li + 32); aLo.y += __shfl(aLo.y, li + 32);
  aLo.z += __shfl(aLo.z, li + 32); aLo.w += __shfl(aLo.w, li + 32);
  aHi.x += __shfl(aHi.x, li + 32); aHi.y += __shfl(aHi.y, li + 32);
  aHi.z += __shfl(aHi.z, li + 32); aHi.w += __shfl(aHi.w, li + 32);
  if (half == 0) {
    uint4 hn = *(const uint4*)(h + (size_t)n * 256 + c8);
    uint4 o = pack8(
        eps1 * bf2f((u16)(hn.x & 0xFFFF)) + aLo.x,
        eps1 * bf2f((u16)(hn.x >> 16))    + aLo.y,
        eps1 * bf2f((u16)(hn.y & 0xFFFF)) + aLo.z,
        eps1 * bf2f((u16)(hn.y >> 16))    + aLo.w,
        eps1 * bf2f((u16)(hn.z & 0xFFFF)) + aHi.x,
        eps1 * bf2f((u16)(hn.z >> 16))    + aHi.y,
        eps1 * bf2f((u16)(hn.w & 0xFFFF)) + aHi.z,
        eps1 * bf2f((u16)(hn.w >> 16))    + aHi.w);
    *(uint4*)(z + (size_t)n * 256 + c8) = o;
  }
}

// ---------------- agg (W=448, layer 0): lane owns 8 cols, 56 live lanes --------
__global__ __launch_bounds__(256) void agg_z448(
    const u16* __restrict__ h, const float* __restrict__ etab,
    const int* __restrict__ ro, const int* __restrict__ csr,
    const float* __restrict__ epsp, u16* __restrict__ z, int N) {
  int wid = threadIdx.x >> 6, lane = threadIdx.x & 63;
  int n = blockIdx.x * 4 + wid;
  if (n >= N) return;
  int s0 = ro[n], s1 = ro[n + 1];
  float eps1 = 1.0f + *epsp;
  bool live = lane < 56;
  int c8 = live ? lane * 8 : 440;    // clamp dead lanes to a harmless chunk
  float4 aLo = {0, 0, 0, 0}, aHi = {0, 0, 0, 0};

  for (int base = s0; base < s1; base += 64) {
    int m = s1 - base; if (m > 64) m = 64;
    int pk = (lane < m) ? csr[base + lane] : 0;
    int j = 0;
    for (; j + 1 < m; j += 2) {
      int p0 = __shfl(pk, j);
      int p1 = __shfl(pk, j + 1);
      uint4 h0v = *(const uint4*)(h + (size_t)(p0 & 0xFFFFF) * W0 + c8);
      uint4 h1v = *(const uint4*)(h + (size_t)(p1 & 0xFFFFF) * W0 + c8);
      const float* e0p = etab + (size_t)(p0 >> 20) * W0 + c8;
      const float* e1p = etab + (size_t)(p1 >> 20) * W0 + c8;
      float4 e0a = *(const float4*)e0p, e0b = *(const float4*)(e0p + 4);
      float4 e1a = *(const float4*)e1p, e1b = *(const float4*)(e1p + 4);
      acc8(aLo, aHi, h0v, e0a, e0b);
      acc8(aLo, aHi, h1v, e1a, e1b);
    }
    if (j < m) {
      int p = __shfl(pk, j);
      uint4 hv = *(const uint4*)(h + (size_t)(p & 0xFFFFF) * W0 + c8);
      const float* ep = etab + (size_t)(p >> 20) * W0 + c8;
      float4 ea = *(const float4*)ep, eb = *(const float4*)(ep + 4);
      acc8(aLo, aHi, hv, ea, eb);
    }
  }
  if (live) {
    uint4 hn = *(const uint4*)(h + (size_t)n * W0 + c8);
    uint4 o = pack8(
        eps1 * bf2f((u16)(hn.x & 0xFFFF)) + aLo.x,
        eps1 * bf2f((u16)(hn.x >> 16))    + aLo.y,
        eps1 * bf2f((u16)(hn.y & 0xFFFF)) + aLo.z,
        eps1 * bf2f((u16)(hn.y >> 16))    + aLo.w,
        eps1 * bf2f((u16)(hn.z & 0xFFFF)) + aHi.x,
        eps1 * bf2f((u16)(hn.z >> 16))    + aHi.y,
        eps1 * bf2f((u16)(hn.w & 0xFFFF)) + aHi.z,
        eps1 * bf2f((u16)(hn.w >> 16))    + aHi.w);
    *(uint4*)(z + (size_t)n * W0 + c8) = o;
  }
}

// ---------------- bf16 MFMA GEMM: C[M,256] = silu(((A@B)+bias)*scale+shift) ----
__device__ __forceinline__ void g2l16(const u16* g, u16* l) {
  __builtin_amdgcn_global_load_lds(
      (__attribute__((address_space(1))) u32*)g,
      (__attribute__((address_space(3))) u32*)l, 16, 0, 0);
}

__global__ __launch_bounds__(256, 2) void gemm_fused(
    const u16* __restrict__ A, const u16* __restrict__ BT,
    const float* __restrict__ bias, const float* __restrict__ scale,
    const float* __restrict__ shift, u16* __restrict__ C, int M, int K) {
  __shared__ __align__(16) u16 smem[32768];   // 64 KB: staging (48 KB) / epilogue (64 KB)
  u16* lA = smem;                // 128 rows x 64 k  (8192 u16)
  u16* lB = smem + 8192;         // 256 rows x 64 k  (16384 u16)
  int tid = threadIdx.x;
  int wid = tid >> 6, lane = tid & 63;
  int q = lane >> 4, rr = lane & 15;
  int m0 = blockIdx.x * 128;
  int lr = lane >> 3;                       // row within an 8-row DMA group
  int swz = (lane & 7) ^ (lr & 7);          // swizzled k-chunk this lane fetches

  f32x4 acc[2][16] = {};

  for (int k0 = 0; k0 < K; k0 += 64) {
#pragma unroll
    for (int p = 0; p < 4; ++p) {           // A tile: 16 KB
      int idx = wid * 4 + p;                // 0..15
      int gr = m0 + idx * 8 + lr;
      if (gr >= M) gr = M - 1;
      g2l16(A + (size_t)gr * K + k0 + swz * 8, lA + idx * 512);
    }
#pragma unroll
    for (int p = 0; p < 8; ++p) {           // B tile: 32 KB
      int idx = wid * 8 + p;                // 0..31
      int nr = idx * 8 + lr;
      g2l16(BT + (size_t)nr * K + k0 + swz * 8, lB + idx * 512);
    }
    __syncthreads();
#pragma unroll
    for (int ks = 0; ks < 2; ++ks) {
      int ch = (ks << 2) | q;
      int r0 = wid * 32 + rr;
      bf16x8 a0 = *(const bf16x8*)&lA[r0 * 64 + ((ch ^ (rr & 7)) << 3)];
      bf16x8 a1 = *(const bf16x8*)&lA[(r0 + 16) * 64 + ((ch ^ (rr & 7)) << 3)];
#pragma unroll
      for (int ct = 0; ct < 16; ++ct) {
        int n = ct * 16 + rr;
        bf16x8 b = *(const bf16x8*)&lB[n * 64 + ((ch ^ (rr & 7)) << 3)];
        acc[0][ct] = __builtin_amdgcn_mfma_f32_16x16x32_bf16(a0, b, acc[0][ct], 0, 0, 0);
        acc[1][ct] = __builtin_amdgcn_mfma_f32_16x16x32_bf16(a1, b, acc[1][ct], 0, 0, 0);
      }
    }
    __syncthreads();
  }

  // epilogue: fused bias/BN/SiLU -> per-wave LDS slice -> coalesced dwordx4 stores
  u16* slice = smem + wid * 8192;           // 32 rows x 256 cols per wave
#pragma unroll
  for (int ct = 0; ct < 16; ++ct) {
    int c = ct * 16 + rr;
    float b = bias[c];
    float sc = scale ? scale[c] * 0.9999950000374997f : 1.0f;   // gamma/sqrt(1+1e-5)
    float sh = shift ? shift[c] : 0.0f;
#pragma unroll
    for (int rt = 0; rt < 2; ++rt)
#pragma unroll
      for (int i = 0; i < 4; ++i) {
        float y = (acc[rt][ct][i] + b) * sc + sh;
        slice[(rt * 16 + q * 4 + i) * 256 + c] = f2bf(siluf(y));
      }
  }
  __syncthreads();
  int rbase = m0 + wid * 32;
#pragma unroll
  for (int j = 0; j < 16; ++j) {
    int off = j * 512 + lane * 8;           // u16 index within slice
    int rloc = off >> 8;
    if (rbase + rloc < M)
      *(uint4*)(C + (size_t)(rbase + rloc) * 256 + (off & 255)) =
          *(const uint4*)(slice + off);
  }
}

// ---------------- MFMA head GEMM: [N,256] @ [256,32] -> atom_out[N,16], P[N,8(5)]
__global__ __launch_bounds__(256) void head_gemm(
    const u16* __restrict__ A, const u16* __restrict__ WT,
    const float* __restrict__ atomB,
    float* __restrict__ atom_out, float* __restrict__ P, int M) {
  __shared__ __align__(16) u16 lA[128 * 32];
  __shared__ __align__(16) u16 lB[32 * 264];
  int tid = threadIdx.x;
  int wid = tid >> 6, lane = tid & 63;
  int q = lane >> 4, rr = lane & 15;
  int m0 = blockIdx.x * 128;

  for (int i = tid; i < 32 * 256; i += 256)
    lB[(i >> 8) * 264 + (i & 255)] = WT[i];

  f32x4 acc[2][2] = {};
  int arow = tid >> 2, acol = (tid & 3) * 8;

  for (int k0 = 0; k0 < 256; k0 += 32) {
#pragma unroll
    for (int p = 0; p < 2; ++p) {
      int gr = m0 + p * 64 + arow;
      if (gr >= M) gr = M - 1;
      g2l16(A + (size_t)gr * 256 + k0 + acol, &lA[p * 2048 + wid * 512]);
    }
    __syncthreads();
    bf16x8 af[2], bfr[2];
#pragma unroll
    for (int mt = 0; mt < 2; ++mt)
      af[mt] = *(const bf16x8*)&lA[(wid * 32 + mt * 16 + rr) * 32 + q * 8];
#pragma unroll
    for (int nt = 0; nt < 2; ++nt)
      bfr[nt] = *(const bf16x8*)&lB[(nt * 16 + rr) * 264 + k0 + q * 8];
#pragma unroll
    for (int mt = 0; mt < 2; ++mt)
#pragma unroll
      for (int nt = 0; nt < 2; ++nt)
        acc[mt][nt] = __builtin_amdgcn_mfma_f32_16x16x32_bf16(af[mt], bfr[nt], acc[mt][nt], 0, 0, 0);
    __syncthreads();
  }

#pragma unroll
  for (int nt = 0; nt < 2; ++nt) {
    int c = nt * 16 + rr;
    float bb = (c < 16) ? atomB[c] : 0.0f;
#pragma unroll
    for (int mt = 0; mt < 2; ++mt) {
      int rbase = m0 + wid * 32 + mt * 16 + q * 4;
#pragma unroll
      for (int r2 = 0; r2 < 4; ++r2) {
        int row = rbase + r2;
        if (row < M) {
          float v = acc[mt][nt][r2];
          if (c < 16) atom_out[(size_t)row * 16 + c] = v + bb;
          else if (c < 21) P[(size_t)row * 8 + (c - 16)] = v;
        }
      }
    }
  }
}

// ---------------- bond edge output: out[e] = P[src]+P[dst]+b -------------------
__global__ __launch_bounds__(256) void bond_edge(
    const float* __restrict__ P, const int* __restrict__ src,
    const int* __restrict__ dst, const float* __restrict__ b,
    float* __restrict__ out, int E) {
  __shared__ float so[256 * 5];
  int t = threadIdx.x;
  int e = blockIdx.x * 256 + t;
  float v0 = 0, v1 = 0, v2 = 0, v3 = 0, v4 = 0;
  if (e < E) {
    int s = src[e], d = dst[e];
    float4 ps = *(const float4*)(P + (size_t)s * 8);
    float  p4s = P[(size_t)s * 8 + 4];
    float4 pd = *(const float4*)(P + (size_t)d * 8);
    float  p4d = P[(size_t)d * 8 + 4];
    v0 = ps.x + pd.x + b[0];
    v1 = ps.y + pd.y + b[1];
    v2 = ps.z + pd.z + b[2];
    v3 = ps.w + pd.w + b[3];
    v4 = p4s + p4d + b[4];
  }
  so[t * 5 + 0] = v0; so[t * 5 + 1] = v1; so[t * 5 + 2] = v2;
  so[t * 5 + 3] = v3; so[t * 5 + 4] = v4;
  __syncthreads();
  size_t base = (size_t)blockIdx.x * 256 * 5;
  size_t lim = (size_t)E * 5;
  for (int i = t; i < 256 * 5; i += 256) {
    size_t g = base + i;
    if (g < lim) out[g] = so[i];
  }
}

// ---------------- host ---------------------------------------------------------
extern "C" void kernel_launch(void* const* d_in, const int* in_sizes, int n_in,
                              void* d_out, int out_size, void* d_ws, size_t ws_size,
                              hipStream_t stream) {
  const int*   x_noisy   = (const int*)d_in[0];
  const int*   nmaskobs  = (const int*)d_in[1];
  const int*   ea        = (const int*)d_in[2];
  const int*   em        = (const int*)d_in[3];
  const int*   eidx      = (const int*)d_in[4];
  const int*   tnode     = (const int*)d_in[5];
  const float* cvec      = (const float*)d_in[6];
  const int*   batch     = (const int*)d_in[7];
  const float* atom_emb  = (const float*)d_in[8];
  const float* bond_emb  = (const float*)d_in[9];
  const float* nmask_emb = (const float*)d_in[10];
  const float* emask_emb = (const float*)d_in[11];
  const float* t_W1      = (const float*)d_in[12];
  const float* t_b1      = (const float*)d_in[13];
  const float* t_W2      = (const float*)d_in[14];
  const float* t_b2      = (const float*)d_in[15];
  const float* cond_W    = (const float*)d_in[16];
  const float* cond_b    = (const float*)d_in[17];
  const float* edge_W1   = (const float*)d_in[18];
  const float* edge_b1   = (const float*)d_in[19];
  const float* edge_W2   = (const float*)d_in[20];
  const float* edge_b2   = (const float*)d_in[21];
  const float* e0_W      = (const float*)d_in[22];
  const float* conv0_W1  = (const float*)d_in[23];
  const float* conv0_b1  = (const float*)d_in[24];
  const float* conv0_W2  = (const float*)d_in[25];
  const float* conv0_b2  = (const float*)d_in[26];
  const float* conv0_eps = (const float*)d_in[27];
  const float* convs_W1  = (const float*)d_in[28];
  const float* convs_b1  = (const float*)d_in[29];
  const float* convs_W2  = (const float*)d_in[30];
  const float* convs_b2  = (const float*)d_in[31];
  const float* convs_eps = (const float*)d_in[32];
  const float* bn_gamma  = (const float*)d_in[33];
  const float* bn_beta   = (const float*)d_in[34];
  const float* atom_W    = (const float*)d_in[35];
  const float* atom_b    = (const float*)d_in[36];
  const float* bond_W    = (const float*)d_in[37];
  const float* bond_b    = (const float*)d_in[38];

  const int N = in_sizes[0];
  const int E = in_sizes[2];
  const int B = in_sizes[6] / 2;
  const int* srcp = eidx;
  const int* dstp = eidx + E;

  char* base = (char*)d_ws;
  size_t off = 0;
  auto alloc = [&](size_t bytes) -> char* {
    char* p = base + off;
    off = (off + bytes + 255) & ~(size_t)255;
    return p;
  };
  u16* h0   = (u16*)alloc((size_t)N * W0 * 2);     // reused as h [N,256] after layer 0
  u16* z0   = (u16*)alloc((size_t)N * W0 * 2);     // reused as z [N,256]
  u16* ubuf = (u16*)alloc((size_t)N * DM * 2);
  u16* w10t = (u16*)alloc((size_t)DM * W0 * 2);
  u16* w20t = (u16*)alloc((size_t)DM * DM * 2);
  u16* wc1t = (u16*)alloc((size_t)5 * DM * DM * 2);
  u16* wc2t = (u16*)alloc((size_t)5 * DM * DM * 2);
  u16* wht  = (u16*)alloc((size_t)32 * DM * 2);
  float* ttab  = (float*)alloc((size_t)200 * DM * 4);
  float* cprojb= (float*)alloc((size_t)B * DM * 4);
  float* eftab = (float*)alloc((size_t)10 * DM * 4);
  float* e0tab = (float*)alloc((size_t)10 * W0 * 4);
  float* Pbuf  = (float*)alloc((size_t)N * 8 * 4);
  int* deg  = (int*)alloc((size_t)N * 4);
  int* ro   = (int*)alloc((size_t)(N + 1) * 4);
  int* cur  = (int*)alloc((size_t)N * 4);
  int* csr  = (int*)alloc((size_t)E * 4);
  int* bsum = (int*)alloc((size_t)256 * 4);
  (void)ws_size; (void)n_in; (void)out_size;

  u16* hbuf = h0;
  u16* zbuf = z0;
  float* atom_out = (float*)d_out;
  float* bond_out = atom_out + (size_t)N * 16;

  hipMemsetAsync(deg, 0, (size_t)N * 4, stream);

  // precompute: weights (transposed bf16), tables
  wT_kernel<<<(DM * W0 + 255) / 256, 256, 0, stream>>>(conv0_W1, w10t, 1, W0_REAL, W0, DM);
  wT_kernel<<<(DM * DM + 255) / 256, 256, 0, stream>>>(conv0_W2, w20t, 1, DM, DM, DM);
  wT_kernel<<<(5 * DM * DM + 255) / 256, 256, 0, stream>>>(convs_W1, wc1t, 5, DM, DM, DM);
  wT_kernel<<<(5 * DM * DM + 255) / 256, 256, 0, stream>>>(convs_W2, wc2t, 5, DM, DM, DM);
  whead_kernel<<<32, 256, 0, stream>>>(atom_W, bond_W, wht);
  t_table_kernel<<<200, 256, 0, stream>>>(t_W1, t_b1, t_W2, t_b2, ttab);
  cproj_kernel<<<(B * DM + 255) / 256, 256, 0, stream>>>(cvec, cond_W, cond_b, cprojb, B);
  ef_tab_kernel<<<10, 256, 0, stream>>>(bond_emb, emask_emb, edge_W1, edge_b1, edge_W2, edge_b2, eftab);
  e0_tab_kernel<<<10, 512, 0, stream>>>(eftab, e0_W, e0tab);
  h0_kernel<<<(N * 56 + 255) / 256, 256, 0, stream>>>(x_noisy, nmaskobs, tnode, batch,
      atom_emb, nmask_emb, ttab, cprojb, h0, N);
  // CSR by dst
  const int nscan = (N + 255) / 256;
  deg_kernel<<<(E + 255) / 256, 256, 0, stream>>>(dstp, deg, E);
  scan1_kernel<<<nscan, 256, 0, stream>>>(deg, ro, bsum, N);
  scan2_kernel<<<1, 256, 0, stream>>>(bsum, nscan);
  scan3_kernel<<<nscan, 256, 0, stream>>>(ro, cur, bsum, N, E);
  fill_kernel<<<(E + 255) / 256, 256, 0, stream>>>(srcp, dstp, ea, em, cur, csr, E);

  const int ggrid = (N + 127) / 128;
  const int nagg = (N + 3) / 4;
  // layer 0
  agg_z448<<<nagg, 256, 0, stream>>>(h0, e0tab, ro, csr, conv0_eps, z0, N);
  gemm_fused<<<ggrid, 256, 0, stream>>>(z0, w10t, conv0_b1, nullptr, nullptr, ubuf, N, W0);
  gemm_fused<<<ggrid, 256, 0, stream>>>(ubuf, w20t, conv0_b2, bn_gamma, bn_beta, hbuf, N, DM);
  // layers 1..5
  for (int i = 0; i < 5; ++i) {
    agg_z256<<<nagg, 256, 0, stream>>>(hbuf, eftab, ro, csr, convs_eps + i, zbuf, N);
    gemm_fused<<<ggrid, 256, 0, stream>>>(zbuf, wc1t + (size_t)i * DM * DM, convs_b1 + i * DM,
                                          nullptr, nullptr, ubuf, N, DM);
    gemm_fused<<<ggrid, 256, 0, stream>>>(ubuf, wc2t + (size_t)i * DM * DM, convs_b2 + i * DM,
                                          bn_gamma + (i + 1) * DM, bn_beta + (i + 1) * DM, hbuf, N, DM);
  }
  // heads
  head_gemm<<<(N + 127) / 128, 256, 0, stream>>>(hbuf, wht, atom_b, atom_out, Pbuf, N);
  bond_edge<<<(E + 255) / 256, 256, 0, stream>>>(Pbuf, srcp, dstp, bond_b, bond_out, E);
}

// Round 7
// 676.406 us; speedup vs baseline: 2.0409x; 1.0430x over previous
//
#include <hip/hip_runtime.h>
#include <cstdint>
#include <cmath>

typedef unsigned short u16;
typedef unsigned int   u32;

using bf16x8 = __attribute__((ext_vector_type(8))) short;
using f32x4  = __attribute__((ext_vector_type(4))) float;

#define DM 256        // d_model
#define W0 448        // layer-0 input width padded 392 -> 448 (multiple of 64)
#define W0_REAL 392

__device__ __forceinline__ float bf2f(u16 v) {
  union { u32 u; float f; } c; c.u = ((u32)v) << 16; return c.f;
}
__device__ __forceinline__ u16 f2bf(float f) {
  union { float f; u32 u; } c; c.f = f;
  u32 u = c.u;
  return (u16)((u + 0x7FFFu + ((u >> 16) & 1u)) >> 16);  // RNE
}
__device__ __forceinline__ float siluf(float y) {
  return y / (1.0f + __expf(-y));
}
__device__ __forceinline__ uint4 pack8(float f0, float f1, float f2, float f3,
                                       float f4, float f5, float f6, float f7) {
  uint4 o;
  o.x = (u32)f2bf(f0) | ((u32)f2bf(f1) << 16);
  o.y = (u32)f2bf(f2) | ((u32)f2bf(f3) << 16);
  o.z = (u32)f2bf(f4) | ((u32)f2bf(f5) << 16);
  o.w = (u32)f2bf(f6) | ((u32)f2bf(f7) << 16);
  return o;
}
// acc += relu(bf16x8(hv) + e[0..7]) elementwise
__device__ __forceinline__ void acc8(float4& lo, float4& hi, uint4 hv,
                                     float4 ea, float4 eb) {
  lo.x += fmaxf(bf2f((u16)(hv.x & 0xFFFF)) + ea.x, 0.f);
  lo.y += fmaxf(bf2f((u16)(hv.x >> 16))    + ea.y, 0.f);
  lo.z += fmaxf(bf2f((u16)(hv.y & 0xFFFF)) + ea.z, 0.f);
  lo.w += fmaxf(bf2f((u16)(hv.y >> 16))    + ea.w, 0.f);
  hi.x += fmaxf(bf2f((u16)(hv.z & 0xFFFF)) + eb.x, 0.f);
  hi.y += fmaxf(bf2f((u16)(hv.z >> 16))    + eb.y, 0.f);
  hi.z += fmaxf(bf2f((u16)(hv.w & 0xFFFF)) + eb.z, 0.f);
  hi.w += fmaxf(bf2f((u16)(hv.w >> 16))    + eb.w, 0.f);
}

// ---------------- weight transpose + bf16 convert: out[n*Kpad+k] = W[k*Nc+n] ----
__global__ void wT_kernel(const float* __restrict__ W, u16* __restrict__ out,
                          int nmat, int K, int Kpad, int Nc) {
  int idx = blockIdx.x * 256 + threadIdx.x;
  int tot = nmat * Nc * Kpad;
  if (idx >= tot) return;
  int m = idx / (Nc * Kpad);
  int r = idx - m * (Nc * Kpad);
  int n = r / Kpad;
  int k = r - n * Kpad;
  float v = (k < K) ? W[(size_t)m * K * Nc + (size_t)k * Nc + n] : 0.0f;
  out[idx] = f2bf(v);
}

// ---------------- combined head weight: [32,256] bf16 --------------------------
__global__ void whead_kernel(const float* __restrict__ atomW, const float* __restrict__ bondW,
                             u16* __restrict__ out) {
  int idx = blockIdx.x * 256 + threadIdx.x;
  if (idx >= 32 * 256) return;
  int j = idx >> 8, k = idx & 255;
  float v = 0.0f;
  if (j < 16) v = atomW[k * 16 + j];
  else if (j < 21) v = bondW[k * 5 + (j - 16)];
  out[idx] = f2bf(v);
}

// ---------------- timestep MLP table: 200 x 256 (f32) --------------------------
__global__ void t_table_kernel(const float* __restrict__ W1, const float* __restrict__ b1,
                               const float* __restrict__ W2, const float* __restrict__ b2,
                               float* __restrict__ out) {
  __shared__ float s[256];
  __shared__ float a1[256];
  int r = blockIdx.x, t = threadIdx.x;
  float tv = (float)r;
  float coef = -logf(10000.0f) / 127.0f;
  int j = t & 127;
  float ang = tv * expf(coef * (float)j);
  s[t] = (t < 128) ? sinf(ang) : cosf(ang);
  __syncthreads();
  float acc = b1[t];
  for (int k = 0; k < 256; ++k) acc = fmaf(s[k], W1[k * 256 + t], acc);
  a1[t] = acc / (1.0f + expf(-acc));
  __syncthreads();
  float acc2 = b2[t];
  for (int k = 0; k < 256; ++k) acc2 = fmaf(a1[k], W2[k * 256 + t], acc2);
  out[r * 256 + t] = acc2;
}

// ---------------- cond projection: B x 256 (f32) -------------------------------
__global__ void cproj_kernel(const float* __restrict__ cv, const float* __restrict__ W,
                             const float* __restrict__ b, float* __restrict__ out, int B) {
  int i = blockIdx.x * 256 + threadIdx.x;
  if (i < B * 256) {
    int g = i >> 8, c = i & 255;
    out[i] = fmaf(cv[g * 2], W[c], fmaf(cv[g * 2 + 1], W[256 + c], b[c]));
  }
}

// ---------------- edge-feature table: 10 x 256 (f32) ---------------------------
__global__ void ef_tab_kernel(const float* __restrict__ bond_emb, const float* __restrict__ emask_emb,
                              const float* __restrict__ W1, const float* __restrict__ b1,
                              const float* __restrict__ W2, const float* __restrict__ b2,
                              float* __restrict__ out) {
  __shared__ float ein[72];
  __shared__ float a1[256];
  int bidx = blockIdx.x;           // 0..9
  int bt = bidx >> 1, m = bidx & 1;
  int t = threadIdx.x;
  if (t < 64) ein[t] = bond_emb[bt * 64 + t];
  else if (t < 72) ein[t] = emask_emb[m * 8 + (t - 64)];
  __syncthreads();
  float acc = b1[t];
  for (int k = 0; k < 72; ++k) acc = fmaf(ein[k], W1[k * 256 + t], acc);
  a1[t] = acc / (1.0f + expf(-acc));
  __syncthreads();
  float acc2 = b2[t];
  for (int k = 0; k < 256; ++k) acc2 = fmaf(a1[k], W2[k * 256 + t], acc2);
  out[bidx * 256 + t] = acc2;
}

// ---------------- layer-0 edge table: e_feat @ e0_W -> 10 x 448 (padded) -------
__global__ void e0_tab_kernel(const float* __restrict__ eftab, const float* __restrict__ e0W,
                              float* __restrict__ out) {
  __shared__ float ef[256];
  int bidx = blockIdx.x, t = threadIdx.x;
  if (t < 256) ef[t] = eftab[bidx * 256 + t];
  __syncthreads();
  if (t < W0) {
    float acc = 0.0f;
    if (t < W0_REAL) {
      for (int k = 0; k < 256; ++k) acc = fmaf(ef[k], e0W[k * W0_REAL + t], acc);
    }
    out[bidx * W0 + t] = acc;
  }
}

// ---------------- h0 build: [N, 448] bf16, 8-col chunks ------------------------
__global__ void h0_kernel(const int* __restrict__ x, const int* __restrict__ nm,
                          const int* __restrict__ tnode, const int* __restrict__ batch,
                          const float* __restrict__ atom_emb, const float* __restrict__ nmask_emb,
                          const float* __restrict__ ttab, const float* __restrict__ cproj,
                          u16* __restrict__ h0, int N) {
  int idx = blockIdx.x * 256 + threadIdx.x;
  if (idx >= N * 56) return;
  int n = idx / 56;
  int ch = idx - n * 56;
  uint4 o;
  if (ch < 16) {
    const float* s = atom_emb + (size_t)x[n] * 128 + ch * 8;
    float4 a = *(const float4*)s, b = *(const float4*)(s + 4);
    o = pack8(a.x, a.y, a.z, a.w, b.x, b.y, b.z, b.w);
  } else if (ch == 16) {
    const float* s = nmask_emb + (size_t)nm[n] * 8;
    float4 a = *(const float4*)s, b = *(const float4*)(s + 4);
    o = pack8(a.x, a.y, a.z, a.w, b.x, b.y, b.z, b.w);
  } else if (ch < 49) {
    int cc = ch * 8 - 136;
    const float* ta = ttab + (size_t)tnode[n] * 256 + cc;
    const float* cb = cproj + (size_t)batch[n] * 256 + cc;
    float4 a = *(const float4*)ta, b = *(const float4*)(ta + 4);
    float4 c = *(const float4*)cb, d = *(const float4*)(cb + 4);
    o = pack8(a.x + c.x, a.y + c.y, a.z + c.z, a.w + c.w,
              b.x + d.x, b.y + d.y, b.z + d.z, b.w + d.w);
  } else {
    o = make_uint4(0, 0, 0, 0);
  }
  *(uint4*)(h0 + (size_t)n * W0 + ch * 8) = o;
}

// ---------------- CSR build ----------------------------------------------------
__global__ void deg_kernel(const int* __restrict__ dst, int* __restrict__ deg, int E) {
  int e = blockIdx.x * 256 + threadIdx.x;
  if (e < E) atomicAdd(&deg[dst[e]], 1);
}

__global__ void scan1_kernel(const int* __restrict__ deg, int* __restrict__ ro,
                             int* __restrict__ bsum, int N) {
  __shared__ int tmp[256];
  int tid = threadIdx.x, i = blockIdx.x * 256 + tid;
  int v = (i < N) ? deg[i] : 0;
  tmp[tid] = v;
  __syncthreads();
  for (int o = 1; o < 256; o <<= 1) {
    int t = (tid >= o) ? tmp[tid - o] : 0;
    __syncthreads();
    tmp[tid] += t;
    __syncthreads();
  }
  if (i < N) ro[i] = tmp[tid] - v;
  if (tid == 255) bsum[blockIdx.x] = tmp[255];
}

__global__ void scan2_kernel(int* __restrict__ bsum, int nb) {
  __shared__ int tmp[256];
  int tid = threadIdx.x;
  int v = (tid < nb) ? bsum[tid] : 0;
  tmp[tid] = v;
  __syncthreads();
  for (int o = 1; o < 256; o <<= 1) {
    int t = (tid >= o) ? tmp[tid - o] : 0;
    __syncthreads();
    tmp[tid] += t;
    __syncthreads();
  }
  if (tid < nb) bsum[tid] = tmp[tid] - v;
}

__global__ void scan3_kernel(int* __restrict__ ro, int* __restrict__ cur,
                             const int* __restrict__ bsum, int N, int E) {
  int i = blockIdx.x * 256 + threadIdx.x;
  if (i < N) {
    int r = ro[i] + bsum[blockIdx.x];
    ro[i] = r;
    cur[i] = r;
  }
  if (i == 0) ro[N] = E;
}

__global__ void fill_kernel(const int* __restrict__ src, const int* __restrict__ dst,
                            const int* __restrict__ ea, const int* __restrict__ em,
                            int* __restrict__ cur, int* __restrict__ csr, int E) {
  int e = blockIdx.x * 256 + threadIdx.x;
  if (e < E) {
    int d = dst[e];
    int pos = atomicAdd(&cur[d], 1);
    csr[pos] = src[e] | ((ea[e] * 2 + em[e]) << 20);
  }
}

// ---------------- agg (W=256): 2 edges per wave, lane owns 8 cols --------------
__global__ __launch_bounds__(256) void agg_z256(
    const u16* __restrict__ h, const float* __restrict__ etab,
    const int* __restrict__ ro, const int* __restrict__ csr,
    const float* __restrict__ epsp, u16* __restrict__ z, int N) {
  int wid = threadIdx.x >> 6, lane = threadIdx.x & 63;
  int n = blockIdx.x * 4 + wid;
  if (n >= N) return;
  int s0 = ro[n], s1 = ro[n + 1];
  float eps1 = 1.0f + *epsp;
  int half = lane >> 5, li = lane & 31;
  int c8 = li * 8;
  float4 aLo = {0, 0, 0, 0}, aHi = {0, 0, 0, 0};

  for (int base = s0; base < s1; base += 64) {
    int m = s1 - base; if (m > 64) m = 64;
    int pk = (lane < m) ? csr[base + lane] : 0;
    int j = 0;
    for (; j + 3 < m; j += 4) {       // 4 edges per iter (2 per half-wave pair)
      int p0 = __shfl(pk, j + half);
      int p1 = __shfl(pk, j + 2 + half);
      uint4 h0v = *(const uint4*)(h + (size_t)(p0 & 0xFFFFF) * 256 + c8);
      uint4 h1v = *(const uint4*)(h + (size_t)(p1 & 0xFFFFF) * 256 + c8);
      const float* e0p = etab + (size_t)(p0 >> 20) * 256 + c8;
      const float* e1p = etab + (size_t)(p1 >> 20) * 256 + c8;
      float4 e0a = *(const float4*)e0p, e0b = *(const float4*)(e0p + 4);
      float4 e1a = *(const float4*)e1p, e1b = *(const float4*)(e1p + 4);
      acc8(aLo, aHi, h0v, e0a, e0b);
      acc8(aLo, aHi, h1v, e1a, e1b);
    }
    for (; j < m; j += 2) {           // tail (up to 3 edges)
      int idx = j + half;
      bool act = idx < m;
      int p = __shfl(pk, act ? idx : (m - 1));
      uint4 hv = *(const uint4*)(h + (size_t)(p & 0xFFFFF) * 256 + c8);
      const float* ep = etab + (size_t)(p >> 20) * 256 + c8;
      float4 ea = *(const float4*)ep, eb = *(const float4*)(ep + 4);
      if (act) acc8(aLo, aHi, hv, ea, eb);
    }
  }
  // fold half-1 partial sums into half-0
  aLo.x += __shfl(aLo.x, li + 32); aLo.y += __shfl(aLo.y, li + 32);
  aLo.z += __shfl(aLo.z, li + 32); aLo.w += __shfl(aLo.w, li + 32);
  aHi.x += __shfl(aHi.x, li + 32); aHi.y += __shfl(aHi.y, li + 32);
  aHi.z += __shfl(aHi.z, li + 32); aHi.w += __shfl(aHi.w, li + 32);
  if (half == 0) {
    uint4 hn = *(const uint4*)(h + (size_t)n * 256 + c8);
    uint4 o = pack8(
        eps1 * bf2f((u16)(hn.x & 0xFFFF)) + aLo.x,
        eps1 * bf2f((u16)(hn.x >> 16))    + aLo.y,
        eps1 * bf2f((u16)(hn.y & 0xFFFF)) + aLo.z,
        eps1 * bf2f((u16)(hn.y >> 16))    + aLo.w,
        eps1 * bf2f((u16)(hn.z & 0xFFFF)) + aHi.x,
        eps1 * bf2f((u16)(hn.z >> 16))    + aHi.y,
        eps1 * bf2f((u16)(hn.w & 0xFFFF)) + aHi.z,
        eps1 * bf2f((u16)(hn.w >> 16))    + aHi.w);
    *(uint4*)(z + (size_t)n * 256 + c8) = o;
  }
}

// ---------------- agg (W=448, layer 0): lane owns 8 cols, 56 live lanes --------
__global__ __launch_bounds__(256) void agg_z448(
    const u16* __restrict__ h, const float* __restrict__ etab,
    const int* __restrict__ ro, const int* __restrict__ csr,
    const float* __restrict__ epsp, u16* __restrict__ z, int N) {
  int wid = threadIdx.x >> 6, lane = threadIdx.x & 63;
  int n = blockIdx.x * 4 + wid;
  if (n >= N) return;
  int s0 = ro[n], s1 = ro[n + 1];
  float eps1 = 1.0f + *epsp;
  bool live = lane < 56;
  int c8 = live ? lane * 8 : 440;    // clamp dead lanes to a harmless chunk
  float4 aLo = {0, 0, 0, 0}, aHi = {0, 0, 0, 0};

  for (int base = s0; base < s1; base += 64) {
    int m = s1 - base; if (m > 64) m = 64;
    int pk = (lane < m) ? csr[base + lane] : 0;
    int j = 0;
    for (; j + 1 < m; j += 2) {
      int p0 = __shfl(pk, j);
      int p1 = __shfl(pk, j + 1);
      uint4 h0v = *(const uint4*)(h + (size_t)(p0 & 0xFFFFF) * W0 + c8);
      uint4 h1v = *(const uint4*)(h + (size_t)(p1 & 0xFFFFF) * W0 + c8);
      const float* e0p = etab + (size_t)(p0 >> 20) * W0 + c8;
      const float* e1p = etab + (size_t)(p1 >> 20) * W0 + c8;
      float4 e0a = *(const float4*)e0p, e0b = *(const float4*)(e0p + 4);
      float4 e1a = *(const float4*)e1p, e1b = *(const float4*)(e1p + 4);
      acc8(aLo, aHi, h0v, e0a, e0b);
      acc8(aLo, aHi, h1v, e1a, e1b);
    }
    if (j < m) {
      int p = __shfl(pk, j);
      uint4 hv = *(const uint4*)(h + (size_t)(p & 0xFFFFF) * W0 + c8);
      const float* ep = etab + (size_t)(p >> 20) * W0 + c8;
      float4 ea = *(const float4*)ep, eb = *(const float4*)(ep + 4);
      acc8(aLo, aHi, hv, ea, eb);
    }
  }
  if (live) {
    uint4 hn = *(const uint4*)(h + (size_t)n * W0 + c8);
    uint4 o = pack8(
        eps1 * bf2f((u16)(hn.x & 0xFFFF)) + aLo.x,
        eps1 * bf2f((u16)(hn.x >> 16))    + aLo.y,
        eps1 * bf2f((u16)(hn.y & 0xFFFF)) + aLo.z,
        eps1 * bf2f((u16)(hn.y >> 16))    + aLo.w,
        eps1 * bf2f((u16)(hn.z & 0xFFFF)) + aHi.x,
        eps1 * bf2f((u16)(hn.z >> 16))    + aHi.y,
        eps1 * bf2f((u16)(hn.w & 0xFFFF)) + aHi.z,
        eps1 * bf2f((u16)(hn.w >> 16))    + aHi.w);
    *(uint4*)(z + (size_t)n * W0 + c8) = o;
  }
}

// ---------------- bf16 MFMA GEMM: C[M,256] = silu(((A@B)+bias)*scale+shift) ----
// Block: 128 rows x 256 cols, BK=64, waves tiled 2x2 (each wave 64 rows x 128
// cols): per-BK ds_read_b128 count 24 vs 64 MFMA -> MFMA-bound inner loop.
__device__ __forceinline__ void g2l16(const u16* g, u16* l) {
  __builtin_amdgcn_global_load_lds(
      (__attribute__((address_space(1))) u32*)g,
      (__attribute__((address_space(3))) u32*)l, 16, 0, 0);
}

__global__ __launch_bounds__(256, 2) void gemm_fused(
    const u16* __restrict__ A, const u16* __restrict__ BT,
    const float* __restrict__ bias, const float* __restrict__ scale,
    const float* __restrict__ shift, u16* __restrict__ C, int M, int K) {
  __shared__ __align__(16) u16 smem[32768];   // 64 KB: staging (48 KB) / epilogue
  u16* lA = smem;                // 128 rows x 64 k  (8192 u16)
  u16* lB = smem + 8192;         // 256 rows x 64 k  (16384 u16)
  int tid = threadIdx.x;
  int wid = tid >> 6, lane = tid & 63;
  int q = lane >> 4, rr = lane & 15;
  int wm = wid >> 1, wn = wid & 1;          // 2x2 wave grid
  int m0 = blockIdx.x * 128;
  int lr = lane >> 3;                       // row within an 8-row DMA group
  int swz = (lane & 7) ^ (lr & 7);          // swizzled k-chunk this lane fetches

  f32x4 acc[4][8] = {};

  for (int k0 = 0; k0 < K; k0 += 64) {
#pragma unroll
    for (int p = 0; p < 4; ++p) {           // A tile: 16 KB
      int idx = wid * 4 + p;                // 0..15
      int gr = m0 + idx * 8 + lr;
      if (gr >= M) gr = M - 1;
      g2l16(A + (size_t)gr * K + k0 + swz * 8, lA + idx * 512);
    }
#pragma unroll
    for (int p = 0; p < 8; ++p) {           // B tile: 32 KB
      int idx = wid * 8 + p;                // 0..31
      int nr = idx * 8 + lr;
      g2l16(BT + (size_t)nr * K + k0 + swz * 8, lB + idx * 512);
    }
    __syncthreads();
#pragma unroll
    for (int ks = 0; ks < 2; ++ks) {
      int ch = (ks << 2) | q;
      int slot = (ch ^ (rr & 7)) << 3;
      bf16x8 af[4], bf[8];
#pragma unroll
      for (int mt = 0; mt < 4; ++mt)
        af[mt] = *(const bf16x8*)&lA[(wm * 64 + mt * 16 + rr) * 64 + slot];
#pragma unroll
      for (int nt = 0; nt < 8; ++nt)
        bf[nt] = *(const bf16x8*)&lB[(wn * 128 + nt * 16 + rr) * 64 + slot];
#pragma unroll
      for (int mt = 0; mt < 4; ++mt)
#pragma unroll
        for (int nt = 0; nt < 8; ++nt)
          acc[mt][nt] = __builtin_amdgcn_mfma_f32_16x16x32_bf16(af[mt], bf[nt], acc[mt][nt], 0, 0, 0);
    }
    __syncthreads();
  }

  // epilogue: fused bias/BN/SiLU -> per-wave 16 KB LDS slice (64 rows x 128
  // cols) -> coalesced dwordx4 stores (256B segments)
  u16* slice = smem + wid * 8192;
#pragma unroll
  for (int nt = 0; nt < 8; ++nt) {
    int c = wn * 128 + nt * 16 + rr;
    float b = bias[c];
    float sc = scale ? scale[c] * 0.9999950000374997f : 1.0f;   // gamma/sqrt(1+1e-5)
    float sh = shift ? shift[c] : 0.0f;
#pragma unroll
    for (int mt = 0; mt < 4; ++mt)
#pragma unroll
      for (int i = 0; i < 4; ++i) {
        float y = (acc[mt][nt][i] + b) * sc + sh;
        slice[(mt * 16 + q * 4 + i) * 128 + nt * 16 + rr] = f2bf(siluf(y));
      }
  }
  __syncthreads();
  int rbase = m0 + wm * 64;
  int cbase = wn * 128;
#pragma unroll
  for (int j = 0; j < 16; ++j) {
    int idx = j * 64 + lane;                // uint4 index in slice (1024 total)
    int rloc = idx >> 4;                    // 16 uint4 per 128-col row
    int c8 = (idx & 15) * 8;
    if (rbase + rloc < M)
      *(uint4*)(C + (size_t)(rbase + rloc) * 256 + cbase + c8) =
          *(const uint4*)(slice + rloc * 128 + c8);
  }
}

// ---------------- MFMA head GEMM: [N,256] @ [256,32] -> atom_out[N,16], P[N,8(5)]
__global__ __launch_bounds__(256) void head_gemm(
    const u16* __restrict__ A, const u16* __restrict__ WT,
    const float* __restrict__ atomB,
    float* __restrict__ atom_out, float* __restrict__ P, int M) {
  __shared__ __align__(16) u16 lA[128 * 32];
  __shared__ __align__(16) u16 lB[32 * 264];
  int tid = threadIdx.x;
  int wid = tid >> 6, lane = tid & 63;
  int q = lane >> 4, rr = lane & 15;
  int m0 = blockIdx.x * 128;

  for (int i = tid; i < 32 * 256; i += 256)
    lB[(i >> 8) * 264 + (i & 255)] = WT[i];

  f32x4 acc[2][2] = {};
  int arow = tid >> 2, acol = (tid & 3) * 8;

  for (int k0 = 0; k0 < 256; k0 += 32) {
#pragma unroll
    for (int p = 0; p < 2; ++p) {
      int gr = m0 + p * 64 + arow;
      if (gr >= M) gr = M - 1;
      g2l16(A + (size_t)gr * 256 + k0 + acol, &lA[p * 2048 + wid * 512]);
    }
    __syncthreads();
    bf16x8 af[2], bfr[2];
#pragma unroll
    for (int mt = 0; mt < 2; ++mt)
      af[mt] = *(const bf16x8*)&lA[(wid * 32 + mt * 16 + rr) * 32 + q * 8];
#pragma unroll
    for (int nt = 0; nt < 2; ++nt)
      bfr[nt] = *(const bf16x8*)&lB[(nt * 16 + rr) * 264 + k0 + q * 8];
#pragma unroll
    for (int mt = 0; mt < 2; ++mt)
#pragma unroll
      for (int nt = 0; nt < 2; ++nt)
        acc[mt][nt] = __builtin_amdgcn_mfma_f32_16x16x32_bf16(af[mt], bfr[nt], acc[mt][nt], 0, 0, 0);
    __syncthreads();
  }

#pragma unroll
  for (int nt = 0; nt < 2; ++nt) {
    int c = nt * 16 + rr;
    float bb = (c < 16) ? atomB[c] : 0.0f;
#pragma unroll
    for (int mt = 0; mt < 2; ++mt) {
      int rbase = m0 + wid * 32 + mt * 16 + q * 4;
#pragma unroll
      for (int r2 = 0; r2 < 4; ++r2) {
        int row = rbase + r2;
        if (row < M) {
          float v = acc[mt][nt][r2];
          if (c < 16) atom_out[(size_t)row * 16 + c] = v + bb;
          else if (c < 21) P[(size_t)row * 8 + (c - 16)] = v;
        }
      }
    }
  }
}

// ---------------- bond edge output: out[e] = P[src]+P[dst]+b -------------------
__global__ __launch_bounds__(256) void bond_edge(
    const float* __restrict__ P, const int* __restrict__ src,
    const int* __restrict__ dst, const float* __restrict__ b,
    float* __restrict__ out, int E) {
  __shared__ float so[256 * 5];
  int t = threadIdx.x;
  int e = blockIdx.x * 256 + t;
  float v0 = 0, v1 = 0, v2 = 0, v3 = 0, v4 = 0;
  if (e < E) {
    int s = src[e], d = dst[e];
    float4 ps = *(const float4*)(P + (size_t)s * 8);
    float  p4s = P[(size_t)s * 8 + 4];
    float4 pd = *(const float4*)(P + (size_t)d * 8);
    float  p4d = P[(size_t)d * 8 + 4];
    v0 = ps.x + pd.x + b[0];
    v1 = ps.y + pd.y + b[1];
    v2 = ps.z + pd.z + b[2];
    v3 = ps.w + pd.w + b[3];
    v4 = p4s + p4d + b[4];
  }
  so[t * 5 + 0] = v0; so[t * 5 + 1] = v1; so[t * 5 + 2] = v2;
  so[t * 5 + 3] = v3; so[t * 5 + 4] = v4;
  __syncthreads();
  size_t base = (size_t)blockIdx.x * 256 * 5;
  size_t lim = (size_t)E * 5;
  for (int i = t; i < 256 * 5; i += 256) {
    size_t g = base + i;
    if (g < lim) out[g] = so[i];
  }
}

// ---------------- host ---------------------------------------------------------
extern "C" void kernel_launch(void* const* d_in, const int* in_sizes, int n_in,
                              void* d_out, int out_size, void* d_ws, size_t ws_size,
                              hipStream_t stream) {
  const int*   x_noisy   = (const int*)d_in[0];
  const int*   nmaskobs  = (const int*)d_in[1];
  const int*   ea        = (const int*)d_in[2];
  const int*   em        = (const int*)d_in[3];
  const int*   eidx      = (const int*)d_in[4];
  const int*   tnode     = (const int*)d_in[5];
  const float* cvec      = (const float*)d_in[6];
  const int*   batch     = (const int*)d_in[7];
  const float* atom_emb  = (const float*)d_in[8];
  const float* bond_emb  = (const float*)d_in[9];
  const float* nmask_emb = (const float*)d_in[10];
  const float* emask_emb = (const float*)d_in[11];
  const float* t_W1      = (const float*)d_in[12];
  const float* t_b1      = (const float*)d_in[13];
  const float* t_W2      = (const float*)d_in[14];
  const float* t_b2      = (const float*)d_in[15];
  const float* cond_W    = (const float*)d_in[16];
  const float* cond_b    = (const float*)d_in[17];
  const float* edge_W1   = (const float*)d_in[18];
  const float* edge_b1   = (const float*)d_in[19];
  const float* edge_W2   = (const float*)d_in[20];
  const float* edge_b2   = (const float*)d_in[21];
  const float* e0_W      = (const float*)d_in[22];
  const float* conv0_W1  = (const float*)d_in[23];
  const float* conv0_b1  = (const float*)d_in[24];
  const float* conv0_W2  = (const float*)d_in[25];
  const float* conv0_b2  = (const float*)d_in[26];
  const float* conv0_eps = (const float*)d_in[27];
  const float* convs_W1  = (const float*)d_in[28];
  const float* convs_b1  = (const float*)d_in[29];
  const float* convs_W2  = (const float*)d_in[30];
  const float* convs_b2  = (const float*)d_in[31];
  const float* convs_eps = (const float*)d_in[32];
  const float* bn_gamma  = (const float*)d_in[33];
  const float* bn_beta   = (const float*)d_in[34];
  const float* atom_W    = (const float*)d_in[35];
  const float* atom_b    = (const float*)d_in[36];
  const float* bond_W    = (const float*)d_in[37];
  const float* bond_b    = (const float*)d_in[38];

  const int N = in_sizes[0];
  const int E = in_sizes[2];
  const int B = in_sizes[6] / 2;
  const int* srcp = eidx;
  const int* dstp = eidx + E;

  char* base = (char*)d_ws;
  size_t off = 0;
  auto alloc = [&](size_t bytes) -> char* {
    char* p = base + off;
    off = (off + bytes + 255) & ~(size_t)255;
    return p;
  };
  u16* h0   = (u16*)alloc((size_t)N * W0 * 2);     // reused as h [N,256] after layer 0
  u16* z0   = (u16*)alloc((size_t)N * W0 * 2);     // reused as z [N,256]
  u16* ubuf = (u16*)alloc((size_t)N * DM * 2);
  u16* w10t = (u16*)alloc((size_t)DM * W0 * 2);
  u16* w20t = (u16*)alloc((size_t)DM * DM * 2);
  u16* wc1t = (u16*)alloc((size_t)5 * DM * DM * 2);
  u16* wc2t = (u16*)alloc((size_t)5 * DM * DM * 2);
  u16* wht  = (u16*)alloc((size_t)32 * DM * 2);
  float* ttab  = (float*)alloc((size_t)200 * DM * 4);
  float* cprojb= (float*)alloc((size_t)B * DM * 4);
  float* eftab = (float*)alloc((size_t)10 * DM * 4);
  float* e0tab = (float*)alloc((size_t)10 * W0 * 4);
  float* Pbuf  = (float*)alloc((size_t)N * 8 * 4);
  int* deg  = (int*)alloc((size_t)N * 4);
  int* ro   = (int*)alloc((size_t)(N + 1) * 4);
  int* cur  = (int*)alloc((size_t)N * 4);
  int* csr  = (int*)alloc((size_t)E * 4);
  int* bsum = (int*)alloc((size_t)256 * 4);
  (void)ws_size; (void)n_in; (void)out_size;

  u16* hbuf = h0;
  u16* zbuf = z0;
  float* atom_out = (float*)d_out;
  float* bond_out = atom_out + (size_t)N * 16;

  hipMemsetAsync(deg, 0, (size_t)N * 4, stream);

  // precompute: weights (transposed bf16), tables
  wT_kernel<<<(DM * W0 + 255) / 256, 256, 0, stream>>>(conv0_W1, w10t, 1, W0_REAL, W0, DM);
  wT_kernel<<<(DM * DM + 255) / 256, 256, 0, stream>>>(conv0_W2, w20t, 1, DM, DM, DM);
  wT_kernel<<<(5 * DM * DM + 255) / 256, 256, 0, stream>>>(convs_W1, wc1t, 5, DM, DM, DM);
  wT_kernel<<<(5 * DM * DM + 255) / 256, 256, 0, stream>>>(convs_W2, wc2t, 5, DM, DM, DM);
  whead_kernel<<<32, 256, 0, stream>>>(atom_W, bond_W, wht);
  t_table_kernel<<<200, 256, 0, stream>>>(t_W1, t_b1, t_W2, t_b2, ttab);
  cproj_kernel<<<(B * DM + 255) / 256, 256, 0, stream>>>(cvec, cond_W, cond_b, cprojb, B);
  ef_tab_kernel<<<10, 256, 0, stream>>>(bond_emb, emask_emb, edge_W1, edge_b1, edge_W2, edge_b2, eftab);
  e0_tab_kernel<<<10, 512, 0, stream>>>(eftab, e0_W, e0tab);
  h0_kernel<<<(N * 56 + 255) / 256, 256, 0, stream>>>(x_noisy, nmaskobs, tnode, batch,
      atom_emb, nmask_emb, ttab, cprojb, h0, N);
  // CSR by dst
  const int nscan = (N + 255) / 256;
  deg_kernel<<<(E + 255) / 256, 256, 0, stream>>>(dstp, deg, E);
  scan1_kernel<<<nscan, 256, 0, stream>>>(deg, ro, bsum, N);
  scan2_kernel<<<1, 256, 0, stream>>>(bsum, nscan);
  scan3_kernel<<<nscan, 256, 0, stream>>>(ro, cur, bsum, N, E);
  fill_kernel<<<(E + 255) / 256, 256, 0, stream>>>(srcp, dstp, ea, em, cur, csr, E);

  const int ggrid = (N + 127) / 128;
  const int nagg = (N + 3) / 4;
  // layer 0
  agg_z448<<<nagg, 256, 0, stream>>>(h0, e0tab, ro, csr, conv0_eps, z0, N);
  gemm_fused<<<ggrid, 256, 0, stream>>>(z0, w10t, conv0_b1, nullptr, nullptr, ubuf, N, W0);
  gemm_fused<<<ggrid, 256, 0, stream>>>(ubuf, w20t, conv0_b2, bn_gamma, bn_beta, hbuf, N, DM);
  // layers 1..5
  for (int i = 0; i < 5; ++i) {
    agg_z256<<<nagg, 256, 0, stream>>>(hbuf, eftab, ro, csr, convs_eps + i, zbuf, N);
    gemm_fused<<<ggrid, 256, 0, stream>>>(zbuf, wc1t + (size_t)i * DM * DM, convs_b1 + i * DM,
                                          nullptr, nullptr, ubuf, N, DM);
    gemm_fused<<<ggrid, 256, 0, stream>>>(ubuf, wc2t + (size_t)i * DM * DM, convs_b2 + i * DM,
                                          bn_gamma + (i + 1) * DM, bn_beta + (i + 1) * DM, hbuf, N, DM);
  }
  // heads
  head_gemm<<<(N + 127) / 128, 256, 0, stream>>>(hbuf, wht, atom_b, atom_out, Pbuf, N);
  bond_edge<<<(E + 255) / 256, 256, 0, stream>>>(Pbuf, srcp, dstp, bond_b, bond_out, E);
}